// Round 1
// 2786.222 us; speedup vs baseline: 3.7462x; 3.7462x over previous
//
#include <hip/hip_runtime.h>
#include <hip/hip_bf16.h>

#define NLAYER 12
#define DMODEL 768
#define NHEAD  12
#define HDIM   64
#define FDIM   3072
#define VOCAB  30522
#define SLEN   512
#define NBATCH 4
#define NTOK   (NBATCH*SLEN)
#define EPSLN  1e-5f

typedef unsigned short u16;
using bf16 = __hip_bfloat16;
typedef __bf16 bf16x8 __attribute__((ext_vector_type(8)));
typedef float  f32x4  __attribute__((ext_vector_type(4)));

__device__ __forceinline__ u16 f2bs(float f) {
    bf16 h = __float2bfloat16(f);
    return *reinterpret_cast<u16*>(&h);
}

// async global->LDS, 16B per lane. LDS dest = wave-uniform base + lane*16.
__device__ __forceinline__ void gload_lds16(const void* g, void* l) {
    auto gp = (const __attribute__((address_space(1))) unsigned int*)g;
    auto lp = (__attribute__((address_space(3))) unsigned int*)(unsigned long long)l;
    __builtin_amdgcn_global_load_lds(gp, lp, 16, 0, 0);
}

// ---------------- reductions ----------------
__device__ __forceinline__ float wave_sum64(float v) {
#pragma unroll
    for (int off = 32; off > 0; off >>= 1) v += __shfl_down(v, off, 64);
    return v;
}
__device__ __forceinline__ float wave_max64(float v) {
#pragma unroll
    for (int off = 32; off > 0; off >>= 1) v = fmaxf(v, __shfl_down(v, off, 64));
    return v;
}
__device__ __forceinline__ float block_sum256(float v, float* red) {
    v = wave_sum64(v);
    __syncthreads();
    if ((threadIdx.x & 63) == 0) red[threadIdx.x >> 6] = v;
    __syncthreads();
    return red[0] + red[1] + red[2] + red[3];
}
__device__ __forceinline__ float block_max256(float v, float* red) {
    v = wave_max64(v);
    __syncthreads();
    if ((threadIdx.x & 63) == 0) red[threadIdx.x >> 6] = v;
    __syncthreads();
    return fmaxf(fmaxf(red[0], red[1]), fmaxf(red[2], red[3]));
}

// ---------------- embedding + LN (writes f32 + bf16) ----------------
__global__ __launch_bounds__(256) void embed_ln_kernel(
    const int* __restrict__ ids, const float* __restrict__ word,
    const float* __restrict__ pos, const float* __restrict__ seg,
    const float* __restrict__ g, const float* __restrict__ b,
    float* __restrict__ out, u16* __restrict__ outb)
{
    __shared__ float red[4];
    int t = blockIdx.x;
    int s = t & (SLEN - 1);
    long woff = (long)ids[t] * DMODEL;
    float vals[3];
#pragma unroll
    for (int i = 0; i < 3; i++) {
        int d = threadIdx.x + i * 256;
        vals[i] = word[woff + d] + pos[(long)s * DMODEL + d] + seg[d];
    }
    float mu = block_sum256(vals[0] + vals[1] + vals[2], red) * (1.0f / DMODEL);
    float vv = 0.f;
#pragma unroll
    for (int i = 0; i < 3; i++) { float d0 = vals[i] - mu; vv += d0 * d0; }
    float rstd = rsqrtf(block_sum256(vv, red) * (1.0f / DMODEL) + EPSLN);
#pragma unroll
    for (int i = 0; i < 3; i++) {
        int d = threadIdx.x + i * 256;
        float r = (vals[i] - mu) * rstd * g[d] + b[d];
        out[(long)t * DMODEL + d] = r;
        outb[(long)t * DMODEL + d] = f2bs(r);
    }
}

// ---------------- residual + LN (writes f32 + bf16) ----------------
__global__ __launch_bounds__(256) void ln_res_kernel(
    const float* __restrict__ a, const float* __restrict__ bres,
    const float* __restrict__ g, const float* __restrict__ beta,
    float* __restrict__ out, u16* __restrict__ outb)
{
    __shared__ float red[4];
    long t = blockIdx.x;
    float vals[3];
#pragma unroll
    for (int i = 0; i < 3; i++) {
        int d = threadIdx.x + i * 256;
        vals[i] = a[t * DMODEL + d] + bres[t * DMODEL + d];
    }
    float mu = block_sum256(vals[0] + vals[1] + vals[2], red) * (1.0f / DMODEL);
    float vv = 0.f;
#pragma unroll
    for (int i = 0; i < 3; i++) { float d0 = vals[i] - mu; vv += d0 * d0; }
    float rstd = rsqrtf(block_sum256(vv, red) * (1.0f / DMODEL) + EPSLN);
#pragma unroll
    for (int i = 0; i < 3; i++) {
        int d = threadIdx.x + i * 256;
        float r = (vals[i] - mu) * rstd * g[d] + beta[d];
        out[t * DMODEL + d] = r;
        outb[t * DMODEL + d] = f2bs(r);
    }
}

// ---------------- masked softmax (in-place f32, + bf16 copy) --------------
__global__ __launch_bounds__(256) void softmax_kernel(
    float* __restrict__ attn, const int* __restrict__ amask, u16* __restrict__ pb)
{
    __shared__ float red[4];
    long row = blockIdx.x;                 // b*H*S + h*S + q
    int b = (int)(row / (NHEAD * SLEN));
    float* p = attn + row * SLEN;
    u16* pbp = pb + row * SLEN;
    const int* m = amask + (long)b * SLEN;
    int tid = threadIdx.x;
    float v0 = m[tid]       ? p[tid]       : -1e30f;
    float v1 = m[tid + 256] ? p[tid + 256] : -1e30f;
    float mx = block_max256(fmaxf(v0, v1), red);
    float e0 = expf(v0 - mx), e1 = expf(v1 - mx);
    float sum = block_sum256(e0 + e1, red);
    float inv = 1.0f / sum;
    float r0 = e0 * inv, r1 = e1 * inv;
    p[tid]         = r0;
    p[tid + 256]   = r1;
    pbp[tid]       = f2bs(r0);
    pbp[tid + 256] = f2bs(r1);
}

// ---------------- transpose-convert f32 [K][N] -> bf16 [N][K] ------------
__global__ __launch_bounds__(256) void convT_kernel(
    const float* __restrict__ src, int K, int N, u16* __restrict__ dst)
{
    __shared__ float t[32][33];
    int n0 = blockIdx.x * 32, k0 = blockIdx.y * 32;
    int tx = threadIdx.x & 31, ty = threadIdx.x >> 5;
#pragma unroll
    for (int i = 0; i < 32; i += 8) {
        int k = k0 + ty + i, n = n0 + tx;
        t[ty + i][tx] = (k < K && n < N) ? src[(long)k * N + n] : 0.f;
    }
    __syncthreads();
#pragma unroll
    for (int i = 0; i < 32; i += 8) {
        int n = n0 + ty + i, k = k0 + tx;
        if (n < N && k < K) dst[(long)n * K + k] = f2bs(t[tx][ty + i]);
    }
}

// ---------------- V transpose (bf16): qkv[b,s,2304] v-part -> vt[b,h,hd,s] --
__global__ __launch_bounds__(256) void transpose_v_kernel(
    const u16* __restrict__ qkv, u16* __restrict__ vt)
{
    __shared__ u16 t[64][65];
    int s0 = blockIdx.x * 64;
    int z = blockIdx.y;                   // b*H + h
    int b = z / NHEAD, h = z - b * NHEAD;
    const u16* src = qkv + (long)b * SLEN * (3 * DMODEL) + 2 * DMODEL + h * HDIM;
    int tx = threadIdx.x & 63, ty = threadIdx.x >> 6;   // tx: hd or s; ty: 0..3
#pragma unroll
    for (int i = 0; i < 64; i += 4)
        t[ty + i][tx] = src[(long)(s0 + ty + i) * (3 * DMODEL) + tx];
    __syncthreads();
    u16* dst = vt + (long)z * HDIM * SLEN + s0;
#pragma unroll
    for (int i = 0; i < 64; i += 4)
        dst[(long)(ty + i) * SLEN + tx] = t[tx][ty + i];
}

// ---------------- bf16 MFMA GEMM, m97 structure -------------------------
// C[z] = epi( scale * A[z] @ B[z]^T + bias ),  A:[M][K] bf16, B:[N][K] bf16
// OUTBF=0: C f32.  OUTBF=1: C bf16.  GELU applies exact erf GELU.
template<int BM, int BN, int OUTBF, int GELU>
__global__ __launch_bounds__(256) void gemm_bf16(
    const u16* __restrict__ A, int lda, long sA1, long sA2,
    const u16* __restrict__ B, int ldb, long sB1, long sB2,
    void* __restrict__ Cv, int ldc, long sC1, long sC2,
    int zdiv, const float* __restrict__ bias,
    int N, int K, float scale)
{
    __shared__ u16 As[BM][32];
    __shared__ u16 Bs[BN][32];
    int z = blockIdx.z;
    int zq = z / zdiv, zr = z - zq * zdiv;
    A += zq * sA1 + zr * sA2;
    B += zq * sB1 + zr * sB2;

    int m0 = blockIdx.y * BM;
    int n0 = blockIdx.x * BN;
    int tid = threadIdx.x;
    int wave = tid >> 6, lane = tid & 63;
    int quad = lane >> 4, l16 = lane & 15;
    int wr = wave >> 1, wc = wave & 1;
    constexpr int MR = BM / 32, NR = BN / 32;

    f32x4 acc[MR][NR];
#pragma unroll
    for (int i = 0; i < MR; i++)
#pragma unroll
        for (int j = 0; j < NR; j++) acc[i][j] = (f32x4){0.f, 0.f, 0.f, 0.f};

    int srow = lane >> 2;          // 0..15
    int scol = (lane & 3) * 8;     // 0,8,16,24

    for (int k0 = 0; k0 < K; k0 += 32) {
        __syncthreads();
#pragma unroll
        for (int i = 0; i < BM / 64; i++) {
            int chunk = wave * (BM / 64) + i;
            int row = chunk * 16 + srow;
            gload_lds16(A + (long)(m0 + row) * lda + k0 + scol, &As[chunk * 16][0]);
        }
#pragma unroll
        for (int i = 0; i < BN / 64; i++) {
            int chunk = wave * (BN / 64) + i;
            int row = n0 + chunk * 16 + srow;
            if (row > N - 1) row = N - 1;   // tail: duplicate reads, masked in epilogue
            gload_lds16(B + (long)row * ldb + k0 + scol, &Bs[chunk * 16][0]);
        }
        __syncthreads();

        bf16x8 afr[MR], bfr[NR];
#pragma unroll
        for (int i = 0; i < MR; i++)
            afr[i] = *reinterpret_cast<const bf16x8*>(&As[wr * (BM / 2) + i * 16 + l16][quad * 8]);
#pragma unroll
        for (int j = 0; j < NR; j++)
            bfr[j] = *reinterpret_cast<const bf16x8*>(&Bs[wc * (BN / 2) + j * 16 + l16][quad * 8]);
#pragma unroll
        for (int i = 0; i < MR; i++)
#pragma unroll
            for (int j = 0; j < NR; j++)
                acc[i][j] = __builtin_amdgcn_mfma_f32_16x16x32_bf16(afr[i], bfr[j], acc[i][j], 0, 0, 0);
    }

    float* Cf = (float*)Cv;
    u16*   Cb = (u16*)Cv;
    long coff = zq * sC1 + zr * sC2;
#pragma unroll
    for (int i = 0; i < MR; i++) {
        int rbase = m0 + wr * (BM / 2) + i * 16 + quad * 4;
#pragma unroll
        for (int j = 0; j < NR; j++) {
            int col = n0 + wc * (BN / 2) + j * 16 + l16;
            if (col < N) {
                float badd = bias ? bias[col] : 0.f;
#pragma unroll
                for (int r = 0; r < 4; r++) {
                    float vv = acc[i][j][r] * scale + badd;
                    if (GELU) vv = 0.5f * vv * (1.0f + erff(vv * 0.70710678118f));
                    long idx = coff + (long)(rbase + r) * ldc + col;
                    if (OUTBF) Cb[idx] = f2bs(vv);
                    else       Cf[idx] = vv;
                }
            }
        }
    }
}

template<int BM, int BN, int OUTBF, int GELU>
static inline void launch_gemm(hipStream_t stream,
    const u16* A, int lda, long sA1, long sA2,
    const u16* B, int ldb, long sB1, long sB2,
    void* C, int ldc, long sC1, long sC2,
    int zdiv, const float* bias, int M, int N, int K, float scale, int Z)
{
    dim3 grid((N + BN - 1) / BN, M / BM, Z);
    gemm_bf16<BM, BN, OUTBF, GELU><<<grid, 256, 0, stream>>>(
        A, lda, sA1, sA2, B, ldb, sB1, sB2, C, ldc, sC1, sC2,
        zdiv, bias, N, K, scale);
}

// ---------------- driver ----------------
extern "C" void kernel_launch(void* const* d_in, const int* in_sizes, int n_in,
                              void* d_out, int out_size, void* d_ws, size_t ws_size,
                              hipStream_t stream)
{
    const int*   ids   = (const int*)d_in[0];
    const int*   amask = (const int*)d_in[1];
    const float* word  = (const float*)d_in[2];
    const float* pos   = (const float*)d_in[3];
    const float* seg   = (const float*)d_in[4];
    const float* eg    = (const float*)d_in[5];
    const float* eb    = (const float*)d_in[6];
    const float* Wq    = (const float*)d_in[7];
    const float* Wk    = (const float*)d_in[8];
    const float* Wv    = (const float*)d_in[9];
    const float* Wo    = (const float*)d_in[10];
    const float* F1w   = (const float*)d_in[11];
    const float* F1b   = (const float*)d_in[12];
    const float* F2w   = (const float*)d_in[13];
    const float* F2b   = (const float*)d_in[14];
    const float* G1    = (const float*)d_in[15];
    const float* B1    = (const float*)d_in[16];
    const float* G2    = (const float*)d_in[17];
    const float* B2    = (const float*)d_in[18];
    const float* OutW  = (const float*)d_in[19];
    const float* OutB  = (const float*)d_in[20];

    float* logits = (float*)d_out;
    float* attn_base = logits + (long)NTOK * VOCAB;

    long nd = (long)NTOK * DMODEL;
    // f32 region
    float* x  = (float*)d_ws;          // NTOK x D
    float* x1 = x + nd;                // NTOK x D
    float* o2 = x1 + nd;               // NTOK x D  (h2 aliases o2)
    float* h2 = o2;
    // bf16 region
    u16* xb   = (u16*)(o2 + nd);                       // NTOK x D
    u16* x1b  = xb + nd;                               // NTOK x D
    u16* qkvb = x1b + nd;                              // NTOK x 3D
    u16* vtb  = qkvb + (long)NTOK * 3 * DMODEL;        // B*H x HD x S == nd
    u16* ob   = vtb + nd;                              // NTOK x D
    u16* pb   = ob + nd;                               // B*H x S x S
    u16* hb   = pb;                                    // alias: NTOK x F  (pb dead when FF1 runs)
    u16* wT   = pb + (long)NBATCH * NHEAD * SLEN * SLEN;
    u16* qkvT = wT;                                    // [3D][D]
    u16* woT  = qkvT + (long)3 * DMODEL * DMODEL;      // [D][D]
    u16* f1T  = woT + (long)DMODEL * DMODEL;           // [F][D]
    u16* f2T  = f1T + (long)FDIM * DMODEL;             // [D][F]
    u16* owT  = qkvb;   // alias over layer scratch (used only after the loop)

    const float scoreScale = 0.036084391824351615f;    // 1/sqrt(768)

    embed_ln_kernel<<<NTOK, 256, 0, stream>>>(ids, word, pos, seg, eg, eb, x, xb);

    for (int l = 0; l < NLAYER; l++) {
        const float* wq  = Wq  + (long)l * DMODEL * DMODEL;
        const float* wk  = Wk  + (long)l * DMODEL * DMODEL;
        const float* wv  = Wv  + (long)l * DMODEL * DMODEL;
        const float* wo  = Wo  + (long)l * DMODEL * DMODEL;
        const float* f1w = F1w + (long)l * DMODEL * FDIM;
        const float* f1b = F1b + (long)l * FDIM;
        const float* f2w = F2w + (long)l * FDIM * DMODEL;
        const float* f2b = F2b + (long)l * DMODEL;
        float* attn_l = attn_base + (long)l * NBATCH * NHEAD * SLEN * SLEN;

        // transpose-convert this layer's weights to bf16 [N][K]
        convT_kernel<<<dim3(24, 24), 256, 0, stream>>>(wq, DMODEL, DMODEL, qkvT);
        convT_kernel<<<dim3(24, 24), 256, 0, stream>>>(wk, DMODEL, DMODEL, qkvT + (long)DMODEL * DMODEL);
        convT_kernel<<<dim3(24, 24), 256, 0, stream>>>(wv, DMODEL, DMODEL, qkvT + (long)2 * DMODEL * DMODEL);
        convT_kernel<<<dim3(24, 24), 256, 0, stream>>>(wo, DMODEL, DMODEL, woT);
        convT_kernel<<<dim3(96, 24), 256, 0, stream>>>(f1w, DMODEL, FDIM, f1T);
        convT_kernel<<<dim3(24, 96), 256, 0, stream>>>(f2w, FDIM, DMODEL, f2T);

        // fused QKV: [NTOK,768] @ [768,2304] -> qkvb bf16 [NTOK,2304]
        launch_gemm<128, 128, 1, 0>(stream, xb, DMODEL, 0, 0,
                                    qkvT, DMODEL, 0, 0,
                                    qkvb, 3 * DMODEL, 0, 0,
                                    1, nullptr, NTOK, 3 * DMODEL, DMODEL, 1.f, 1);

        transpose_v_kernel<<<dim3(SLEN / 64, NBATCH * NHEAD), 256, 0, stream>>>(qkvb, vtb);

        // scores = scale * Q K^T  per (b,h) -> attn_l f32
        launch_gemm<128, 128, 0, 0>(stream,
            qkvb,              3 * DMODEL, (long)SLEN * 3 * DMODEL, HDIM,
            qkvb + DMODEL,     3 * DMODEL, (long)SLEN * 3 * DMODEL, HDIM,
            attn_l, SLEN, (long)NHEAD * SLEN * SLEN, (long)SLEN * SLEN,
            NHEAD, nullptr, SLEN, SLEN, HDIM, scoreScale, NBATCH * NHEAD);

        softmax_kernel<<<NBATCH * NHEAD * SLEN, 256, 0, stream>>>(attn_l, amask, pb);

        // o = P @ V  per (b,h)  -> ob bf16 [NTOK, D]
        launch_gemm<64, 64, 1, 0>(stream,
            pb,  SLEN, (long)NHEAD * SLEN * SLEN, (long)SLEN * SLEN,
            vtb, SLEN, (long)NHEAD * HDIM * SLEN, (long)HDIM * SLEN,
            ob, DMODEL, (long)SLEN * DMODEL, HDIM,
            NHEAD, nullptr, SLEN, HDIM, SLEN, 1.f, NBATCH * NHEAD);

        // o2 = o @ Wo  (f32)
        launch_gemm<64, 64, 0, 0>(stream, ob, DMODEL, 0, 0,
                                  woT, DMODEL, 0, 0,
                                  o2, DMODEL, 0, 0,
                                  1, nullptr, NTOK, DMODEL, DMODEL, 1.f, 1);

        ln_res_kernel<<<NTOK, 256, 0, stream>>>(x, o2, G1 + (long)l * DMODEL, B1 + (long)l * DMODEL, x1, x1b);

        // h = gelu(x1 @ f1w + f1b)  -> hb bf16
        launch_gemm<128, 128, 1, 1>(stream, x1b, DMODEL, 0, 0,
                                    f1T, DMODEL, 0, 0,
                                    hb, FDIM, 0, 0,
                                    1, f1b, NTOK, FDIM, DMODEL, 1.f, 1);
        // h2 = h @ f2w + f2b  (f32)
        launch_gemm<64, 64, 0, 0>(stream, hb, FDIM, 0, 0,
                                  f2T, FDIM, 0, 0,
                                  h2, DMODEL, 0, 0,
                                  1, f2b, NTOK, DMODEL, FDIM, 1.f, 1);

        ln_res_kernel<<<NTOK, 256, 0, stream>>>(x1, h2, G2 + (long)l * DMODEL, B2 + (long)l * DMODEL, x, xb);
    }

    // logits = x @ out_w + out_b
    convT_kernel<<<dim3((VOCAB + 31) / 32, 24), 256, 0, stream>>>(OutW, DMODEL, VOCAB, owT);
    launch_gemm<128, 128, 0, 0>(stream, xb, DMODEL, 0, 0,
                                owT, DMODEL, 0, 0,
                                logits, VOCAB, 0, 0,
                                1, OutB, NTOK, VOCAB, DMODEL, 1.f, 1);
}

// Round 2
// 2771.006 us; speedup vs baseline: 3.7667x; 1.0055x over previous
//
#include <hip/hip_runtime.h>
#include <hip/hip_bf16.h>

#define NLAYER 12
#define DMODEL 768
#define NHEAD  12
#define HDIM   64
#define FDIM   3072
#define VOCAB  30522
#define SLEN   512
#define NBATCH 4
#define NTOK   (NBATCH*SLEN)
#define EPSLN  1e-5f

typedef unsigned short u16;
using bf16 = __hip_bfloat16;
typedef __bf16 bf16x8 __attribute__((ext_vector_type(8)));
typedef float  f32x4  __attribute__((ext_vector_type(4)));

__device__ __forceinline__ u16 f2bs(float f) {
    bf16 h = __float2bfloat16(f);
    return *reinterpret_cast<u16*>(&h);
}

// async global->LDS, 16B per lane. LDS dest = wave-uniform base + lane*16.
__device__ __forceinline__ void gload_lds16(const void* g, void* l) {
    auto gp = (const __attribute__((address_space(1))) unsigned int*)g;
    auto lp = (__attribute__((address_space(3))) unsigned int*)(unsigned long long)l;
    __builtin_amdgcn_global_load_lds(gp, lp, 16, 0, 0);
}

// ---------------- reductions ----------------
__device__ __forceinline__ float wave_sum64(float v) {
#pragma unroll
    for (int off = 32; off > 0; off >>= 1) v += __shfl_down(v, off, 64);
    return v;
}
__device__ __forceinline__ float block_sum256(float v, float* red) {
    v = wave_sum64(v);
    __syncthreads();
    if ((threadIdx.x & 63) == 0) red[threadIdx.x >> 6] = v;
    __syncthreads();
    return red[0] + red[1] + red[2] + red[3];
}

// ---------------- embedding + LN (writes f32 + bf16) ----------------
__global__ __launch_bounds__(256) void embed_ln_kernel(
    const int* __restrict__ ids, const float* __restrict__ word,
    const float* __restrict__ pos, const float* __restrict__ seg,
    const float* __restrict__ g, const float* __restrict__ b,
    float* __restrict__ out, u16* __restrict__ outb)
{
    __shared__ float red[4];
    int t = blockIdx.x;
    int s = t & (SLEN - 1);
    long woff = (long)ids[t] * DMODEL;
    float vals[3];
#pragma unroll
    for (int i = 0; i < 3; i++) {
        int d = threadIdx.x + i * 256;
        vals[i] = word[woff + d] + pos[(long)s * DMODEL + d] + seg[d];
    }
    float mu = block_sum256(vals[0] + vals[1] + vals[2], red) * (1.0f / DMODEL);
    float vv = 0.f;
#pragma unroll
    for (int i = 0; i < 3; i++) { float d0 = vals[i] - mu; vv += d0 * d0; }
    float rstd = rsqrtf(block_sum256(vv, red) * (1.0f / DMODEL) + EPSLN);
#pragma unroll
    for (int i = 0; i < 3; i++) {
        int d = threadIdx.x + i * 256;
        float r = (vals[i] - mu) * rstd * g[d] + b[d];
        out[(long)t * DMODEL + d] = r;
        outb[(long)t * DMODEL + d] = f2bs(r);
    }
}

// ---------------- residual + LN (writes f32 + bf16) ----------------
__global__ __launch_bounds__(256) void ln_res_kernel(
    const float* __restrict__ a, const float* __restrict__ bres,
    const float* __restrict__ g, const float* __restrict__ beta,
    float* __restrict__ out, u16* __restrict__ outb)
{
    __shared__ float red[4];
    long t = blockIdx.x;
    float vals[3];
#pragma unroll
    for (int i = 0; i < 3; i++) {
        int d = threadIdx.x + i * 256;
        vals[i] = a[t * DMODEL + d] + bres[t * DMODEL + d];
    }
    float mu = block_sum256(vals[0] + vals[1] + vals[2], red) * (1.0f / DMODEL);
    float vv = 0.f;
#pragma unroll
    for (int i = 0; i < 3; i++) { float d0 = vals[i] - mu; vv += d0 * d0; }
    float rstd = rsqrtf(block_sum256(vv, red) * (1.0f / DMODEL) + EPSLN);
#pragma unroll
    for (int i = 0; i < 3; i++) {
        int d = threadIdx.x + i * 256;
        float r = (vals[i] - mu) * rstd * g[d] + beta[d];
        out[t * DMODEL + d] = r;
        outb[t * DMODEL + d] = f2bs(r);
    }
}

// ---------------- all-weights transpose-convert, ONE launch ----------------
// src f32 [K][N] -> dst bf16 [N][K]
#define DD (DMODEL*DMODEL)
#define DF (DMODEL*FDIM)
#define LAYER_W_ELEMS (4*DD + 2*DF)
#define TILES_DD 576                       // 24*24
#define TILES_DF 2304                      // 96*24
#define TILES_LAYER (4*TILES_DD + 2*TILES_DF)
#define TILES_ALL (NLAYER*TILES_LAYER)
#define NTX_OW ((VOCAB + 31) / 32)         // 954
#define TILES_OW (NTX_OW * (DMODEL/32))    // 22896

__global__ __launch_bounds__(256) void conv_all_kernel(
    const float* __restrict__ Wq, const float* __restrict__ Wk,
    const float* __restrict__ Wv, const float* __restrict__ Wo,
    const float* __restrict__ F1w, const float* __restrict__ F2w,
    const float* __restrict__ OutW, u16* __restrict__ wT, u16* __restrict__ owT)
{
    __shared__ float t[32][33];
    int id = blockIdx.x;
    const float* src; u16* dst; int K, N, tt;
    if (id < TILES_ALL) {
        int l = id / TILES_LAYER, r = id - l * TILES_LAYER;
        u16* base = wT + (long)l * LAYER_W_ELEMS;
        if (r < TILES_DD)           { src = Wq  + (long)l * DD; dst = base;            K = DMODEL; N = DMODEL; tt = r; }
        else if (r < 2 * TILES_DD)  { src = Wk  + (long)l * DD; dst = base + DD;       K = DMODEL; N = DMODEL; tt = r - TILES_DD; }
        else if (r < 3 * TILES_DD)  { src = Wv  + (long)l * DD; dst = base + 2 * DD;   K = DMODEL; N = DMODEL; tt = r - 2 * TILES_DD; }
        else if (r < 4 * TILES_DD)  { src = Wo  + (long)l * DD; dst = base + 3 * DD;   K = DMODEL; N = DMODEL; tt = r - 3 * TILES_DD; }
        else if (r < 4 * TILES_DD + TILES_DF)
                                    { src = F1w + (long)l * DF; dst = base + 4 * DD;   K = DMODEL; N = FDIM;   tt = r - 4 * TILES_DD; }
        else                        { src = F2w + (long)l * DF; dst = base + 4 * DD + DF; K = FDIM; N = DMODEL; tt = r - 4 * TILES_DD - TILES_DF; }
    } else {
        src = OutW; dst = owT; K = DMODEL; N = VOCAB; tt = id - TILES_ALL;
    }
    int ntx = (N + 31) >> 5;
    int n0 = (tt % ntx) * 32, k0 = (tt / ntx) * 32;
    int tx = threadIdx.x & 31, ty = threadIdx.x >> 5;
#pragma unroll
    for (int i = 0; i < 32; i += 8) {
        int k = k0 + ty + i, n = n0 + tx;
        t[ty + i][tx] = (k < K && n < N) ? src[(long)k * N + n] : 0.f;
    }
    __syncthreads();
#pragma unroll
    for (int i = 0; i < 32; i += 8) {
        int n = n0 + ty + i, k = k0 + tx;
        if (n < N && k < K) dst[(long)n * K + k] = f2bs(t[tx][ty + i]);
    }
}

// ---------------- V transpose (bf16): qkv v-part -> vt[b,h,hd,s] ----------
__global__ __launch_bounds__(256) void transpose_v_kernel(
    const u16* __restrict__ qkv, u16* __restrict__ vt)
{
    __shared__ u16 t[64][65];
    int s0 = blockIdx.x * 64;
    int z = blockIdx.y;                   // b*H + h
    int b = z / NHEAD, h = z - b * NHEAD;
    const u16* src = qkv + (long)b * SLEN * (3 * DMODEL) + 2 * DMODEL + h * HDIM;
    int tx = threadIdx.x & 63, ty = threadIdx.x >> 6;
#pragma unroll
    for (int i = 0; i < 64; i += 4)
        t[ty + i][tx] = src[(long)(s0 + ty + i) * (3 * DMODEL) + tx];
    __syncthreads();
    u16* dst = vt + (long)z * HDIM * SLEN + s0;
#pragma unroll
    for (int i = 0; i < 64; i += 4)
        dst[(long)(ty + i) * SLEN + tx] = t[tx][ty + i];
}

// ---------------- fused QK^T + mask + softmax ----------------------------
// grid (S/64, B*H).  4 waves; wave w owns cols [w*128, w*128+128) of all 64 rows.
// Writes probs f32 (attn output) + bf16 (pb for PV).
__global__ __launch_bounds__(256, 2) void attn_kernel(
    const u16* __restrict__ qkvb, const int* __restrict__ amask,
    float* __restrict__ attn, u16* __restrict__ pb)
{
    __shared__ u16 Qs[64][64];
    __shared__ u16 Ks[SLEN][64];
    __shared__ float maskadd[SLEN];
    __shared__ __align__(16) float redA[64][4];
    __shared__ __align__(16) float redB[64][4];

    int z = blockIdx.y;
    int b = z / NHEAD, h = z - b * NHEAD;
    int m0 = blockIdx.x * 64;
    int tid = threadIdx.x;
    int wave = tid >> 6, lane = tid & 63;
    int quad = lane >> 4, l16 = lane & 15;
    const float scale = 0.036084391824351615f;   // 1/sqrt(768)

    for (int i = tid; i < SLEN; i += 256)
        maskadd[i] = amask[b * SLEN + i] ? 0.f : -1e30f;

    const u16* Qbase = qkvb + (long)(b * SLEN) * (3 * DMODEL) + h * HDIM;
    const u16* Kbase = Qbase + DMODEL;

    // stage Q (8KB): pre-swizzled source so LDS slot (row,c) holds chunk c^(row&7)
#pragma unroll
    for (int i = 0; i < 2; i++) {
        int off = wave * 2048 + i * 1024 + lane * 16;
        int row = off >> 7;
        int c = (off >> 4) & 7;
        int g = c ^ (row & 7);
        gload_lds16(Qbase + (long)(m0 + row) * (3 * DMODEL) + g * 8,
                    (char*)&Qs[0][0] + wave * 2048 + i * 1024);
    }
    // stage K (64KB)
#pragma unroll
    for (int i = 0; i < 16; i++) {
        int off = wave * 16384 + i * 1024 + lane * 16;
        int row = off >> 7;
        int c = (off >> 4) & 7;
        int g = c ^ (row & 7);
        gload_lds16(Kbase + (long)row * (3 * DMODEL) + g * 8,
                    (char*)&Ks[0][0] + wave * 16384 + i * 1024);
    }
    __syncthreads();

    f32x4 acc[4][8];
#pragma unroll
    for (int i = 0; i < 4; i++)
#pragma unroll
        for (int j = 0; j < 8; j++) acc[i][j] = (f32x4){0.f, 0.f, 0.f, 0.f};

#pragma unroll
    for (int ks = 0; ks < 2; ks++) {
        bf16x8 afr[4], bfr[8];
#pragma unroll
        for (int i = 0; i < 4; i++) {
            int row = i * 16 + l16;
            int slot = ((ks << 2) + quad) ^ (row & 7);
            afr[i] = *reinterpret_cast<const bf16x8*>((char*)&Qs[0][0] + row * 128 + slot * 16);
        }
#pragma unroll
        for (int j = 0; j < 8; j++) {
            int row = wave * 128 + j * 16 + l16;
            int slot = ((ks << 2) + quad) ^ (row & 7);
            bfr[j] = *reinterpret_cast<const bf16x8*>((char*)&Ks[0][0] + row * 128 + slot * 16);
        }
#pragma unroll
        for (int i = 0; i < 4; i++)
#pragma unroll
            for (int j = 0; j < 8; j++)
                acc[i][j] = __builtin_amdgcn_mfma_f32_16x16x32_bf16(afr[i], bfr[j], acc[i][j], 0, 0, 0);
    }

    // mask addends for this lane's 8 col-fragments
    float ma[8];
#pragma unroll
    for (int j = 0; j < 8; j++) ma[j] = maskadd[wave * 128 + j * 16 + l16];

    // per-row max: local over j, then shfl_xor over l16
    float rmax[4][4];
#pragma unroll
    for (int i = 0; i < 4; i++)
#pragma unroll
        for (int r = 0; r < 4; r++) {
            float m = -3e38f;
#pragma unroll
            for (int j = 0; j < 8; j++) m = fmaxf(m, acc[i][j][r] * scale + ma[j]);
            rmax[i][r] = m;
        }
#pragma unroll
    for (int off = 1; off < 16; off <<= 1)
#pragma unroll
        for (int i = 0; i < 4; i++)
#pragma unroll
            for (int r = 0; r < 4; r++)
                rmax[i][r] = fmaxf(rmax[i][r], __shfl_xor(rmax[i][r], off, 64));
    if (l16 == 0) {
#pragma unroll
        for (int i = 0; i < 4; i++)
#pragma unroll
            for (int r = 0; r < 4; r++) redA[i * 16 + quad * 4 + r][wave] = rmax[i][r];
    }
    __syncthreads();
#pragma unroll
    for (int i = 0; i < 4; i++)
#pragma unroll
        for (int r = 0; r < 4; r++) {
            f32x4 v = *reinterpret_cast<const f32x4*>(&redA[i * 16 + quad * 4 + r][0]);
            rmax[i][r] = fmaxf(fmaxf(v[0], v[1]), fmaxf(v[2], v[3]));
        }

    // exp (in place) + per-row sum
    float rsum[4][4];
#pragma unroll
    for (int i = 0; i < 4; i++)
#pragma unroll
        for (int r = 0; r < 4; r++) {
            float s = 0.f;
#pragma unroll
            for (int j = 0; j < 8; j++) {
                float e = expf(acc[i][j][r] * scale + ma[j] - rmax[i][r]);
                acc[i][j][r] = e;
                s += e;
            }
            rsum[i][r] = s;
        }
#pragma unroll
    for (int off = 1; off < 16; off <<= 1)
#pragma unroll
        for (int i = 0; i < 4; i++)
#pragma unroll
            for (int r = 0; r < 4; r++)
                rsum[i][r] += __shfl_xor(rsum[i][r], off, 64);
    if (l16 == 0) {
#pragma unroll
        for (int i = 0; i < 4; i++)
#pragma unroll
            for (int r = 0; r < 4; r++) redB[i * 16 + quad * 4 + r][wave] = rsum[i][r];
    }
    __syncthreads();

    float* ap = attn + (long)z * SLEN * SLEN;
    u16*   pp = pb   + (long)z * SLEN * SLEN;
#pragma unroll
    for (int i = 0; i < 4; i++)
#pragma unroll
        for (int r = 0; r < 4; r++) {
            f32x4 v = *reinterpret_cast<const f32x4*>(&redB[i * 16 + quad * 4 + r][0]);
            float inv = 1.0f / (v[0] + v[1] + v[2] + v[3]);
            long row = m0 + i * 16 + quad * 4 + r;
#pragma unroll
            for (int j = 0; j < 8; j++) {
                int col = wave * 128 + j * 16 + l16;
                float p = acc[i][j][r] * inv;
                ap[row * SLEN + col] = p;
                pp[row * SLEN + col] = f2bs(p);
            }
        }
}

// ---------------- bf16 MFMA GEMM, m97 structure -------------------------
// C[z] = epi( scale * A[z] @ B[z]^T + bias ),  A:[M][K] bf16, B:[N][K] bf16
template<int BM, int BN, int OUTBF, int GELU>
__global__ __launch_bounds__(256) void gemm_bf16(
    const u16* __restrict__ A, int lda, long sA1, long sA2,
    const u16* __restrict__ B, int ldb, long sB1, long sB2,
    void* __restrict__ Cv, int ldc, long sC1, long sC2,
    int zdiv, const float* __restrict__ bias,
    int N, int K, float scale)
{
    __shared__ u16 As[BM][32];
    __shared__ u16 Bs[BN][32];
    int z = blockIdx.z;
    int zq = z / zdiv, zr = z - zq * zdiv;
    A += zq * sA1 + zr * sA2;
    B += zq * sB1 + zr * sB2;

    int m0 = blockIdx.y * BM;
    int n0 = blockIdx.x * BN;
    int tid = threadIdx.x;
    int wave = tid >> 6, lane = tid & 63;
    int quad = lane >> 4, l16 = lane & 15;
    int wr = wave >> 1, wc = wave & 1;
    constexpr int MR = BM / 32, NR = BN / 32;

    f32x4 acc[MR][NR];
#pragma unroll
    for (int i = 0; i < MR; i++)
#pragma unroll
        for (int j = 0; j < NR; j++) acc[i][j] = (f32x4){0.f, 0.f, 0.f, 0.f};

    int srow = lane >> 2;          // 0..15
    int scol = (lane & 3) * 8;     // 0,8,16,24

    for (int k0 = 0; k0 < K; k0 += 32) {
        __syncthreads();
#pragma unroll
        for (int i = 0; i < BM / 64; i++) {
            int chunk = wave * (BM / 64) + i;
            int row = chunk * 16 + srow;
            gload_lds16(A + (long)(m0 + row) * lda + k0 + scol, &As[chunk * 16][0]);
        }
#pragma unroll
        for (int i = 0; i < BN / 64; i++) {
            int chunk = wave * (BN / 64) + i;
            int row = n0 + chunk * 16 + srow;
            if (row > N - 1) row = N - 1;   // tail: duplicate reads, masked in epilogue
            gload_lds16(B + (long)row * ldb + k0 + scol, &Bs[chunk * 16][0]);
        }
        __syncthreads();

        bf16x8 afr[MR], bfr[NR];
#pragma unroll
        for (int i = 0; i < MR; i++)
            afr[i] = *reinterpret_cast<const bf16x8*>(&As[wr * (BM / 2) + i * 16 + l16][quad * 8]);
#pragma unroll
        for (int j = 0; j < NR; j++)
            bfr[j] = *reinterpret_cast<const bf16x8*>(&Bs[wc * (BN / 2) + j * 16 + l16][quad * 8]);
#pragma unroll
        for (int i = 0; i < MR; i++)
#pragma unroll
            for (int j = 0; j < NR; j++)
                acc[i][j] = __builtin_amdgcn_mfma_f32_16x16x32_bf16(afr[i], bfr[j], acc[i][j], 0, 0, 0);
    }

    float* Cf = (float*)Cv;
    u16*   Cb = (u16*)Cv;
    long coff = zq * sC1 + zr * sC2;
#pragma unroll
    for (int i = 0; i < MR; i++) {
        int rbase = m0 + wr * (BM / 2) + i * 16 + quad * 4;
#pragma unroll
        for (int j = 0; j < NR; j++) {
            int col = n0 + wc * (BN / 2) + j * 16 + l16;
            if (col < N) {
                float badd = bias ? bias[col] : 0.f;
#pragma unroll
                for (int r = 0; r < 4; r++) {
                    float vv = acc[i][j][r] * scale + badd;
                    if (GELU) vv = 0.5f * vv * (1.0f + erff(vv * 0.70710678118f));
                    long idx = coff + (long)(rbase + r) * ldc + col;
                    if (OUTBF) Cb[idx] = f2bs(vv);
                    else       Cf[idx] = vv;
                }
            }
        }
    }
}

template<int BM, int BN, int OUTBF, int GELU>
static inline void launch_gemm(hipStream_t stream,
    const u16* A, int lda, long sA1, long sA2,
    const u16* B, int ldb, long sB1, long sB2,
    void* C, int ldc, long sC1, long sC2,
    int zdiv, const float* bias, int M, int N, int K, float scale, int Z)
{
    dim3 grid((N + BN - 1) / BN, M / BM, Z);
    gemm_bf16<BM, BN, OUTBF, GELU><<<grid, 256, 0, stream>>>(
        A, lda, sA1, sA2, B, ldb, sB1, sB2, C, ldc, sC1, sC2,
        zdiv, bias, N, K, scale);
}

// ---------------- driver ----------------
extern "C" void kernel_launch(void* const* d_in, const int* in_sizes, int n_in,
                              void* d_out, int out_size, void* d_ws, size_t ws_size,
                              hipStream_t stream)
{
    const int*   ids   = (const int*)d_in[0];
    const int*   amask = (const int*)d_in[1];
    const float* word  = (const float*)d_in[2];
    const float* pos   = (const float*)d_in[3];
    const float* seg   = (const float*)d_in[4];
    const float* eg    = (const float*)d_in[5];
    const float* eb    = (const float*)d_in[6];
    const float* Wq    = (const float*)d_in[7];
    const float* Wk    = (const float*)d_in[8];
    const float* Wv    = (const float*)d_in[9];
    const float* Wo    = (const float*)d_in[10];
    const float* F1w   = (const float*)d_in[11];
    const float* F1b   = (const float*)d_in[12];
    const float* F2w   = (const float*)d_in[13];
    const float* F2b   = (const float*)d_in[14];
    const float* G1    = (const float*)d_in[15];
    const float* B1    = (const float*)d_in[16];
    const float* G2    = (const float*)d_in[17];
    const float* B2    = (const float*)d_in[18];
    const float* OutW  = (const float*)d_in[19];
    const float* OutB  = (const float*)d_in[20];

    float* logits = (float*)d_out;
    float* attn_base = logits + (long)NTOK * VOCAB;

    long nd = (long)NTOK * DMODEL;
    // f32 region
    float* x  = (float*)d_ws;          // NTOK x D
    float* x1 = x + nd;                // NTOK x D
    float* o2 = x1 + nd;               // NTOK x D  (h2 aliases o2)
    float* h2 = o2;
    // bf16 region
    u16* xb   = (u16*)(o2 + nd);                       // NTOK x D
    u16* x1b  = xb + nd;                               // NTOK x D
    u16* qkvb = x1b + nd;                              // NTOK x 3D
    u16* vtb  = qkvb + (long)NTOK * 3 * DMODEL;        // B*H x HD x S == nd
    u16* ob   = vtb + nd;                              // NTOK x D
    u16* pb   = ob + nd;                               // B*H x S x S
    u16* hb   = pb;                                    // alias: NTOK x F (pb dead when FF1 runs)
    u16* wT   = pb + (long)NBATCH * NHEAD * SLEN * SLEN;   // 12 x LAYER_W_ELEMS
    u16* owT  = wT + (long)NLAYER * LAYER_W_ELEMS;         // [VOCAB][D]

    // ---- convert ALL weights (all layers + out_w) in one launch ----
    conv_all_kernel<<<TILES_ALL + TILES_OW, 256, 0, stream>>>(
        Wq, Wk, Wv, Wo, F1w, F2w, OutW, wT, owT);

    embed_ln_kernel<<<NTOK, 256, 0, stream>>>(ids, word, pos, seg, eg, eb, x, xb);

    for (int l = 0; l < NLAYER; l++) {
        const u16* qkvT = wT + (long)l * LAYER_W_ELEMS;
        const u16* woT  = qkvT + 3 * DD;
        const u16* f1T  = qkvT + 4 * DD;
        const u16* f2T  = qkvT + 4 * DD + DF;
        const float* f1b = F1b + (long)l * FDIM;
        const float* f2b = F2b + (long)l * DMODEL;
        float* attn_l = attn_base + (long)l * NBATCH * NHEAD * SLEN * SLEN;

        // fused QKV: [NTOK,768] @ [768,2304] -> qkvb bf16
        launch_gemm<128, 128, 1, 0>(stream, xb, DMODEL, 0, 0,
                                    qkvT, DMODEL, 0, 0,
                                    qkvb, 3 * DMODEL, 0, 0,
                                    1, nullptr, NTOK, 3 * DMODEL, DMODEL, 1.f, 1);

        transpose_v_kernel<<<dim3(SLEN / 64, NBATCH * NHEAD), 256, 0, stream>>>(qkvb, vtb);

        // fused QK^T + mask + softmax -> attn_l (f32) + pb (bf16)
        attn_kernel<<<dim3(SLEN / 64, NBATCH * NHEAD), 256, 0, stream>>>(
            qkvb, amask, attn_l, pb);

        // o = P @ V  per (b,h)  -> ob bf16 [NTOK, D]
        launch_gemm<128, 64, 1, 0>(stream,
            pb,  SLEN, (long)NHEAD * SLEN * SLEN, (long)SLEN * SLEN,
            vtb, SLEN, (long)NHEAD * HDIM * SLEN, (long)HDIM * SLEN,
            ob, DMODEL, (long)SLEN * DMODEL, HDIM,
            NHEAD, nullptr, SLEN, HDIM, SLEN, 1.f, NBATCH * NHEAD);

        // o2 = o @ Wo  (f32)
        launch_gemm<128, 64, 0, 0>(stream, ob, DMODEL, 0, 0,
                                   woT, DMODEL, 0, 0,
                                   o2, DMODEL, 0, 0,
                                   1, nullptr, NTOK, DMODEL, DMODEL, 1.f, 1);

        ln_res_kernel<<<NTOK, 256, 0, stream>>>(x, o2, G1 + (long)l * DMODEL, B1 + (long)l * DMODEL, x1, x1b);

        // h = gelu(x1 @ f1w + f1b)  -> hb bf16
        launch_gemm<128, 128, 1, 1>(stream, x1b, DMODEL, 0, 0,
                                    f1T, DMODEL, 0, 0,
                                    hb, FDIM, 0, 0,
                                    1, f1b, NTOK, FDIM, DMODEL, 1.f, 1);
        // h2 = h @ f2w + f2b  (f32)
        launch_gemm<128, 64, 0, 0>(stream, hb, FDIM, 0, 0,
                                   f2T, FDIM, 0, 0,
                                   h2, DMODEL, 0, 0,
                                   1, f2b, NTOK, DMODEL, FDIM, 1.f, 1);

        ln_res_kernel<<<NTOK, 256, 0, stream>>>(x1, h2, G2 + (long)l * DMODEL, B2 + (long)l * DMODEL, x, xb);
    }

    // logits = x @ out_w + out_b
    launch_gemm<128, 128, 0, 0>(stream, xb, DMODEL, 0, 0,
                                owT, DMODEL, 0, 0,
                                logits, VOCAB, 0, 0,
                                1, OutB, NTOK, VOCAB, DMODEL, 1.f, 1);
}

// Round 3
// 2262.098 us; speedup vs baseline: 4.6141x; 1.2250x over previous
//
#include <hip/hip_runtime.h>
#include <hip/hip_bf16.h>

#define NLAYER 12
#define DMODEL 768
#define NHEAD  12
#define HDIM   64
#define FDIM   3072
#define VOCAB  30522
#define SLEN   512
#define NBATCH 4
#define NTOK   (NBATCH*SLEN)
#define EPSLN  1e-5f

typedef unsigned short u16;
using bf16 = __hip_bfloat16;
typedef __bf16 bf16x8 __attribute__((ext_vector_type(8)));
typedef float  f32x4  __attribute__((ext_vector_type(4)));

__device__ __forceinline__ u16 f2bs(float f) {
    bf16 h = __float2bfloat16(f);
    return *reinterpret_cast<u16*>(&h);
}

// async global->LDS, 16B per lane. LDS dest = wave-uniform base + lane*16.
__device__ __forceinline__ void gload_lds16(const void* g, void* l) {
    auto gp = (const __attribute__((address_space(1))) unsigned int*)g;
    auto lp = (__attribute__((address_space(3))) unsigned int*)(unsigned long long)l;
    __builtin_amdgcn_global_load_lds(gp, lp, 16, 0, 0);
}

// ---------------- reductions ----------------
__device__ __forceinline__ float wave_sum64(float v) {
#pragma unroll
    for (int off = 32; off > 0; off >>= 1) v += __shfl_down(v, off, 64);
    return v;
}
__device__ __forceinline__ float block_sum256(float v, float* red) {
    v = wave_sum64(v);
    __syncthreads();
    if ((threadIdx.x & 63) == 0) red[threadIdx.x >> 6] = v;
    __syncthreads();
    return red[0] + red[1] + red[2] + red[3];
}

// ---------------- embedding + LN (writes f32 + bf16) ----------------
__global__ __launch_bounds__(256) void embed_ln_kernel(
    const int* __restrict__ ids, const float* __restrict__ word,
    const float* __restrict__ pos, const float* __restrict__ seg,
    const float* __restrict__ g, const float* __restrict__ b,
    float* __restrict__ out, u16* __restrict__ outb)
{
    __shared__ float red[4];
    int t = blockIdx.x;
    int s = t & (SLEN - 1);
    long woff = (long)ids[t] * DMODEL;
    float vals[3];
#pragma unroll
    for (int i = 0; i < 3; i++) {
        int d = threadIdx.x + i * 256;
        vals[i] = word[woff + d] + pos[(long)s * DMODEL + d] + seg[d];
    }
    float mu = block_sum256(vals[0] + vals[1] + vals[2], red) * (1.0f / DMODEL);
    float vv = 0.f;
#pragma unroll
    for (int i = 0; i < 3; i++) { float d0 = vals[i] - mu; vv += d0 * d0; }
    float rstd = rsqrtf(block_sum256(vv, red) * (1.0f / DMODEL) + EPSLN);
#pragma unroll
    for (int i = 0; i < 3; i++) {
        int d = threadIdx.x + i * 256;
        float r = (vals[i] - mu) * rstd * g[d] + b[d];
        out[(long)t * DMODEL + d] = r;
        outb[(long)t * DMODEL + d] = f2bs(r);
    }
}

// ---------------- residual + LN (writes f32 + bf16) ----------------
__global__ __launch_bounds__(256) void ln_res_kernel(
    const float* __restrict__ a, const float* __restrict__ bres,
    const float* __restrict__ g, const float* __restrict__ beta,
    float* __restrict__ out, u16* __restrict__ outb)
{
    __shared__ float red[4];
    long t = blockIdx.x;
    float vals[3];
#pragma unroll
    for (int i = 0; i < 3; i++) {
        int d = threadIdx.x + i * 256;
        vals[i] = a[t * DMODEL + d] + bres[t * DMODEL + d];
    }
    float mu = block_sum256(vals[0] + vals[1] + vals[2], red) * (1.0f / DMODEL);
    float vv = 0.f;
#pragma unroll
    for (int i = 0; i < 3; i++) { float d0 = vals[i] - mu; vv += d0 * d0; }
    float rstd = rsqrtf(block_sum256(vv, red) * (1.0f / DMODEL) + EPSLN);
#pragma unroll
    for (int i = 0; i < 3; i++) {
        int d = threadIdx.x + i * 256;
        float r = (vals[i] - mu) * rstd * g[d] + beta[d];
        out[t * DMODEL + d] = r;
        outb[t * DMODEL + d] = f2bs(r);
    }
}

// ------------- residual + 2 partials + bias + LN (split-K FF2 reduce) -------
__global__ __launch_bounds__(256) void ln_res2_kernel(
    const float* __restrict__ a, const float* __restrict__ p0,
    const float* __restrict__ p1, const float* __restrict__ cbias,
    const float* __restrict__ g, const float* __restrict__ beta,
    float* __restrict__ out, u16* __restrict__ outb)
{
    __shared__ float red[4];
    long t = blockIdx.x;
    float vals[3];
#pragma unroll
    for (int i = 0; i < 3; i++) {
        int d = threadIdx.x + i * 256;
        vals[i] = a[t * DMODEL + d] + p0[t * DMODEL + d] + p1[t * DMODEL + d] + cbias[d];
    }
    float mu = block_sum256(vals[0] + vals[1] + vals[2], red) * (1.0f / DMODEL);
    float vv = 0.f;
#pragma unroll
    for (int i = 0; i < 3; i++) { float d0 = vals[i] - mu; vv += d0 * d0; }
    float rstd = rsqrtf(block_sum256(vv, red) * (1.0f / DMODEL) + EPSLN);
#pragma unroll
    for (int i = 0; i < 3; i++) {
        int d = threadIdx.x + i * 256;
        float r = (vals[i] - mu) * rstd * g[d] + beta[d];
        out[t * DMODEL + d] = r;
        outb[t * DMODEL + d] = f2bs(r);
    }
}

// ---------------- all-weights transpose-convert, ONE launch ----------------
// src f32 [K][N] -> dst bf16 [N][K]
#define DD (DMODEL*DMODEL)
#define DF (DMODEL*FDIM)
#define LAYER_W_ELEMS (4*DD + 2*DF)
#define TILES_DD 576                       // 24*24
#define TILES_DF 2304                      // 96*24
#define TILES_LAYER (4*TILES_DD + 2*TILES_DF)
#define TILES_ALL (NLAYER*TILES_LAYER)
#define NTX_OW ((VOCAB + 31) / 32)         // 954
#define TILES_OW (NTX_OW * (DMODEL/32))    // 22896

__global__ __launch_bounds__(256) void conv_all_kernel(
    const float* __restrict__ Wq, const float* __restrict__ Wk,
    const float* __restrict__ Wv, const float* __restrict__ Wo,
    const float* __restrict__ F1w, const float* __restrict__ F2w,
    const float* __restrict__ OutW, u16* __restrict__ wT, u16* __restrict__ owT)
{
    __shared__ float t[32][33];
    int id = blockIdx.x;
    const float* src; u16* dst; int K, N, tt;
    if (id < TILES_ALL) {
        int l = id / TILES_LAYER, r = id - l * TILES_LAYER;
        u16* base = wT + (long)l * LAYER_W_ELEMS;
        if (r < TILES_DD)           { src = Wq  + (long)l * DD; dst = base;            K = DMODEL; N = DMODEL; tt = r; }
        else if (r < 2 * TILES_DD)  { src = Wk  + (long)l * DD; dst = base + DD;       K = DMODEL; N = DMODEL; tt = r - TILES_DD; }
        else if (r < 3 * TILES_DD)  { src = Wv  + (long)l * DD; dst = base + 2 * DD;   K = DMODEL; N = DMODEL; tt = r - 2 * TILES_DD; }
        else if (r < 4 * TILES_DD)  { src = Wo  + (long)l * DD; dst = base + 3 * DD;   K = DMODEL; N = DMODEL; tt = r - 3 * TILES_DD; }
        else if (r < 4 * TILES_DD + TILES_DF)
                                    { src = F1w + (long)l * DF; dst = base + 4 * DD;   K = DMODEL; N = FDIM;   tt = r - 4 * TILES_DD; }
        else                        { src = F2w + (long)l * DF; dst = base + 4 * DD + DF; K = FDIM; N = DMODEL; tt = r - 4 * TILES_DD - TILES_DF; }
    } else {
        src = OutW; dst = owT; K = DMODEL; N = VOCAB; tt = id - TILES_ALL;
    }
    int ntx = (N + 31) >> 5;
    int n0 = (tt % ntx) * 32, k0 = (tt / ntx) * 32;
    int tx = threadIdx.x & 31, ty = threadIdx.x >> 5;
#pragma unroll
    for (int i = 0; i < 32; i += 8) {
        int k = k0 + ty + i, n = n0 + tx;
        t[ty + i][tx] = (k < K && n < N) ? src[(long)k * N + n] : 0.f;
    }
    __syncthreads();
#pragma unroll
    for (int i = 0; i < 32; i += 8) {
        int n = n0 + ty + i, k = k0 + tx;
        if (n < N && k < K) dst[(long)n * K + k] = f2bs(t[tx][ty + i]);
    }
}

// ---------------- V transpose (bf16): qkv v-part -> vt[b,h,hd,s] ----------
__global__ __launch_bounds__(256) void transpose_v_kernel(
    const u16* __restrict__ qkv, u16* __restrict__ vt)
{
    __shared__ u16 t[64][65];
    int s0 = blockIdx.x * 64;
    int z = blockIdx.y;                   // b*H + h
    int b = z / NHEAD, h = z - b * NHEAD;
    const u16* src = qkv + (long)b * SLEN * (3 * DMODEL) + 2 * DMODEL + h * HDIM;
    int tx = threadIdx.x & 63, ty = threadIdx.x >> 6;
#pragma unroll
    for (int i = 0; i < 64; i += 4)
        t[ty + i][tx] = src[(long)(s0 + ty + i) * (3 * DMODEL) + tx];
    __syncthreads();
    u16* dst = vt + (long)z * HDIM * SLEN + s0;
#pragma unroll
    for (int i = 0; i < 64; i += 4)
        dst[(long)(ty + i) * SLEN + tx] = t[tx][ty + i];
}

// ---------------- fused QK^T + mask + softmax ----------------------------
// grid (S/64, B*H).  4 waves; wave w owns cols [w*128, w*128+128) of all 64 rows.
__global__ __launch_bounds__(256, 2) void attn_kernel(
    const u16* __restrict__ qkvb, const int* __restrict__ amask,
    float* __restrict__ attn, u16* __restrict__ pb)
{
    __shared__ u16 Qs[64][64];
    __shared__ u16 Ks[SLEN][64];
    __shared__ float maskadd[SLEN];
    __shared__ __align__(16) float redA[64][4];
    __shared__ __align__(16) float redB[64][4];

    int z = blockIdx.y;
    int b = z / NHEAD, h = z - b * NHEAD;
    int m0 = blockIdx.x * 64;
    int tid = threadIdx.x;
    int wave = tid >> 6, lane = tid & 63;
    int quad = lane >> 4, l16 = lane & 15;
    const float scale = 0.036084391824351615f;   // 1/sqrt(768)

    for (int i = tid; i < SLEN; i += 256)
        maskadd[i] = amask[b * SLEN + i] ? 0.f : -1e30f;

    const u16* Qbase = qkvb + (long)(b * SLEN) * (3 * DMODEL) + h * HDIM;
    const u16* Kbase = Qbase + DMODEL;

    // stage Q (8KB): pre-swizzled source so LDS slot (row,c) holds chunk c^(row&7)
#pragma unroll
    for (int i = 0; i < 2; i++) {
        int off = wave * 2048 + i * 1024 + lane * 16;
        int row = off >> 7;
        int c = (off >> 4) & 7;
        int g = c ^ (row & 7);
        gload_lds16(Qbase + (long)(m0 + row) * (3 * DMODEL) + g * 8,
                    (char*)&Qs[0][0] + wave * 2048 + i * 1024);
    }
    // stage K (64KB)
#pragma unroll
    for (int i = 0; i < 16; i++) {
        int off = wave * 16384 + i * 1024 + lane * 16;
        int row = off >> 7;
        int c = (off >> 4) & 7;
        int g = c ^ (row & 7);
        gload_lds16(Kbase + (long)row * (3 * DMODEL) + g * 8,
                    (char*)&Ks[0][0] + wave * 16384 + i * 1024);
    }
    __syncthreads();

    f32x4 acc[4][8];
#pragma unroll
    for (int i = 0; i < 4; i++)
#pragma unroll
        for (int j = 0; j < 8; j++) acc[i][j] = (f32x4){0.f, 0.f, 0.f, 0.f};

#pragma unroll
    for (int ks = 0; ks < 2; ks++) {
        bf16x8 afr[4], bfr[8];
#pragma unroll
        for (int i = 0; i < 4; i++) {
            int row = i * 16 + l16;
            int slot = ((ks << 2) + quad) ^ (row & 7);
            afr[i] = *reinterpret_cast<const bf16x8*>((char*)&Qs[0][0] + row * 128 + slot * 16);
        }
#pragma unroll
        for (int j = 0; j < 8; j++) {
            int row = wave * 128 + j * 16 + l16;
            int slot = ((ks << 2) + quad) ^ (row & 7);
            bfr[j] = *reinterpret_cast<const bf16x8*>((char*)&Ks[0][0] + row * 128 + slot * 16);
        }
#pragma unroll
        for (int i = 0; i < 4; i++)
#pragma unroll
            for (int j = 0; j < 8; j++)
                acc[i][j] = __builtin_amdgcn_mfma_f32_16x16x32_bf16(afr[i], bfr[j], acc[i][j], 0, 0, 0);
    }

    float ma[8];
#pragma unroll
    for (int j = 0; j < 8; j++) ma[j] = maskadd[wave * 128 + j * 16 + l16];

    float rmax[4][4];
#pragma unroll
    for (int i = 0; i < 4; i++)
#pragma unroll
        for (int r = 0; r < 4; r++) {
            float m = -3e38f;
#pragma unroll
            for (int j = 0; j < 8; j++) m = fmaxf(m, acc[i][j][r] * scale + ma[j]);
            rmax[i][r] = m;
        }
#pragma unroll
    for (int off = 1; off < 16; off <<= 1)
#pragma unroll
        for (int i = 0; i < 4; i++)
#pragma unroll
            for (int r = 0; r < 4; r++)
                rmax[i][r] = fmaxf(rmax[i][r], __shfl_xor(rmax[i][r], off, 64));
    if (l16 == 0) {
#pragma unroll
        for (int i = 0; i < 4; i++)
#pragma unroll
            for (int r = 0; r < 4; r++) redA[i * 16 + quad * 4 + r][wave] = rmax[i][r];
    }
    __syncthreads();
#pragma unroll
    for (int i = 0; i < 4; i++)
#pragma unroll
        for (int r = 0; r < 4; r++) {
            f32x4 v = *reinterpret_cast<const f32x4*>(&redA[i * 16 + quad * 4 + r][0]);
            rmax[i][r] = fmaxf(fmaxf(v[0], v[1]), fmaxf(v[2], v[3]));
        }

    float rsum[4][4];
#pragma unroll
    for (int i = 0; i < 4; i++)
#pragma unroll
        for (int r = 0; r < 4; r++) {
            float s = 0.f;
#pragma unroll
            for (int j = 0; j < 8; j++) {
                float e = expf(acc[i][j][r] * scale + ma[j] - rmax[i][r]);
                acc[i][j][r] = e;
                s += e;
            }
            rsum[i][r] = s;
        }
#pragma unroll
    for (int off = 1; off < 16; off <<= 1)
#pragma unroll
        for (int i = 0; i < 4; i++)
#pragma unroll
            for (int r = 0; r < 4; r++)
                rsum[i][r] += __shfl_xor(rsum[i][r], off, 64);
    if (l16 == 0) {
#pragma unroll
        for (int i = 0; i < 4; i++)
#pragma unroll
            for (int r = 0; r < 4; r++) redB[i * 16 + quad * 4 + r][wave] = rsum[i][r];
    }
    __syncthreads();

    float* ap = attn + (long)z * SLEN * SLEN;
    u16*   pp = pb   + (long)z * SLEN * SLEN;
#pragma unroll
    for (int i = 0; i < 4; i++)
#pragma unroll
        for (int r = 0; r < 4; r++) {
            f32x4 v = *reinterpret_cast<const f32x4*>(&redB[i * 16 + quad * 4 + r][0]);
            float inv = 1.0f / (v[0] + v[1] + v[2] + v[3]);
            long row = m0 + i * 16 + quad * 4 + r;
#pragma unroll
            for (int j = 0; j < 8; j++) {
                int col = wave * 128 + j * 16 + l16;
                float p = acc[i][j][r] * inv;
                ap[row * SLEN + col] = p;
                pp[row * SLEN + col] = f2bs(p);
            }
        }
}

// ------- bf16 MFMA GEMM, double-buffered 2-phase pipeline (T3-minimum) -----
// C[z] = epi( scale * A[z] @ B[z]^T + bias ),  A:[M][K] bf16, B:[N][K] bf16
template<int BM, int BN, int OUTBF, int GELU>
__global__ __launch_bounds__(256) void gemm_bf16(
    const u16* __restrict__ A, int lda, long sA1, long sA2,
    const u16* __restrict__ B, int ldb, long sB1, long sB2,
    void* __restrict__ Cv, int ldc, long sC1, long sC2,
    int zdiv, const float* __restrict__ bias,
    int N, int K, float scale)
{
    __shared__ u16 As[2][BM][32];
    __shared__ u16 Bs[2][BN][32];
    int z = blockIdx.z;
    int zq = z / zdiv, zr = z - zq * zdiv;
    A += zq * sA1 + zr * sA2;
    B += zq * sB1 + zr * sB2;

    int m0 = blockIdx.y * BM;
    int n0 = blockIdx.x * BN;
    int tid = threadIdx.x;
    int wave = tid >> 6, lane = tid & 63;
    int quad = lane >> 4, l16 = lane & 15;
    int wr = wave >> 1, wc = wave & 1;
    constexpr int MR = BM / 32, NR = BN / 32;

    f32x4 acc[MR][NR];
#pragma unroll
    for (int i = 0; i < MR; i++)
#pragma unroll
        for (int j = 0; j < NR; j++) acc[i][j] = (f32x4){0.f, 0.f, 0.f, 0.f};

    int srow = lane >> 2;          // 0..15
    int scol = (lane & 3) * 8;     // 0,8,16,24

    // per-wave staging row pointers (row component constant across k)
    auto stage = [&](int buf, int k0) {
#pragma unroll
        for (int i = 0; i < BM / 64; i++) {
            int chunk = wave * (BM / 64) + i;
            int row = chunk * 16 + srow;
            gload_lds16(A + (long)(m0 + row) * lda + k0 + scol, &As[buf][chunk * 16][0]);
        }
#pragma unroll
        for (int i = 0; i < BN / 64; i++) {
            int chunk = wave * (BN / 64) + i;
            int row = n0 + chunk * 16 + srow;
            if (row > N - 1) row = N - 1;   // tail: duplicate reads, masked in epilogue
            gload_lds16(B + (long)row * ldb + k0 + scol, &Bs[buf][chunk * 16][0]);
        }
    };

    int nt = K >> 5;
    stage(0, 0);
    __syncthreads();               // drain prologue loads, all waves aligned

    int cur = 0;
    for (int t = 0; t < nt; ++t) {
        if (t + 1 < nt) stage(cur ^ 1, (t + 1) << 5);   // issue next-tile loads FIRST

        bf16x8 afr[MR], bfr[NR];
#pragma unroll
        for (int i = 0; i < MR; i++)
            afr[i] = *reinterpret_cast<const bf16x8*>(&As[cur][wr * (BM / 2) + i * 16 + l16][quad * 8]);
#pragma unroll
        for (int j = 0; j < NR; j++)
            bfr[j] = *reinterpret_cast<const bf16x8*>(&Bs[cur][wc * (BN / 2) + j * 16 + l16][quad * 8]);
#pragma unroll
        for (int i = 0; i < MR; i++)
#pragma unroll
            for (int j = 0; j < NR; j++)
                acc[i][j] = __builtin_amdgcn_mfma_f32_16x16x32_bf16(afr[i], bfr[j], acc[i][j], 0, 0, 0);

        __syncthreads();           // drains vmcnt (next tile ready) + lgkm (reads of cur done)
        cur ^= 1;
    }

    float* Cf = (float*)Cv;
    u16*   Cb = (u16*)Cv;
    long coff = zq * sC1 + zr * sC2;
#pragma unroll
    for (int i = 0; i < MR; i++) {
        int rbase = m0 + wr * (BM / 2) + i * 16 + quad * 4;
#pragma unroll
        for (int j = 0; j < NR; j++) {
            int col = n0 + wc * (BN / 2) + j * 16 + l16;
            if (col < N) {
                float badd = bias ? bias[col] : 0.f;
#pragma unroll
                for (int r = 0; r < 4; r++) {
                    float vv = acc[i][j][r] * scale + badd;
                    if (GELU) vv = 0.5f * vv * (1.0f + erff(vv * 0.70710678118f));
                    long idx = coff + (long)(rbase + r) * ldc + col;
                    if (OUTBF) Cb[idx] = f2bs(vv);
                    else       Cf[idx] = vv;
                }
            }
        }
    }
}

template<int BM, int BN, int OUTBF, int GELU>
static inline void launch_gemm(hipStream_t stream,
    const u16* A, int lda, long sA1, long sA2,
    const u16* B, int ldb, long sB1, long sB2,
    void* C, int ldc, long sC1, long sC2,
    int zdiv, const float* bias, int M, int N, int K, float scale, int Z)
{
    dim3 grid((N + BN - 1) / BN, M / BM, Z);
    gemm_bf16<BM, BN, OUTBF, GELU><<<grid, 256, 0, stream>>>(
        A, lda, sA1, sA2, B, ldb, sB1, sB2, C, ldc, sC1, sC2,
        zdiv, bias, N, K, scale);
}

// ---------------- driver ----------------
extern "C" void kernel_launch(void* const* d_in, const int* in_sizes, int n_in,
                              void* d_out, int out_size, void* d_ws, size_t ws_size,
                              hipStream_t stream)
{
    const int*   ids   = (const int*)d_in[0];
    const int*   amask = (const int*)d_in[1];
    const float* word  = (const float*)d_in[2];
    const float* pos   = (const float*)d_in[3];
    const float* seg   = (const float*)d_in[4];
    const float* eg    = (const float*)d_in[5];
    const float* eb    = (const float*)d_in[6];
    const float* Wq    = (const float*)d_in[7];
    const float* Wk    = (const float*)d_in[8];
    const float* Wv    = (const float*)d_in[9];
    const float* Wo    = (const float*)d_in[10];
    const float* F1w   = (const float*)d_in[11];
    const float* F1b   = (const float*)d_in[12];
    const float* F2w   = (const float*)d_in[13];
    const float* F2b   = (const float*)d_in[14];
    const float* G1    = (const float*)d_in[15];
    const float* B1    = (const float*)d_in[16];
    const float* G2    = (const float*)d_in[17];
    const float* B2    = (const float*)d_in[18];
    const float* OutW  = (const float*)d_in[19];
    const float* OutB  = (const float*)d_in[20];

    float* logits = (float*)d_out;
    float* attn_base = logits + (long)NTOK * VOCAB;

    long nd = (long)NTOK * DMODEL;
    // f32 region
    float* x  = (float*)d_ws;          // NTOK x D
    float* x1 = x + nd;                // NTOK x D
    float* o2 = x1 + nd;               // NTOK x D   (FF2 partial 0 aliases o2)
    float* p0 = o2;
    float* p1 = p0 + nd;               // NTOK x D   (FF2 partial 1)
    // bf16 region
    u16* xb   = (u16*)(p1 + nd);                       // NTOK x D
    u16* x1b  = xb + nd;                               // NTOK x D
    u16* qkvb = x1b + nd;                              // NTOK x 3D
    u16* vtb  = qkvb + (long)NTOK * 3 * DMODEL;        // B*H x HD x S == nd
    u16* ob   = vtb + nd;                              // NTOK x D
    u16* pb   = ob + nd;                               // B*H x S x S
    u16* hb   = pb;                                    // alias: NTOK x F (pb dead when FF1 runs)
    u16* wT   = pb + (long)NBATCH * NHEAD * SLEN * SLEN;   // 12 x LAYER_W_ELEMS
    u16* owT  = wT + (long)NLAYER * LAYER_W_ELEMS;         // [VOCAB][D]

    // ---- convert ALL weights (all layers + out_w) in one launch ----
    conv_all_kernel<<<TILES_ALL + TILES_OW, 256, 0, stream>>>(
        Wq, Wk, Wv, Wo, F1w, F2w, OutW, wT, owT);

    embed_ln_kernel<<<NTOK, 256, 0, stream>>>(ids, word, pos, seg, eg, eb, x, xb);

    for (int l = 0; l < NLAYER; l++) {
        const u16* qkvT = wT + (long)l * LAYER_W_ELEMS;
        const u16* woT  = qkvT + 3 * DD;
        const u16* f1T  = qkvT + 4 * DD;
        const u16* f2T  = qkvT + 4 * DD + DF;
        const float* f1b = F1b + (long)l * FDIM;
        const float* f2b = F2b + (long)l * DMODEL;
        float* attn_l = attn_base + (long)l * NBATCH * NHEAD * SLEN * SLEN;

        // fused QKV: [NTOK,768] @ [768,2304] -> qkvb bf16
        launch_gemm<128, 128, 1, 0>(stream, xb, DMODEL, 0, 0,
                                    qkvT, DMODEL, 0, 0,
                                    qkvb, 3 * DMODEL, 0, 0,
                                    1, nullptr, NTOK, 3 * DMODEL, DMODEL, 1.f, 1);

        transpose_v_kernel<<<dim3(SLEN / 64, NBATCH * NHEAD), 256, 0, stream>>>(qkvb, vtb);

        // fused QK^T + mask + softmax -> attn_l (f32) + pb (bf16)
        attn_kernel<<<dim3(SLEN / 64, NBATCH * NHEAD), 256, 0, stream>>>(
            qkvb, amask, attn_l, pb);

        // o = P @ V  per (b,h)  -> ob bf16 [NTOK, D]
        launch_gemm<128, 64, 1, 0>(stream,
            pb,  SLEN, (long)NHEAD * SLEN * SLEN, (long)SLEN * SLEN,
            vtb, SLEN, (long)NHEAD * HDIM * SLEN, (long)HDIM * SLEN,
            ob, DMODEL, (long)SLEN * DMODEL, HDIM,
            NHEAD, nullptr, SLEN, HDIM, SLEN, 1.f, NBATCH * NHEAD);

        // o2 = o @ Wo  (f32)
        launch_gemm<128, 64, 0, 0>(stream, ob, DMODEL, 0, 0,
                                   woT, DMODEL, 0, 0,
                                   o2, DMODEL, 0, 0,
                                   1, nullptr, NTOK, DMODEL, DMODEL, 1.f, 1);

        ln_res_kernel<<<NTOK, 256, 0, stream>>>(x, o2, G1 + (long)l * DMODEL, B1 + (long)l * DMODEL, x1, x1b);

        // h = gelu(x1 @ f1w + f1b)  -> hb bf16
        launch_gemm<128, 128, 1, 1>(stream, x1b, DMODEL, 0, 0,
                                    f1T, DMODEL, 0, 0,
                                    hb, FDIM, 0, 0,
                                    1, f1b, NTOK, FDIM, DMODEL, 1.f, 1);

        // FF2 split-K=2: partial s covers k in [s*1536, s*1536+1536)
        // A offset: s*1536 elems along row; B offset: s*1536 along row; C -> p0/p1
        launch_gemm<128, 128, 0, 0>(stream, hb, FDIM, 1536, 0,
                                    f2T, FDIM, 1536, 0,
                                    p0, DMODEL, nd, 0,
                                    1, nullptr, NTOK, DMODEL, 1536, 1.f, 2);

        ln_res2_kernel<<<NTOK, 256, 0, stream>>>(x1, p0, p1, f2b,
                                                 G2 + (long)l * DMODEL, B2 + (long)l * DMODEL, x, xb);
    }

    // logits = x @ out_w + out_b
    launch_gemm<128, 128, 0, 0>(stream, xb, DMODEL, 0, 0,
                                owT, DMODEL, 0, 0,
                                logits, VOCAB, 0, 0,
                                1, OutB, NTOK, VOCAB, DMODEL, 1.f, 1);
}

// Round 4
// 2148.268 us; speedup vs baseline: 4.8586x; 1.0530x over previous
//
#include <hip/hip_runtime.h>
#include <hip/hip_bf16.h>

#define NLAYER 12
#define DMODEL 768
#define NHEAD  12
#define HDIM   64
#define FDIM   3072
#define VOCAB  30522
#define SLEN   512
#define NBATCH 4
#define NTOK   (NBATCH*SLEN)
#define EPSLN  1e-5f

typedef unsigned short u16;
using bf16 = __hip_bfloat16;
typedef __bf16 bf16x8 __attribute__((ext_vector_type(8)));
typedef float  f32x4  __attribute__((ext_vector_type(4)));
typedef u16    u16x4  __attribute__((ext_vector_type(4)));

__device__ __forceinline__ u16 f2bs(float f) {
    bf16 h = __float2bfloat16(f);
    return *reinterpret_cast<u16*>(&h);
}

// async global->LDS, 16B per lane. LDS dest = wave-uniform base + lane*16.
__device__ __forceinline__ void gload_lds16(const void* g, void* l) {
    auto gp = (const __attribute__((address_space(1))) unsigned int*)g;
    auto lp = (__attribute__((address_space(3))) unsigned int*)(unsigned long long)l;
    __builtin_amdgcn_global_load_lds(gp, lp, 16, 0, 0);
}

// ---------------- reductions ----------------
__device__ __forceinline__ float wave_sum64(float v) {
#pragma unroll
    for (int off = 32; off > 0; off >>= 1) v += __shfl_down(v, off, 64);
    return v;
}
__device__ __forceinline__ float block_sum256(float v, float* red) {
    v = wave_sum64(v);
    __syncthreads();
    if ((threadIdx.x & 63) == 0) red[threadIdx.x >> 6] = v;
    __syncthreads();
    return red[0] + red[1] + red[2] + red[3];
}

// ---------------- embedding + LN (writes f32 + bf16) ----------------
__global__ __launch_bounds__(256) void embed_ln_kernel(
    const int* __restrict__ ids, const float* __restrict__ word,
    const float* __restrict__ pos, const float* __restrict__ seg,
    const float* __restrict__ g, const float* __restrict__ b,
    float* __restrict__ out, u16* __restrict__ outb)
{
    __shared__ float red[4];
    int t = blockIdx.x;
    int s = t & (SLEN - 1);
    long woff = (long)ids[t] * DMODEL;
    float vals[3];
#pragma unroll
    for (int i = 0; i < 3; i++) {
        int d = threadIdx.x + i * 256;
        vals[i] = word[woff + d] + pos[(long)s * DMODEL + d] + seg[d];
    }
    float mu = block_sum256(vals[0] + vals[1] + vals[2], red) * (1.0f / DMODEL);
    float vv = 0.f;
#pragma unroll
    for (int i = 0; i < 3; i++) { float d0 = vals[i] - mu; vv += d0 * d0; }
    float rstd = rsqrtf(block_sum256(vv, red) * (1.0f / DMODEL) + EPSLN);
#pragma unroll
    for (int i = 0; i < 3; i++) {
        int d = threadIdx.x + i * 256;
        float r = (vals[i] - mu) * rstd * g[d] + b[d];
        out[(long)t * DMODEL + d] = r;
        outb[(long)t * DMODEL + d] = f2bs(r);
    }
}

// ---------------- residual + LN (writes f32 + bf16) ----------------
__global__ __launch_bounds__(256) void ln_res_kernel(
    const float* __restrict__ a, const float* __restrict__ bres,
    const float* __restrict__ g, const float* __restrict__ beta,
    float* __restrict__ out, u16* __restrict__ outb)
{
    __shared__ float red[4];
    long t = blockIdx.x;
    float vals[3];
#pragma unroll
    for (int i = 0; i < 3; i++) {
        int d = threadIdx.x + i * 256;
        vals[i] = a[t * DMODEL + d] + bres[t * DMODEL + d];
    }
    float mu = block_sum256(vals[0] + vals[1] + vals[2], red) * (1.0f / DMODEL);
    float vv = 0.f;
#pragma unroll
    for (int i = 0; i < 3; i++) { float d0 = vals[i] - mu; vv += d0 * d0; }
    float rstd = rsqrtf(block_sum256(vv, red) * (1.0f / DMODEL) + EPSLN);
#pragma unroll
    for (int i = 0; i < 3; i++) {
        int d = threadIdx.x + i * 256;
        float r = (vals[i] - mu) * rstd * g[d] + beta[d];
        out[t * DMODEL + d] = r;
        outb[t * DMODEL + d] = f2bs(r);
    }
}

// ------------- residual + 2 partials + bias + LN (split-K FF2 reduce) -------
__global__ __launch_bounds__(256) void ln_res2_kernel(
    const float* __restrict__ a, const float* __restrict__ p0,
    const float* __restrict__ p1, const float* __restrict__ cbias,
    const float* __restrict__ g, const float* __restrict__ beta,
    float* __restrict__ out, u16* __restrict__ outb)
{
    __shared__ float red[4];
    long t = blockIdx.x;
    float vals[3];
#pragma unroll
    for (int i = 0; i < 3; i++) {
        int d = threadIdx.x + i * 256;
        vals[i] = a[t * DMODEL + d] + p0[t * DMODEL + d] + p1[t * DMODEL + d] + cbias[d];
    }
    float mu = block_sum256(vals[0] + vals[1] + vals[2], red) * (1.0f / DMODEL);
    float vv = 0.f;
#pragma unroll
    for (int i = 0; i < 3; i++) { float d0 = vals[i] - mu; vv += d0 * d0; }
    float rstd = rsqrtf(block_sum256(vv, red) * (1.0f / DMODEL) + EPSLN);
#pragma unroll
    for (int i = 0; i < 3; i++) {
        int d = threadIdx.x + i * 256;
        float r = (vals[i] - mu) * rstd * g[d] + beta[d];
        out[t * DMODEL + d] = r;
        outb[t * DMODEL + d] = f2bs(r);
    }
}

// ---------------- all-weights transpose-convert, ONE launch ----------------
// src f32 [K][N] -> dst bf16 [N][K]
#define DD (DMODEL*DMODEL)
#define DF (DMODEL*FDIM)
#define LAYER_W_ELEMS (4*DD + 2*DF)
#define TILES_DD 576                       // 24*24
#define TILES_DF 2304                      // 96*24
#define TILES_LAYER (4*TILES_DD + 2*TILES_DF)
#define TILES_ALL (NLAYER*TILES_LAYER)
#define NTX_OW ((VOCAB + 31) / 32)         // 954
#define TILES_OW (NTX_OW * (DMODEL/32))    // 22896

__global__ __launch_bounds__(256) void conv_all_kernel(
    const float* __restrict__ Wq, const float* __restrict__ Wk,
    const float* __restrict__ Wv, const float* __restrict__ Wo,
    const float* __restrict__ F1w, const float* __restrict__ F2w,
    const float* __restrict__ OutW, u16* __restrict__ wT, u16* __restrict__ owT)
{
    __shared__ float t[32][33];
    int id = blockIdx.x;
    const float* src; u16* dst; int K, N, tt;
    if (id < TILES_ALL) {
        int l = id / TILES_LAYER, r = id - l * TILES_LAYER;
        u16* base = wT + (long)l * LAYER_W_ELEMS;
        if (r < TILES_DD)           { src = Wq  + (long)l * DD; dst = base;            K = DMODEL; N = DMODEL; tt = r; }
        else if (r < 2 * TILES_DD)  { src = Wk  + (long)l * DD; dst = base + DD;       K = DMODEL; N = DMODEL; tt = r - TILES_DD; }
        else if (r < 3 * TILES_DD)  { src = Wv  + (long)l * DD; dst = base + 2 * DD;   K = DMODEL; N = DMODEL; tt = r - 2 * TILES_DD; }
        else if (r < 4 * TILES_DD)  { src = Wo  + (long)l * DD; dst = base + 3 * DD;   K = DMODEL; N = DMODEL; tt = r - 3 * TILES_DD; }
        else if (r < 4 * TILES_DD + TILES_DF)
                                    { src = F1w + (long)l * DF; dst = base + 4 * DD;   K = DMODEL; N = FDIM;   tt = r - 4 * TILES_DD; }
        else                        { src = F2w + (long)l * DF; dst = base + 4 * DD + DF; K = FDIM; N = DMODEL; tt = r - 4 * TILES_DD - TILES_DF; }
    } else {
        src = OutW; dst = owT; K = DMODEL; N = VOCAB; tt = id - TILES_ALL;
    }
    int ntx = (N + 31) >> 5;
    int n0 = (tt % ntx) * 32, k0 = (tt / ntx) * 32;
    int tx = threadIdx.x & 31, ty = threadIdx.x >> 5;
#pragma unroll
    for (int i = 0; i < 32; i += 8) {
        int k = k0 + ty + i, n = n0 + tx;
        t[ty + i][tx] = (k < K && n < N) ? src[(long)k * N + n] : 0.f;
    }
    __syncthreads();
#pragma unroll
    for (int i = 0; i < 32; i += 8) {
        int n = n0 + ty + i, k = k0 + tx;
        if (n < N && k < K) dst[(long)n * K + k] = f2bs(t[tx][ty + i]);
    }
}

// -------- fused QK^T + mask + softmax + PV  (one kernel per 64 Q-rows) -----
// grid (S/64, B*H).  4 waves. Phase 1: wave w computes score cols [w*128,+128).
// Phase 2: P -> LDS (bf16, swizzled), V^T staged over dead K region; wave w
// computes O rows [w*16,+16) over k in two 256-halves. Writes attn f32 + O bf16.
__global__ __launch_bounds__(256, 2) void attn_kernel(
    const u16* __restrict__ qkvb, const u16* __restrict__ vtb,
    const int* __restrict__ amask,
    float* __restrict__ attn, u16* __restrict__ ob)
{
    __shared__ u16 Qs[64][64];        // 8 KB  (swizzled)
    __shared__ u16 Ks[SLEN][64];      // 64 KB (swizzled); after QK^T reused:
                                      //   lower 32 KB: Ph[64][256], upper 32 KB: Vh[64][256]
    __shared__ float maskadd[SLEN];
    __shared__ __align__(16) float redA[64][4];
    __shared__ __align__(16) float redB[64][4];

    u16* Ph = &Ks[0][0];
    u16* Vh = &Ks[256][0];

    int z = blockIdx.y;
    int b = z / NHEAD, h = z - b * NHEAD;
    int m0 = blockIdx.x * 64;
    int tid = threadIdx.x;
    int wave = tid >> 6, lane = tid & 63;
    int quad = lane >> 4, l16 = lane & 15;
    const float scale = 0.036084391824351615f;   // 1/sqrt(768)

    for (int i = tid; i < SLEN; i += 256)
        maskadd[i] = amask[b * SLEN + i] ? 0.f : -1e30f;

    const u16* Qbase = qkvb + (long)(b * SLEN) * (3 * DMODEL) + h * HDIM;
    const u16* Kbase = Qbase + DMODEL;
    const u16* Vtbase = vtb + (long)z * HDIM * SLEN;

    // stage Q (8KB), K (64KB): pre-swizzled source, LDS slot (row,c) holds chunk c^(row&7)
#pragma unroll
    for (int i = 0; i < 2; i++) {
        int off = wave * 2048 + i * 1024 + lane * 16;
        int row = off >> 7, c = (off >> 4) & 7, g = c ^ (row & 7);
        gload_lds16(Qbase + (long)(m0 + row) * (3 * DMODEL) + g * 8,
                    (char*)&Qs[0][0] + wave * 2048 + i * 1024);
    }
#pragma unroll
    for (int i = 0; i < 16; i++) {
        int off = wave * 16384 + i * 1024 + lane * 16;
        int row = off >> 7, c = (off >> 4) & 7, g = c ^ (row & 7);
        gload_lds16(Kbase + (long)row * (3 * DMODEL) + g * 8,
                    (char*)&Ks[0][0] + wave * 16384 + i * 1024);
    }
    __syncthreads();

    f32x4 acc[4][8];
#pragma unroll
    for (int i = 0; i < 4; i++)
#pragma unroll
        for (int j = 0; j < 8; j++) acc[i][j] = (f32x4){0.f, 0.f, 0.f, 0.f};

#pragma unroll
    for (int ks = 0; ks < 2; ks++) {
        bf16x8 afr[4], bfr[8];
#pragma unroll
        for (int i = 0; i < 4; i++) {
            int row = i * 16 + l16;
            int slot = ((ks << 2) + quad) ^ (row & 7);
            afr[i] = *reinterpret_cast<const bf16x8*>((char*)&Qs[0][0] + row * 128 + slot * 16);
        }
#pragma unroll
        for (int j = 0; j < 8; j++) {
            int row = wave * 128 + j * 16 + l16;
            int slot = ((ks << 2) + quad) ^ (row & 7);
            bfr[j] = *reinterpret_cast<const bf16x8*>((char*)&Ks[0][0] + row * 128 + slot * 16);
        }
#pragma unroll
        for (int i = 0; i < 4; i++)
#pragma unroll
            for (int j = 0; j < 8; j++)
                acc[i][j] = __builtin_amdgcn_mfma_f32_16x16x32_bf16(afr[i], bfr[j], acc[i][j], 0, 0, 0);
    }

    float ma[8];
#pragma unroll
    for (int j = 0; j < 8; j++) ma[j] = maskadd[wave * 128 + j * 16 + l16];

    float rmax[4][4];
#pragma unroll
    for (int i = 0; i < 4; i++)
#pragma unroll
        for (int r = 0; r < 4; r++) {
            float m = -3e38f;
#pragma unroll
            for (int j = 0; j < 8; j++) m = fmaxf(m, acc[i][j][r] * scale + ma[j]);
            rmax[i][r] = m;
        }
#pragma unroll
    for (int off = 1; off < 16; off <<= 1)
#pragma unroll
        for (int i = 0; i < 4; i++)
#pragma unroll
            for (int r = 0; r < 4; r++)
                rmax[i][r] = fmaxf(rmax[i][r], __shfl_xor(rmax[i][r], off, 64));
    if (l16 == 0) {
#pragma unroll
        for (int i = 0; i < 4; i++)
#pragma unroll
            for (int r = 0; r < 4; r++) redA[i * 16 + quad * 4 + r][wave] = rmax[i][r];
    }
    __syncthreads();          // <- all waves done reading Ks; safe to restage V

    // issue V half0 gloads (into Vh) — hides under softmax VALU
    {
        const u16* Vb = Vtbase + 0;
#pragma unroll
        for (int i = 0; i < 8; i++) {
            int o = wave * 8192 + i * 1024 + lane * 16;
            int hd = o >> 9, c = (o >> 4) & 31, g = c ^ (hd & 7);
            gload_lds16(Vb + (long)hd * SLEN + g * 8, (char*)Vh + wave * 8192 + i * 1024);
        }
    }

#pragma unroll
    for (int i = 0; i < 4; i++)
#pragma unroll
        for (int r = 0; r < 4; r++) {
            f32x4 v = *reinterpret_cast<const f32x4*>(&redA[i * 16 + quad * 4 + r][0]);
            rmax[i][r] = fmaxf(fmaxf(v[0], v[1]), fmaxf(v[2], v[3]));
        }

    float rsum[4][4];
#pragma unroll
    for (int i = 0; i < 4; i++)
#pragma unroll
        for (int r = 0; r < 4; r++) {
            float s = 0.f;
#pragma unroll
            for (int j = 0; j < 8; j++) {
                float e = expf(acc[i][j][r] * scale + ma[j] - rmax[i][r]);
                acc[i][j][r] = e;
                s += e;
            }
            rsum[i][r] = s;
        }
#pragma unroll
    for (int off = 1; off < 16; off <<= 1)
#pragma unroll
        for (int i = 0; i < 4; i++)
#pragma unroll
            for (int r = 0; r < 4; r++)
                rsum[i][r] += __shfl_xor(rsum[i][r], off, 64);
    if (l16 == 0) {
#pragma unroll
        for (int i = 0; i < 4; i++)
#pragma unroll
            for (int r = 0; r < 4; r++) redB[i * 16 + quad * 4 + r][wave] = rsum[i][r];
    }
    __syncthreads();          // (also drains V half0 loads)

    // finalize p in-place (acc <- prob), write attn f32
    float* ap = attn + (long)z * SLEN * SLEN;
#pragma unroll
    for (int i = 0; i < 4; i++)
#pragma unroll
        for (int r = 0; r < 4; r++) {
            f32x4 v = *reinterpret_cast<const f32x4*>(&redB[i * 16 + quad * 4 + r][0]);
            float inv = 1.0f / (v[0] + v[1] + v[2] + v[3]);
            long row = m0 + i * 16 + quad * 4 + r;
#pragma unroll
            for (int j = 0; j < 8; j++) {
                int col = (wave << 7) + j * 16 + l16;
                float p = acc[i][j][r] * inv;
                acc[i][j][r] = p;
                ap[row * SLEN + col] = p;
            }
        }

    // waves 0,1: write P cols [0,256) into Ph (swizzled bf16)
    if (wave < 2) {
#pragma unroll
        for (int i = 0; i < 4; i++)
#pragma unroll
            for (int j = 0; j < 8; j++) {
                int cl = (wave << 7) + j * 16 + l16;
#pragma unroll
                for (int r = 0; r < 4; r++) {
                    int row = i * 16 + quad * 4 + r;
                    int slot = (cl >> 3) ^ (row & 7);
                    *(u16*)((char*)Ph + row * 512 + slot * 16 + (cl & 7) * 2) = f2bs(acc[i][j][r]);
                }
            }
    }
    __syncthreads();          // Ph half0 + Vh half0 ready

    f32x4 acc2[4];
#pragma unroll
    for (int j = 0; j < 4; j++) acc2[j] = (f32x4){0.f, 0.f, 0.f, 0.f};

    // PV half0: wave w computes O rows [w*16, w*16+16), k in [0,256)
#pragma unroll
    for (int step = 0; step < 8; step++) {
        int Prow = (wave << 4) + l16;
        int aslot = (step * 4 + quad) ^ (Prow & 7);
        bf16x8 af = *reinterpret_cast<const bf16x8*>((char*)Ph + Prow * 512 + aslot * 16);
#pragma unroll
        for (int j = 0; j < 4; j++) {
            int hd = j * 16 + l16;
            int bslot = (step * 4 + quad) ^ (hd & 7);
            bf16x8 bf = *reinterpret_cast<const bf16x8*>((char*)Vh + hd * 512 + bslot * 16);
            acc2[j] = __builtin_amdgcn_mfma_f32_16x16x32_bf16(af, bf, acc2[j], 0, 0, 0);
        }
    }
    __syncthreads();          // all reads of half0 regions done

    // stage V half1; waves 2,3 write P cols [256,512)
    {
        const u16* Vb = Vtbase + 256;
#pragma unroll
        for (int i = 0; i < 8; i++) {
            int o = wave * 8192 + i * 1024 + lane * 16;
            int hd = o >> 9, c = (o >> 4) & 31, g = c ^ (hd & 7);
            gload_lds16(Vb + (long)hd * SLEN + g * 8, (char*)Vh + wave * 8192 + i * 1024);
        }
    }
    if (wave >= 2) {
#pragma unroll
        for (int i = 0; i < 4; i++)
#pragma unroll
            for (int j = 0; j < 8; j++) {
                int cl = ((wave - 2) << 7) + j * 16 + l16;
#pragma unroll
                for (int r = 0; r < 4; r++) {
                    int row = i * 16 + quad * 4 + r;
                    int slot = (cl >> 3) ^ (row & 7);
                    *(u16*)((char*)Ph + row * 512 + slot * 16 + (cl & 7) * 2) = f2bs(acc[i][j][r]);
                }
            }
    }
    __syncthreads();          // Ph half1 + Vh half1 ready

    // PV half1: k in [256,512)
#pragma unroll
    for (int step = 0; step < 8; step++) {
        int Prow = (wave << 4) + l16;
        int aslot = (step * 4 + quad) ^ (Prow & 7);
        bf16x8 af = *reinterpret_cast<const bf16x8*>((char*)Ph + Prow * 512 + aslot * 16);
#pragma unroll
        for (int j = 0; j < 4; j++) {
            int hd = j * 16 + l16;
            int bslot = (step * 4 + quad) ^ (hd & 7);
            bf16x8 bf = *reinterpret_cast<const bf16x8*>((char*)Vh + hd * 512 + bslot * 16);
            acc2[j] = __builtin_amdgcn_mfma_f32_16x16x32_bf16(af, bf, acc2[j], 0, 0, 0);
        }
    }

    // write O (bf16) to ob [tok][768]
#pragma unroll
    for (int j = 0; j < 4; j++)
#pragma unroll
        for (int r = 0; r < 4; r++) {
            int q = m0 + (wave << 4) + quad * 4 + r;
            ob[((long)(b * SLEN + q)) * DMODEL + h * HDIM + j * 16 + l16] = f2bs(acc2[j][r]);
        }
}

// ------- bf16 MFMA GEMM, double-buffered 2-phase pipeline (T3-minimum) -----
// C[z] = epi( scale * A[z] @ B[z]^T + bias ),  A:[M][K] bf16, B:[N][K] bf16
// QKVF: also scatter V-part (col>=1536) into vt[b,h,hd,s] (packed ushort4)
template<int BM, int BN, int OUTBF, int GELU, int QKVF>
__global__ __launch_bounds__(256) void gemm_bf16(
    const u16* __restrict__ A, int lda, long sA1, long sA2,
    const u16* __restrict__ B, int ldb, long sB1, long sB2,
    void* __restrict__ Cv, int ldc, long sC1, long sC2,
    int zdiv, const float* __restrict__ bias,
    int N, int K, float scale, u16* __restrict__ vt)
{
    __shared__ u16 As[2][BM][32];
    __shared__ u16 Bs[2][BN][32];
    int z = blockIdx.z;
    int zq = z / zdiv, zr = z - zq * zdiv;
    A += zq * sA1 + zr * sA2;
    B += zq * sB1 + zr * sB2;

    int m0 = blockIdx.y * BM;
    int n0 = blockIdx.x * BN;
    int tid = threadIdx.x;
    int wave = tid >> 6, lane = tid & 63;
    int quad = lane >> 4, l16 = lane & 15;
    int wr = wave >> 1, wc = wave & 1;
    constexpr int MR = BM / 32, NR = BN / 32;

    f32x4 acc[MR][NR];
#pragma unroll
    for (int i = 0; i < MR; i++)
#pragma unroll
        for (int j = 0; j < NR; j++) acc[i][j] = (f32x4){0.f, 0.f, 0.f, 0.f};

    int srow = lane >> 2;          // 0..15
    int scol = (lane & 3) * 8;     // 0,8,16,24

    auto stage = [&](int buf, int k0) {
#pragma unroll
        for (int i = 0; i < BM / 64; i++) {
            int chunk = wave * (BM / 64) + i;
            int row = chunk * 16 + srow;
            gload_lds16(A + (long)(m0 + row) * lda + k0 + scol, &As[buf][chunk * 16][0]);
        }
#pragma unroll
        for (int i = 0; i < BN / 64; i++) {
            int chunk = wave * (BN / 64) + i;
            int row = n0 + chunk * 16 + srow;
            if (row > N - 1) row = N - 1;   // tail: duplicate reads, masked in epilogue
            gload_lds16(B + (long)row * ldb + k0 + scol, &Bs[buf][chunk * 16][0]);
        }
    };

    int nt = K >> 5;
    stage(0, 0);
    __syncthreads();

    int cur = 0;
    for (int t = 0; t < nt; ++t) {
        if (t + 1 < nt) stage(cur ^ 1, (t + 1) << 5);

        bf16x8 afr[MR], bfr[NR];
#pragma unroll
        for (int i = 0; i < MR; i++)
            afr[i] = *reinterpret_cast<const bf16x8*>(&As[cur][wr * (BM / 2) + i * 16 + l16][quad * 8]);
#pragma unroll
        for (int j = 0; j < NR; j++)
            bfr[j] = *reinterpret_cast<const bf16x8*>(&Bs[cur][wc * (BN / 2) + j * 16 + l16][quad * 8]);
#pragma unroll
        for (int i = 0; i < MR; i++)
#pragma unroll
            for (int j = 0; j < NR; j++)
                acc[i][j] = __builtin_amdgcn_mfma_f32_16x16x32_bf16(afr[i], bfr[j], acc[i][j], 0, 0, 0);

        __syncthreads();
        cur ^= 1;
    }

    float* Cf = (float*)Cv;
    u16*   Cb = (u16*)Cv;
    long coff = zq * sC1 + zr * sC2;
#pragma unroll
    for (int i = 0; i < MR; i++) {
        int rbase = m0 + wr * (BM / 2) + i * 16 + quad * 4;
#pragma unroll
        for (int j = 0; j < NR; j++) {
            int col = n0 + wc * (BN / 2) + j * 16 + l16;
            if (col < N) {
                float badd = bias ? bias[col] : 0.f;
                u16x4 v4;
#pragma unroll
                for (int r = 0; r < 4; r++) {
                    float vv = acc[i][j][r] * scale + badd;
                    if (GELU) vv = 0.5f * vv * (1.0f + erff(vv * 0.70710678118f));
                    long idx = coff + (long)(rbase + r) * ldc + col;
                    if (OUTBF) { u16 u = f2bs(vv); Cb[idx] = u; v4[r] = u; }
                    else       Cf[idx] = vv;
                }
                if (QKVF && col >= 2 * DMODEL) {
                    int hh = (col - 2 * DMODEL) >> 6, hd = col & 63;
                    int bb = rbase >> 9, s = rbase & (SLEN - 1);
                    *reinterpret_cast<u16x4*>(
                        vt + ((long)(bb * NHEAD + hh) * HDIM + hd) * SLEN + s) = v4;
                }
            }
        }
    }
}

template<int BM, int BN, int OUTBF, int GELU, int QKVF = 0>
static inline void launch_gemm(hipStream_t stream,
    const u16* A, int lda, long sA1, long sA2,
    const u16* B, int ldb, long sB1, long sB2,
    void* C, int ldc, long sC1, long sC2,
    int zdiv, const float* bias, int M, int N, int K, float scale, int Z,
    u16* vt = nullptr)
{
    dim3 grid((N + BN - 1) / BN, M / BM, Z);
    gemm_bf16<BM, BN, OUTBF, GELU, QKVF><<<grid, 256, 0, stream>>>(
        A, lda, sA1, sA2, B, ldb, sB1, sB2, C, ldc, sC1, sC2,
        zdiv, bias, N, K, scale, vt);
}

// ---------------- driver ----------------
extern "C" void kernel_launch(void* const* d_in, const int* in_sizes, int n_in,
                              void* d_out, int out_size, void* d_ws, size_t ws_size,
                              hipStream_t stream)
{
    const int*   ids   = (const int*)d_in[0];
    const int*   amask = (const int*)d_in[1];
    const float* word  = (const float*)d_in[2];
    const float* pos   = (const float*)d_in[3];
    const float* seg   = (const float*)d_in[4];
    const float* eg    = (const float*)d_in[5];
    const float* eb    = (const float*)d_in[6];
    const float* Wq    = (const float*)d_in[7];
    const float* Wk    = (const float*)d_in[8];
    const float* Wv    = (const float*)d_in[9];
    const float* Wo    = (const float*)d_in[10];
    const float* F1w   = (const float*)d_in[11];
    const float* F1b   = (const float*)d_in[12];
    const float* F2w   = (const float*)d_in[13];
    const float* F2b   = (const float*)d_in[14];
    const float* G1    = (const float*)d_in[15];
    const float* B1    = (const float*)d_in[16];
    const float* G2    = (const float*)d_in[17];
    const float* B2    = (const float*)d_in[18];
    const float* OutW  = (const float*)d_in[19];
    const float* OutB  = (const float*)d_in[20];

    float* logits = (float*)d_out;
    float* attn_base = logits + (long)NTOK * VOCAB;

    long nd = (long)NTOK * DMODEL;
    // f32 region
    float* x  = (float*)d_ws;          // NTOK x D
    float* x1 = x + nd;                // NTOK x D
    float* o2 = x1 + nd;               // NTOK x D   (FF2 partial 0 aliases o2)
    float* p0 = o2;
    float* p1 = p0 + nd;               // NTOK x D   (FF2 partial 1)
    // bf16 region
    u16* xb   = (u16*)(p1 + nd);                       // NTOK x D
    u16* x1b  = xb + nd;                               // NTOK x D
    u16* qkvb = x1b + nd;                              // NTOK x 3D
    u16* vtb  = qkvb + (long)NTOK * 3 * DMODEL;        // B*H x HD x S == nd
    u16* ob   = vtb + nd;                              // NTOK x D
    u16* hb   = ob + nd;                               // NTOK x F
    u16* wT   = hb + (long)NTOK * FDIM;                // 12 x LAYER_W_ELEMS
    u16* owT  = wT + (long)NLAYER * LAYER_W_ELEMS;     // [VOCAB][D]

    // ---- convert ALL weights (all layers + out_w) in one launch ----
    conv_all_kernel<<<TILES_ALL + TILES_OW, 256, 0, stream>>>(
        Wq, Wk, Wv, Wo, F1w, F2w, OutW, wT, owT);

    embed_ln_kernel<<<NTOK, 256, 0, stream>>>(ids, word, pos, seg, eg, eb, x, xb);

    for (int l = 0; l < NLAYER; l++) {
        const u16* qkvT = wT + (long)l * LAYER_W_ELEMS;
        const u16* woT  = qkvT + 3 * DD;
        const u16* f1T  = qkvT + 4 * DD;
        const u16* f2T  = qkvT + 4 * DD + DF;
        const float* f1b = F1b + (long)l * FDIM;
        const float* f2b = F2b + (long)l * DMODEL;
        float* attn_l = attn_base + (long)l * NBATCH * NHEAD * SLEN * SLEN;

        // fused QKV: [NTOK,768] @ [768,2304] -> qkvb bf16 (+ V scattered into vtb)
        launch_gemm<128, 128, 1, 0, 1>(stream, xb, DMODEL, 0, 0,
                                       qkvT, DMODEL, 0, 0,
                                       qkvb, 3 * DMODEL, 0, 0,
                                       1, nullptr, NTOK, 3 * DMODEL, DMODEL, 1.f, 1, vtb);

        // fused QK^T + mask + softmax + PV -> attn_l (f32) + ob (bf16)
        attn_kernel<<<dim3(SLEN / 64, NBATCH * NHEAD), 256, 0, stream>>>(
            qkvb, vtb, amask, attn_l, ob);

        // o2 = o @ Wo  (f32)
        launch_gemm<128, 64, 0, 0>(stream, ob, DMODEL, 0, 0,
                                   woT, DMODEL, 0, 0,
                                   o2, DMODEL, 0, 0,
                                   1, nullptr, NTOK, DMODEL, DMODEL, 1.f, 1);

        ln_res_kernel<<<NTOK, 256, 0, stream>>>(x, o2, G1 + (long)l * DMODEL, B1 + (long)l * DMODEL, x1, x1b);

        // h = gelu(x1 @ f1w + f1b)  -> hb bf16
        launch_gemm<128, 128, 1, 1>(stream, x1b, DMODEL, 0, 0,
                                    f1T, DMODEL, 0, 0,
                                    hb, FDIM, 0, 0,
                                    1, f1b, NTOK, FDIM, DMODEL, 1.f, 1);

        // FF2 split-K=2: partial s covers k in [s*1536, s*1536+1536)
        launch_gemm<128, 128, 0, 0>(stream, hb, FDIM, 1536, 0,
                                    f2T, FDIM, 1536, 0,
                                    p0, DMODEL, nd, 0,
                                    1, nullptr, NTOK, DMODEL, 1536, 1.f, 2);

        ln_res2_kernel<<<NTOK, 256, 0, stream>>>(x1, p0, p1, f2b,
                                                 G2 + (long)l * DMODEL, B2 + (long)l * DMODEL, x, xb);
    }

    // logits = x @ out_w + out_b
    launch_gemm<128, 128, 0, 0>(stream, xb, DMODEL, 0, 0,
                                owT, DMODEL, 0, 0,
                                logits, VOCAB, 0, 0,
                                1, OutB, NTOK, VOCAB, DMODEL, 1.f, 1);
}

// Round 5
// 1926.602 us; speedup vs baseline: 5.4176x; 1.1151x over previous
//
#include <hip/hip_runtime.h>
#include <hip/hip_bf16.h>

#define NLAYER 12
#define DMODEL 768
#define NHEAD  12
#define HDIM   64
#define FDIM   3072
#define VOCAB  30522
#define SLEN   512
#define NBATCH 4
#define NTOK   (NBATCH*SLEN)
#define EPSLN  1e-5f

typedef unsigned short u16;
using bf16 = __hip_bfloat16;
typedef __bf16 bf16x8 __attribute__((ext_vector_type(8)));
typedef float  f32x4  __attribute__((ext_vector_type(4)));
typedef u16    u16x4  __attribute__((ext_vector_type(4)));

__device__ __forceinline__ u16 f2bs(float f) {
    bf16 h = __float2bfloat16(f);
    return *reinterpret_cast<u16*>(&h);
}

// async global->LDS, 16B per lane. LDS dest = wave-uniform base + lane*16.
__device__ __forceinline__ void gload_lds16(const void* g, void* l) {
    auto gp = (const __attribute__((address_space(1))) unsigned int*)g;
    auto lp = (__attribute__((address_space(3))) unsigned int*)(unsigned long long)l;
    __builtin_amdgcn_global_load_lds(gp, lp, 16, 0, 0);
}

template<int N> __device__ __forceinline__ void waitv() {
    if constexpr (N == 0)      asm volatile("s_waitcnt vmcnt(0)" ::: "memory");
    else if constexpr (N == 3) asm volatile("s_waitcnt vmcnt(3)" ::: "memory");
    else if constexpr (N == 4) asm volatile("s_waitcnt vmcnt(4)" ::: "memory");
    else if constexpr (N == 6) asm volatile("s_waitcnt vmcnt(6)" ::: "memory");
    else if constexpr (N == 8) asm volatile("s_waitcnt vmcnt(8)" ::: "memory");
}

// ---------------- reductions ----------------
__device__ __forceinline__ float wave_sum64(float v) {
#pragma unroll
    for (int off = 32; off > 0; off >>= 1) v += __shfl_down(v, off, 64);
    return v;
}
__device__ __forceinline__ float block_sum256(float v, float* red) {
    v = wave_sum64(v);
    __syncthreads();
    if ((threadIdx.x & 63) == 0) red[threadIdx.x >> 6] = v;
    __syncthreads();
    return red[0] + red[1] + red[2] + red[3];
}

// ---------------- embedding + LN (writes f32 + bf16) ----------------
__global__ __launch_bounds__(256) void embed_ln_kernel(
    const int* __restrict__ ids, const float* __restrict__ word,
    const float* __restrict__ pos, const float* __restrict__ seg,
    const float* __restrict__ g, const float* __restrict__ b,
    float* __restrict__ out, u16* __restrict__ outb)
{
    __shared__ float red[4];
    int t = blockIdx.x;
    int s = t & (SLEN - 1);
    long woff = (long)ids[t] * DMODEL;
    float vals[3];
#pragma unroll
    for (int i = 0; i < 3; i++) {
        int d = threadIdx.x + i * 256;
        vals[i] = word[woff + d] + pos[(long)s * DMODEL + d] + seg[d];
    }
    float mu = block_sum256(vals[0] + vals[1] + vals[2], red) * (1.0f / DMODEL);
    float vv = 0.f;
#pragma unroll
    for (int i = 0; i < 3; i++) { float d0 = vals[i] - mu; vv += d0 * d0; }
    float rstd = rsqrtf(block_sum256(vv, red) * (1.0f / DMODEL) + EPSLN);
#pragma unroll
    for (int i = 0; i < 3; i++) {
        int d = threadIdx.x + i * 256;
        float r = (vals[i] - mu) * rstd * g[d] + b[d];
        out[(long)t * DMODEL + d] = r;
        outb[(long)t * DMODEL + d] = f2bs(r);
    }
}

// ------------- residual + 2 partials (+opt bias) + LN ----------------------
__global__ __launch_bounds__(256) void ln_res2_kernel(
    const float* __restrict__ a, const float* __restrict__ p0,
    const float* __restrict__ p1, const float* __restrict__ cbias,
    const float* __restrict__ g, const float* __restrict__ beta,
    float* __restrict__ out, u16* __restrict__ outb)
{
    __shared__ float red[4];
    long t = blockIdx.x;
    float vals[3];
#pragma unroll
    for (int i = 0; i < 3; i++) {
        int d = threadIdx.x + i * 256;
        float bb = cbias ? cbias[d] : 0.f;
        vals[i] = a[t * DMODEL + d] + p0[t * DMODEL + d] + p1[t * DMODEL + d] + bb;
    }
    float mu = block_sum256(vals[0] + vals[1] + vals[2], red) * (1.0f / DMODEL);
    float vv = 0.f;
#pragma unroll
    for (int i = 0; i < 3; i++) { float d0 = vals[i] - mu; vv += d0 * d0; }
    float rstd = rsqrtf(block_sum256(vv, red) * (1.0f / DMODEL) + EPSLN);
#pragma unroll
    for (int i = 0; i < 3; i++) {
        int d = threadIdx.x + i * 256;
        float r = (vals[i] - mu) * rstd * g[d] + beta[d];
        out[t * DMODEL + d] = r;
        outb[t * DMODEL + d] = f2bs(r);
    }
}

// ------------- residual + 4 partials + bias + LN (split-K=4 FF2 reduce) ----
__global__ __launch_bounds__(256) void ln_res4_kernel(
    const float* __restrict__ a, const float* __restrict__ p0,
    const float* __restrict__ p1, const float* __restrict__ p2,
    const float* __restrict__ p3, const float* __restrict__ cbias,
    const float* __restrict__ g, const float* __restrict__ beta,
    float* __restrict__ out, u16* __restrict__ outb)
{
    __shared__ float red[4];
    long t = blockIdx.x;
    float vals[3];
#pragma unroll
    for (int i = 0; i < 3; i++) {
        int d = threadIdx.x + i * 256;
        vals[i] = a[t * DMODEL + d] + p0[t * DMODEL + d] + p1[t * DMODEL + d]
                + p2[t * DMODEL + d] + p3[t * DMODEL + d] + cbias[d];
    }
    float mu = block_sum256(vals[0] + vals[1] + vals[2], red) * (1.0f / DMODEL);
    float vv = 0.f;
#pragma unroll
    for (int i = 0; i < 3; i++) { float d0 = vals[i] - mu; vv += d0 * d0; }
    float rstd = rsqrtf(block_sum256(vv, red) * (1.0f / DMODEL) + EPSLN);
#pragma unroll
    for (int i = 0; i < 3; i++) {
        int d = threadIdx.x + i * 256;
        float r = (vals[i] - mu) * rstd * g[d] + beta[d];
        out[t * DMODEL + d] = r;
        outb[t * DMODEL + d] = f2bs(r);
    }
}

// ---------------- all-weights transpose-convert, ONE launch ----------------
#define DD (DMODEL*DMODEL)
#define DF (DMODEL*FDIM)
#define LAYER_W_ELEMS (4*DD + 2*DF)
#define TILES_DD 576
#define TILES_DF 2304
#define TILES_LAYER (4*TILES_DD + 2*TILES_DF)
#define TILES_ALL (NLAYER*TILES_LAYER)
#define NTX_OW ((VOCAB + 31) / 32)
#define TILES_OW (NTX_OW * (DMODEL/32))

__global__ __launch_bounds__(256) void conv_all_kernel(
    const float* __restrict__ Wq, const float* __restrict__ Wk,
    const float* __restrict__ Wv, const float* __restrict__ Wo,
    const float* __restrict__ F1w, const float* __restrict__ F2w,
    const float* __restrict__ OutW, u16* __restrict__ wT, u16* __restrict__ owT)
{
    __shared__ float t[32][33];
    int id = blockIdx.x;
    const float* src; u16* dst; int K, N, tt;
    if (id < TILES_ALL) {
        int l = id / TILES_LAYER, r = id - l * TILES_LAYER;
        u16* base = wT + (long)l * LAYER_W_ELEMS;
        if (r < TILES_DD)           { src = Wq  + (long)l * DD; dst = base;            K = DMODEL; N = DMODEL; tt = r; }
        else if (r < 2 * TILES_DD)  { src = Wk  + (long)l * DD; dst = base + DD;       K = DMODEL; N = DMODEL; tt = r - TILES_DD; }
        else if (r < 3 * TILES_DD)  { src = Wv  + (long)l * DD; dst = base + 2 * DD;   K = DMODEL; N = DMODEL; tt = r - 2 * TILES_DD; }
        else if (r < 4 * TILES_DD)  { src = Wo  + (long)l * DD; dst = base + 3 * DD;   K = DMODEL; N = DMODEL; tt = r - 3 * TILES_DD; }
        else if (r < 4 * TILES_DD + TILES_DF)
                                    { src = F1w + (long)l * DF; dst = base + 4 * DD;   K = DMODEL; N = FDIM;   tt = r - 4 * TILES_DD; }
        else                        { src = F2w + (long)l * DF; dst = base + 4 * DD + DF; K = FDIM; N = DMODEL; tt = r - 4 * TILES_DD - TILES_DF; }
    } else {
        src = OutW; dst = owT; K = DMODEL; N = VOCAB; tt = id - TILES_ALL;
    }
    int ntx = (N + 31) >> 5;
    int n0 = (tt % ntx) * 32, k0 = (tt / ntx) * 32;
    int tx = threadIdx.x & 31, ty = threadIdx.x >> 5;
#pragma unroll
    for (int i = 0; i < 32; i += 8) {
        int k = k0 + ty + i, n = n0 + tx;
        t[ty + i][tx] = (k < K && n < N) ? src[(long)k * N + n] : 0.f;
    }
    __syncthreads();
#pragma unroll
    for (int i = 0; i < 32; i += 8) {
        int n = n0 + ty + i, k = k0 + tx;
        if (n < N && k < K) dst[(long)n * K + k] = f2bs(t[tx][ty + i]);
    }
}

// -------- fused QK^T + mask + softmax + PV  (one kernel per 64 Q-rows) -----
__global__ __launch_bounds__(256, 2) void attn_kernel(
    const u16* __restrict__ qkvb, const u16* __restrict__ vtb,
    const int* __restrict__ amask,
    float* __restrict__ attn, u16* __restrict__ ob)
{
    __shared__ u16 Qs[64][64];
    __shared__ u16 Ks[SLEN][64];
    __shared__ float maskadd[SLEN];
    __shared__ __align__(16) float redA[64][4];
    __shared__ __align__(16) float redB[64][4];

    u16* Ph = &Ks[0][0];
    u16* Vh = &Ks[256][0];

    int z = blockIdx.y;
    int b = z / NHEAD, h = z - b * NHEAD;
    int m0 = blockIdx.x * 64;
    int tid = threadIdx.x;
    int wave = tid >> 6, lane = tid & 63;
    int quad = lane >> 4, l16 = lane & 15;
    const float scale = 0.036084391824351615f;   // 1/sqrt(768)

    for (int i = tid; i < SLEN; i += 256)
        maskadd[i] = amask[b * SLEN + i] ? 0.f : -1e30f;

    const u16* Qbase = qkvb + (long)(b * SLEN) * (3 * DMODEL) + h * HDIM;
    const u16* Kbase = Qbase + DMODEL;
    const u16* Vtbase = vtb + (long)z * HDIM * SLEN;

#pragma unroll
    for (int i = 0; i < 2; i++) {
        int off = wave * 2048 + i * 1024 + lane * 16;
        int row = off >> 7, c = (off >> 4) & 7, g = c ^ (row & 7);
        gload_lds16(Qbase + (long)(m0 + row) * (3 * DMODEL) + g * 8,
                    (char*)&Qs[0][0] + wave * 2048 + i * 1024);
    }
#pragma unroll
    for (int i = 0; i < 16; i++) {
        int off = wave * 16384 + i * 1024 + lane * 16;
        int row = off >> 7, c = (off >> 4) & 7, g = c ^ (row & 7);
        gload_lds16(Kbase + (long)row * (3 * DMODEL) + g * 8,
                    (char*)&Ks[0][0] + wave * 16384 + i * 1024);
    }
    __syncthreads();

    f32x4 acc[4][8];
#pragma unroll
    for (int i = 0; i < 4; i++)
#pragma unroll
        for (int j = 0; j < 8; j++) acc[i][j] = (f32x4){0.f, 0.f, 0.f, 0.f};

#pragma unroll
    for (int ks = 0; ks < 2; ks++) {
        bf16x8 afr[4], bfr[8];
#pragma unroll
        for (int i = 0; i < 4; i++) {
            int row = i * 16 + l16;
            int slot = ((ks << 2) + quad) ^ (row & 7);
            afr[i] = *reinterpret_cast<const bf16x8*>((char*)&Qs[0][0] + row * 128 + slot * 16);
        }
#pragma unroll
        for (int j = 0; j < 8; j++) {
            int row = wave * 128 + j * 16 + l16;
            int slot = ((ks << 2) + quad) ^ (row & 7);
            bfr[j] = *reinterpret_cast<const bf16x8*>((char*)&Ks[0][0] + row * 128 + slot * 16);
        }
#pragma unroll
        for (int i = 0; i < 4; i++)
#pragma unroll
            for (int j = 0; j < 8; j++)
                acc[i][j] = __builtin_amdgcn_mfma_f32_16x16x32_bf16(afr[i], bfr[j], acc[i][j], 0, 0, 0);
    }

    float ma[8];
#pragma unroll
    for (int j = 0; j < 8; j++) ma[j] = maskadd[wave * 128 + j * 16 + l16];

    float rmax[4][4];
#pragma unroll
    for (int i = 0; i < 4; i++)
#pragma unroll
        for (int r = 0; r < 4; r++) {
            float m = -3e38f;
#pragma unroll
            for (int j = 0; j < 8; j++) m = fmaxf(m, acc[i][j][r] * scale + ma[j]);
            rmax[i][r] = m;
        }
#pragma unroll
    for (int off = 1; off < 16; off <<= 1)
#pragma unroll
        for (int i = 0; i < 4; i++)
#pragma unroll
            for (int r = 0; r < 4; r++)
                rmax[i][r] = fmaxf(rmax[i][r], __shfl_xor(rmax[i][r], off, 64));
    if (l16 == 0) {
#pragma unroll
        for (int i = 0; i < 4; i++)
#pragma unroll
            for (int r = 0; r < 4; r++) redA[i * 16 + quad * 4 + r][wave] = rmax[i][r];
    }
    __syncthreads();          // all waves done reading Ks; safe to restage V

    {
        const u16* Vb = Vtbase + 0;
#pragma unroll
        for (int i = 0; i < 8; i++) {
            int o = wave * 8192 + i * 1024 + lane * 16;
            int hd = o >> 9, c = (o >> 4) & 31, g = c ^ (hd & 7);
            gload_lds16(Vb + (long)hd * SLEN + g * 8, (char*)Vh + wave * 8192 + i * 1024);
        }
    }

#pragma unroll
    for (int i = 0; i < 4; i++)
#pragma unroll
        for (int r = 0; r < 4; r++) {
            f32x4 v = *reinterpret_cast<const f32x4*>(&redA[i * 16 + quad * 4 + r][0]);
            rmax[i][r] = fmaxf(fmaxf(v[0], v[1]), fmaxf(v[2], v[3]));
        }

    float rsum[4][4];
#pragma unroll
    for (int i = 0; i < 4; i++)
#pragma unroll
        for (int r = 0; r < 4; r++) {
            float s = 0.f;
#pragma unroll
            for (int j = 0; j < 8; j++) {
                float e = expf(acc[i][j][r] * scale + ma[j] - rmax[i][r]);
                acc[i][j][r] = e;
                s += e;
            }
            rsum[i][r] = s;
        }
#pragma unroll
    for (int off = 1; off < 16; off <<= 1)
#pragma unroll
        for (int i = 0; i < 4; i++)
#pragma unroll
            for (int r = 0; r < 4; r++)
                rsum[i][r] += __shfl_xor(rsum[i][r], off, 64);
    if (l16 == 0) {
#pragma unroll
        for (int i = 0; i < 4; i++)
#pragma unroll
            for (int r = 0; r < 4; r++) redB[i * 16 + quad * 4 + r][wave] = rsum[i][r];
    }
    __syncthreads();          // (also drains V half0 loads)

    float* ap = attn + (long)z * SLEN * SLEN;
#pragma unroll
    for (int i = 0; i < 4; i++)
#pragma unroll
        for (int r = 0; r < 4; r++) {
            f32x4 v = *reinterpret_cast<const f32x4*>(&redB[i * 16 + quad * 4 + r][0]);
            float inv = 1.0f / (v[0] + v[1] + v[2] + v[3]);
            long row = m0 + i * 16 + quad * 4 + r;
#pragma unroll
            for (int j = 0; j < 8; j++) {
                int col = (wave << 7) + j * 16 + l16;
                float p = acc[i][j][r] * inv;
                acc[i][j][r] = p;
                ap[row * SLEN + col] = p;
            }
        }

    if (wave < 2) {
#pragma unroll
        for (int i = 0; i < 4; i++)
#pragma unroll
            for (int j = 0; j < 8; j++) {
                int cl = (wave << 7) + j * 16 + l16;
#pragma unroll
                for (int r = 0; r < 4; r++) {
                    int row = i * 16 + quad * 4 + r;
                    int slot = (cl >> 3) ^ (row & 7);
                    *(u16*)((char*)Ph + row * 512 + slot * 16 + (cl & 7) * 2) = f2bs(acc[i][j][r]);
                }
            }
    }
    __syncthreads();          // Ph half0 + Vh half0 ready

    f32x4 acc2[4];
#pragma unroll
    for (int j = 0; j < 4; j++) acc2[j] = (f32x4){0.f, 0.f, 0.f, 0.f};

#pragma unroll
    for (int step = 0; step < 8; step++) {
        int Prow = (wave << 4) + l16;
        int aslot = (step * 4 + quad) ^ (Prow & 7);
        bf16x8 af = *reinterpret_cast<const bf16x8*>((char*)Ph + Prow * 512 + aslot * 16);
#pragma unroll
        for (int j = 0; j < 4; j++) {
            int hd = j * 16 + l16;
            int bslot = (step * 4 + quad) ^ (hd & 7);
            bf16x8 bf = *reinterpret_cast<const bf16x8*>((char*)Vh + hd * 512 + bslot * 16);
            acc2[j] = __builtin_amdgcn_mfma_f32_16x16x32_bf16(af, bf, acc2[j], 0, 0, 0);
        }
    }
    __syncthreads();          // all reads of half0 regions done

    {
        const u16* Vb = Vtbase + 256;
#pragma unroll
        for (int i = 0; i < 8; i++) {
            int o = wave * 8192 + i * 1024 + lane * 16;
            int hd = o >> 9, c = (o >> 4) & 31, g = c ^ (hd & 7);
            gload_lds16(Vb + (long)hd * SLEN + g * 8, (char*)Vh + wave * 8192 + i * 1024);
        }
    }
    if (wave >= 2) {
#pragma unroll
        for (int i = 0; i < 4; i++)
#pragma unroll
            for (int j = 0; j < 8; j++) {
                int cl = ((wave - 2) << 7) + j * 16 + l16;
#pragma unroll
                for (int r = 0; r < 4; r++) {
                    int row = i * 16 + quad * 4 + r;
                    int slot = (cl >> 3) ^ (row & 7);
                    *(u16*)((char*)Ph + row * 512 + slot * 16 + (cl & 7) * 2) = f2bs(acc[i][j][r]);
                }
            }
    }
    __syncthreads();          // Ph half1 + Vh half1 ready

#pragma unroll
    for (int step = 0; step < 8; step++) {
        int Prow = (wave << 4) + l16;
        int aslot = (step * 4 + quad) ^ (Prow & 7);
        bf16x8 af = *reinterpret_cast<const bf16x8*>((char*)Ph + Prow * 512 + aslot * 16);
#pragma unroll
        for (int j = 0; j < 4; j++) {
            int hd = j * 16 + l16;
            int bslot = (step * 4 + quad) ^ (hd & 7);
            bf16x8 bf = *reinterpret_cast<const bf16x8*>((char*)Vh + hd * 512 + bslot * 16);
            acc2[j] = __builtin_amdgcn_mfma_f32_16x16x32_bf16(af, bf, acc2[j], 0, 0, 0);
        }
    }

#pragma unroll
    for (int j = 0; j < 4; j++)
#pragma unroll
        for (int r = 0; r < 4; r++) {
            int q = m0 + (wave << 4) + quad * 4 + r;
            ob[((long)(b * SLEN + q)) * DMODEL + h * HDIM + j * 16 + l16] = f2bs(acc2[j][r]);
        }
}

// ------- bf16 MFMA GEMM, depth-3 counted-vmcnt pipeline (T3+T4) ------------
// C[z] = epi( scale * A[z] @ B[z]^T + bias ),  A:[M][K] bf16, B:[N][K] bf16
// QKVF: also scatter V-part (col>=1536) into vt[b,h,hd,s] (packed ushort4)
template<int BM, int BN, int OUTBF, int GELU, int QKVF>
__global__ __launch_bounds__(256) void gemm_bf16(
    const u16* __restrict__ A, int lda, long sA1, long sA2,
    const u16* __restrict__ B, int ldb, long sB1, long sB2,
    void* __restrict__ Cv, int ldc, long sC1, long sC2,
    int zdiv, const float* __restrict__ bias,
    int N, int K, float scale, u16* __restrict__ vt)
{
    __shared__ u16 As[3][BM][32];
    __shared__ u16 Bs[3][BN][32];
    int z = blockIdx.z;
    int zq = z / zdiv, zr = z - zq * zdiv;
    A += zq * sA1 + zr * sA2;
    B += zq * sB1 + zr * sB2;

    int m0 = blockIdx.y * BM;
    int n0 = blockIdx.x * BN;
    int tid = threadIdx.x;
    int wave = tid >> 6, lane = tid & 63;
    int quad = lane >> 4, l16 = lane & 15;
    int wr = wave >> 1, wc = wave & 1;
    constexpr int MR = BM / 32, NR = BN / 32;
    constexpr int LPT = BM / 64 + BN / 64;     // gloads/wave/tile

    f32x4 acc[MR][NR];
#pragma unroll
    for (int i = 0; i < MR; i++)
#pragma unroll
        for (int j = 0; j < NR; j++) acc[i][j] = (f32x4){0.f, 0.f, 0.f, 0.f};

    int srow = lane >> 2;          // 0..15
    int scol = (lane & 3) * 8;     // 0,8,16,24

    auto stage = [&](int buf, int k0) {
#pragma unroll
        for (int i = 0; i < BM / 64; i++) {
            int chunk = wave * (BM / 64) + i;
            int row = chunk * 16 + srow;
            gload_lds16(A + (long)(m0 + row) * lda + k0 + scol, &As[buf][chunk * 16][0]);
        }
#pragma unroll
        for (int i = 0; i < BN / 64; i++) {
            int chunk = wave * (BN / 64) + i;
            int row = n0 + chunk * 16 + srow;
            if (row > N - 1) row = N - 1;   // tail: duplicate reads, masked in epilogue
            gload_lds16(B + (long)row * ldb + k0 + scol, &Bs[buf][chunk * 16][0]);
        }
    };

    int nt = K >> 5;
    stage(0, 0);
    if (nt > 1) stage(1, 32);
    if (nt > 2) stage(2, 64);

    int cur = 0;
    for (int t = 0; t < nt; ++t) {
        // wait for tile t (2 younger tiles may stay in flight), then align waves
        if (t + 2 < nt)      waitv<2 * LPT>();
        else if (t + 1 < nt) waitv<LPT>();
        else                 waitv<0>();
        __builtin_amdgcn_s_barrier();
        __builtin_amdgcn_sched_barrier(0);

        bf16x8 afr[MR], bfr[NR];
#pragma unroll
        for (int i = 0; i < MR; i++)
            afr[i] = *reinterpret_cast<const bf16x8*>(&As[cur][wr * (BM / 2) + i * 16 + l16][quad * 8]);
#pragma unroll
        for (int j = 0; j < NR; j++)
            bfr[j] = *reinterpret_cast<const bf16x8*>(&Bs[cur][wc * (BN / 2) + j * 16 + l16][quad * 8]);
#pragma unroll
        for (int i = 0; i < MR; i++)
#pragma unroll
            for (int j = 0; j < NR; j++)
                acc[i][j] = __builtin_amdgcn_mfma_f32_16x16x32_bf16(afr[i], bfr[j], acc[i][j], 0, 0, 0);

        // all waves finished reading buffer `cur` -> safe to overwrite
        asm volatile("" ::: "memory");
        __builtin_amdgcn_sched_barrier(0);
        __builtin_amdgcn_s_barrier();
        __builtin_amdgcn_sched_barrier(0);
        if (t + 3 < nt) stage(cur, (t + 3) * 32);
        cur = cur + 1; if (cur == 3) cur = 0;
    }

    float* Cf = (float*)Cv;
    u16*   Cb = (u16*)Cv;
    long coff = zq * sC1 + zr * sC2;
#pragma unroll
    for (int i = 0; i < MR; i++) {
        int rbase = m0 + wr * (BM / 2) + i * 16 + quad * 4;
#pragma unroll
        for (int j = 0; j < NR; j++) {
            int col = n0 + wc * (BN / 2) + j * 16 + l16;
            if (col < N) {
                float badd = bias ? bias[col] : 0.f;
                u16x4 v4;
#pragma unroll
                for (int r = 0; r < 4; r++) {
                    float vv = acc[i][j][r] * scale + badd;
                    if (GELU) vv = 0.5f * vv * (1.0f + erff(vv * 0.70710678118f));
                    long idx = coff + (long)(rbase + r) * ldc + col;
                    if (OUTBF) { u16 u = f2bs(vv); Cb[idx] = u; v4[r] = u; }
                    else       Cf[idx] = vv;
                }
                if (QKVF && col >= 2 * DMODEL) {
                    int hh = (col - 2 * DMODEL) >> 6, hd = col & 63;
                    int bb = rbase >> 9, s = rbase & (SLEN - 1);
                    *reinterpret_cast<u16x4*>(
                        vt + ((long)(bb * NHEAD + hh) * HDIM + hd) * SLEN + s) = v4;
                }
            }
        }
    }
}

template<int BM, int BN, int OUTBF, int GELU, int QKVF = 0>
static inline void launch_gemm(hipStream_t stream,
    const u16* A, int lda, long sA1, long sA2,
    const u16* B, int ldb, long sB1, long sB2,
    void* C, int ldc, long sC1, long sC2,
    int zdiv, const float* bias, int M, int N, int K, float scale, int Z,
    u16* vt = nullptr)
{
    dim3 grid((N + BN - 1) / BN, M / BM, Z);
    gemm_bf16<BM, BN, OUTBF, GELU, QKVF><<<grid, 256, 0, stream>>>(
        A, lda, sA1, sA2, B, ldb, sB1, sB2, C, ldc, sC1, sC2,
        zdiv, bias, N, K, scale, vt);
}

// ---------------- driver ----------------
extern "C" void kernel_launch(void* const* d_in, const int* in_sizes, int n_in,
                              void* d_out, int out_size, void* d_ws, size_t ws_size,
                              hipStream_t stream)
{
    const int*   ids   = (const int*)d_in[0];
    const int*   amask = (const int*)d_in[1];
    const float* word  = (const float*)d_in[2];
    const float* pos   = (const float*)d_in[3];
    const float* seg   = (const float*)d_in[4];
    const float* eg    = (const float*)d_in[5];
    const float* eb    = (const float*)d_in[6];
    const float* Wq    = (const float*)d_in[7];
    const float* Wk    = (const float*)d_in[8];
    const float* Wv    = (const float*)d_in[9];
    const float* Wo    = (const float*)d_in[10];
    const float* F1w   = (const float*)d_in[11];
    const float* F1b   = (const float*)d_in[12];
    const float* F2w   = (const float*)d_in[13];
    const float* F2b   = (const float*)d_in[14];
    const float* G1    = (const float*)d_in[15];
    const float* B1    = (const float*)d_in[16];
    const float* G2    = (const float*)d_in[17];
    const float* B2    = (const float*)d_in[18];
    const float* OutW  = (const float*)d_in[19];
    const float* OutB  = (const float*)d_in[20];

    float* logits = (float*)d_out;
    float* attn_base = logits + (long)NTOK * VOCAB;

    long nd = (long)NTOK * DMODEL;
    // f32 region
    float* x  = (float*)d_ws;          // NTOK x D
    float* x1 = x + nd;                // NTOK x D
    float* p0 = x1 + nd;               // NTOK x D partials
    float* p1 = p0 + nd;
    float* p2 = p1 + nd;
    float* p3 = p2 + nd;
    // bf16 region
    u16* xb   = (u16*)(p3 + nd);                       // NTOK x D
    u16* x1b  = xb + nd;                               // NTOK x D
    u16* qkvb = x1b + nd;                              // NTOK x 3D
    u16* vtb  = qkvb + (long)NTOK * 3 * DMODEL;        // B*H x HD x S == nd
    u16* ob   = vtb + nd;                              // NTOK x D
    u16* hb   = ob + nd;                               // NTOK x F
    u16* wT   = hb + (long)NTOK * FDIM;                // 12 x LAYER_W_ELEMS
    u16* owT  = wT + (long)NLAYER * LAYER_W_ELEMS;     // [VOCAB][D]

    conv_all_kernel<<<TILES_ALL + TILES_OW, 256, 0, stream>>>(
        Wq, Wk, Wv, Wo, F1w, F2w, OutW, wT, owT);

    embed_ln_kernel<<<NTOK, 256, 0, stream>>>(ids, word, pos, seg, eg, eb, x, xb);

    for (int l = 0; l < NLAYER; l++) {
        const u16* qkvT = wT + (long)l * LAYER_W_ELEMS;
        const u16* woT  = qkvT + 3 * DD;
        const u16* f1T  = qkvT + 4 * DD;
        const u16* f2T  = qkvT + 4 * DD + DF;
        const float* f1b = F1b + (long)l * FDIM;
        const float* f2b = F2b + (long)l * DMODEL;
        float* attn_l = attn_base + (long)l * NBATCH * NHEAD * SLEN * SLEN;

        // fused QKV: [NTOK,768] @ [768,2304] -> qkvb bf16 (+ V scattered into vtb)
        launch_gemm<128, 128, 1, 0, 1>(stream, xb, DMODEL, 0, 0,
                                       qkvT, DMODEL, 0, 0,
                                       qkvb, 3 * DMODEL, 0, 0,
                                       1, nullptr, NTOK, 3 * DMODEL, DMODEL, 1.f, 1, vtb);

        // fused QK^T + mask + softmax + PV -> attn_l (f32) + ob (bf16)
        attn_kernel<<<dim3(SLEN / 64, NBATCH * NHEAD), 256, 0, stream>>>(
            qkvb, vtb, amask, attn_l, ob);

        // o @ Wo, split-K=2 -> p0,p1  (k-chunk 384)
        launch_gemm<128, 64, 0, 0>(stream, ob, DMODEL, 384, 0,
                                   woT, DMODEL, 384, 0,
                                   p0, DMODEL, nd, 0,
                                   1, nullptr, NTOK, DMODEL, 384, 1.f, 2);

        ln_res2_kernel<<<NTOK, 256, 0, stream>>>(x, p0, p1, nullptr,
                                                 G1 + (long)l * DMODEL, B1 + (long)l * DMODEL, x1, x1b);

        // h = gelu(x1 @ f1w + f1b)  -> hb bf16
        launch_gemm<128, 128, 1, 1>(stream, x1b, DMODEL, 0, 0,
                                    f1T, DMODEL, 0, 0,
                                    hb, FDIM, 0, 0,
                                    1, f1b, NTOK, FDIM, DMODEL, 1.f, 1);

        // FF2 split-K=4: partial s covers k in [s*768, s*768+768)
        launch_gemm<128, 128, 0, 0>(stream, hb, FDIM, 768, 0,
                                    f2T, FDIM, 768, 0,
                                    p0, DMODEL, nd, 0,
                                    1, nullptr, NTOK, DMODEL, 768, 1.f, 4);

        ln_res4_kernel<<<NTOK, 256, 0, stream>>>(x1, p0, p1, p2, p3, f2b,
                                                 G2 + (long)l * DMODEL, B2 + (long)l * DMODEL, x, xb);
    }

    // logits = x @ out_w + out_b
    launch_gemm<128, 128, 0, 0>(stream, xb, DMODEL, 0, 0,
                                owT, DMODEL, 0, 0,
                                logits, VOCAB, 0, 0,
                                1, OutB, NTOK, VOCAB, DMODEL, 1.f, 1);
}

// Round 6
// 1907.166 us; speedup vs baseline: 5.4729x; 1.0102x over previous
//
#include <hip/hip_runtime.h>
#include <hip/hip_bf16.h>

#define NLAYER 12
#define DMODEL 768
#define NHEAD  12
#define HDIM   64
#define FDIM   3072
#define VOCAB  30522
#define SLEN   512
#define NBATCH 4
#define NTOK   (NBATCH*SLEN)
#define EPSLN  1e-5f

typedef unsigned short u16;
using bf16 = __hip_bfloat16;
typedef __bf16 bf16x8 __attribute__((ext_vector_type(8)));
typedef float  f32x4  __attribute__((ext_vector_type(4)));
typedef u16    u16x4  __attribute__((ext_vector_type(4)));

__device__ __forceinline__ u16 f2bs(float f) {
    bf16 h = __float2bfloat16(f);
    return *reinterpret_cast<u16*>(&h);
}

// async global->LDS, 16B per lane. LDS dest = wave-uniform base + lane*16.
__device__ __forceinline__ void gload_lds16(const void* g, void* l) {
    auto gp = (const __attribute__((address_space(1))) unsigned int*)g;
    auto lp = (__attribute__((address_space(3))) unsigned int*)(unsigned long long)l;
    __builtin_amdgcn_global_load_lds(gp, lp, 16, 0, 0);
}

template<int N> __device__ __forceinline__ void waitv() {
    if constexpr (N == 0)      asm volatile("s_waitcnt vmcnt(0)" ::: "memory");
    else if constexpr (N == 3) asm volatile("s_waitcnt vmcnt(3)" ::: "memory");
    else if constexpr (N == 4) asm volatile("s_waitcnt vmcnt(4)" ::: "memory");
    else if constexpr (N == 6) asm volatile("s_waitcnt vmcnt(6)" ::: "memory");
    else if constexpr (N == 8) asm volatile("s_waitcnt vmcnt(8)" ::: "memory");
}

// ---------------- reductions ----------------
__device__ __forceinline__ float wave_sum64(float v) {
#pragma unroll
    for (int off = 32; off > 0; off >>= 1) v += __shfl_down(v, off, 64);
    return v;
}
__device__ __forceinline__ float block_sum256(float v, float* red) {
    v = wave_sum64(v);
    __syncthreads();
    if ((threadIdx.x & 63) == 0) red[threadIdx.x >> 6] = v;
    __syncthreads();
    return red[0] + red[1] + red[2] + red[3];
}

// ---------------- embedding + LN (writes f32 + bf16) ----------------
__global__ __launch_bounds__(256) void embed_ln_kernel(
    const int* __restrict__ ids, const float* __restrict__ word,
    const float* __restrict__ pos, const float* __restrict__ seg,
    const float* __restrict__ g, const float* __restrict__ b,
    float* __restrict__ out, u16* __restrict__ outb)
{
    __shared__ float red[4];
    int t = blockIdx.x;
    int s = t & (SLEN - 1);
    long woff = (long)ids[t] * DMODEL;
    float vals[3];
#pragma unroll
    for (int i = 0; i < 3; i++) {
        int d = threadIdx.x + i * 256;
        vals[i] = word[woff + d] + pos[(long)s * DMODEL + d] + seg[d];
    }
    float mu = block_sum256(vals[0] + vals[1] + vals[2], red) * (1.0f / DMODEL);
    float vv = 0.f;
#pragma unroll
    for (int i = 0; i < 3; i++) { float d0 = vals[i] - mu; vv += d0 * d0; }
    float rstd = rsqrtf(block_sum256(vv, red) * (1.0f / DMODEL) + EPSLN);
#pragma unroll
    for (int i = 0; i < 3; i++) {
        int d = threadIdx.x + i * 256;
        float r = (vals[i] - mu) * rstd * g[d] + b[d];
        out[(long)t * DMODEL + d] = r;
        outb[(long)t * DMODEL + d] = f2bs(r);
    }
}

// ------------- residual + 2 partials (+opt bias) + LN ----------------------
__global__ __launch_bounds__(256) void ln_res2_kernel(
    const float* __restrict__ a, const float* __restrict__ p0,
    const float* __restrict__ p1, const float* __restrict__ cbias,
    const float* __restrict__ g, const float* __restrict__ beta,
    float* __restrict__ out, u16* __restrict__ outb)
{
    __shared__ float red[4];
    long t = blockIdx.x;
    float vals[3];
#pragma unroll
    for (int i = 0; i < 3; i++) {
        int d = threadIdx.x + i * 256;
        float bb = cbias ? cbias[d] : 0.f;
        vals[i] = a[t * DMODEL + d] + p0[t * DMODEL + d] + p1[t * DMODEL + d] + bb;
    }
    float mu = block_sum256(vals[0] + vals[1] + vals[2], red) * (1.0f / DMODEL);
    float vv = 0.f;
#pragma unroll
    for (int i = 0; i < 3; i++) { float d0 = vals[i] - mu; vv += d0 * d0; }
    float rstd = rsqrtf(block_sum256(vv, red) * (1.0f / DMODEL) + EPSLN);
#pragma unroll
    for (int i = 0; i < 3; i++) {
        int d = threadIdx.x + i * 256;
        float r = (vals[i] - mu) * rstd * g[d] + beta[d];
        out[t * DMODEL + d] = r;
        outb[t * DMODEL + d] = f2bs(r);
    }
}

// ------------- residual + 4 partials + bias + LN (split-K=4 FF2 reduce) ----
__global__ __launch_bounds__(256) void ln_res4_kernel(
    const float* __restrict__ a, const float* __restrict__ p0,
    const float* __restrict__ p1, const float* __restrict__ p2,
    const float* __restrict__ p3, const float* __restrict__ cbias,
    const float* __restrict__ g, const float* __restrict__ beta,
    float* __restrict__ out, u16* __restrict__ outb)
{
    __shared__ float red[4];
    long t = blockIdx.x;
    float vals[3];
#pragma unroll
    for (int i = 0; i < 3; i++) {
        int d = threadIdx.x + i * 256;
        vals[i] = a[t * DMODEL + d] + p0[t * DMODEL + d] + p1[t * DMODEL + d]
                + p2[t * DMODEL + d] + p3[t * DMODEL + d] + cbias[d];
    }
    float mu = block_sum256(vals[0] + vals[1] + vals[2], red) * (1.0f / DMODEL);
    float vv = 0.f;
#pragma unroll
    for (int i = 0; i < 3; i++) { float d0 = vals[i] - mu; vv += d0 * d0; }
    float rstd = rsqrtf(block_sum256(vv, red) * (1.0f / DMODEL) + EPSLN);
#pragma unroll
    for (int i = 0; i < 3; i++) {
        int d = threadIdx.x + i * 256;
        float r = (vals[i] - mu) * rstd * g[d] + beta[d];
        out[t * DMODEL + d] = r;
        outb[t * DMODEL + d] = f2bs(r);
    }
}

// ---------------- all-weights transpose-convert, ONE launch ----------------
#define DD (DMODEL*DMODEL)
#define DF (DMODEL*FDIM)
#define LAYER_W_ELEMS (4*DD + 2*DF)
#define TILES_DD 576
#define TILES_DF 2304
#define TILES_LAYER (4*TILES_DD + 2*TILES_DF)
#define TILES_ALL (NLAYER*TILES_LAYER)
#define NTX_OW ((VOCAB + 31) / 32)
#define TILES_OW (NTX_OW * (DMODEL/32))

__global__ __launch_bounds__(256) void conv_all_kernel(
    const float* __restrict__ Wq, const float* __restrict__ Wk,
    const float* __restrict__ Wv, const float* __restrict__ Wo,
    const float* __restrict__ F1w, const float* __restrict__ F2w,
    const float* __restrict__ OutW, u16* __restrict__ wT, u16* __restrict__ owT)
{
    __shared__ float t[32][33];
    int id = blockIdx.x;
    const float* src; u16* dst; int K, N, tt;
    if (id < TILES_ALL) {
        int l = id / TILES_LAYER, r = id - l * TILES_LAYER;
        u16* base = wT + (long)l * LAYER_W_ELEMS;
        if (r < TILES_DD)           { src = Wq  + (long)l * DD; dst = base;            K = DMODEL; N = DMODEL; tt = r; }
        else if (r < 2 * TILES_DD)  { src = Wk  + (long)l * DD; dst = base + DD;       K = DMODEL; N = DMODEL; tt = r - TILES_DD; }
        else if (r < 3 * TILES_DD)  { src = Wv  + (long)l * DD; dst = base + 2 * DD;   K = DMODEL; N = DMODEL; tt = r - 2 * TILES_DD; }
        else if (r < 4 * TILES_DD)  { src = Wo  + (long)l * DD; dst = base + 3 * DD;   K = DMODEL; N = DMODEL; tt = r - 3 * TILES_DD; }
        else if (r < 4 * TILES_DD + TILES_DF)
                                    { src = F1w + (long)l * DF; dst = base + 4 * DD;   K = DMODEL; N = FDIM;   tt = r - 4 * TILES_DD; }
        else                        { src = F2w + (long)l * DF; dst = base + 4 * DD + DF; K = FDIM; N = DMODEL; tt = r - 4 * TILES_DD - TILES_DF; }
    } else {
        src = OutW; dst = owT; K = DMODEL; N = VOCAB; tt = id - TILES_ALL;
    }
    int ntx = (N + 31) >> 5;
    int n0 = (tt % ntx) * 32, k0 = (tt / ntx) * 32;
    int tx = threadIdx.x & 31, ty = threadIdx.x >> 5;
#pragma unroll
    for (int i = 0; i < 32; i += 8) {
        int k = k0 + ty + i, n = n0 + tx;
        t[ty + i][tx] = (k < K && n < N) ? src[(long)k * N + n] : 0.f;
    }
    __syncthreads();
#pragma unroll
    for (int i = 0; i < 32; i += 8) {
        int n = n0 + ty + i, k = k0 + tx;
        if (n < N && k < K) dst[(long)n * K + k] = f2bs(t[tx][ty + i]);
    }
}

// -------- fused QK^T + mask + softmax + PV  (one kernel per 64 Q-rows) -----
__global__ __launch_bounds__(256, 2) void attn_kernel(
    const u16* __restrict__ qkvb, const u16* __restrict__ vtb,
    const int* __restrict__ amask,
    float* __restrict__ attn, u16* __restrict__ ob)
{
    __shared__ u16 Qs[64][64];
    __shared__ u16 Ks[SLEN][64];
    __shared__ float maskadd[SLEN];
    __shared__ __align__(16) float redA[64][4];
    __shared__ __align__(16) float redB[64][4];

    u16* Ph = &Ks[0][0];
    u16* Vh = &Ks[256][0];

    int z = blockIdx.y;
    int b = z / NHEAD, h = z - b * NHEAD;
    int m0 = blockIdx.x * 64;
    int tid = threadIdx.x;
    int wave = tid >> 6, lane = tid & 63;
    int quad = lane >> 4, l16 = lane & 15;
    const float scale = 0.036084391824351615f;   // 1/sqrt(768)

    for (int i = tid; i < SLEN; i += 256)
        maskadd[i] = amask[b * SLEN + i] ? 0.f : -1e30f;

    const u16* Qbase = qkvb + (long)(b * SLEN) * (3 * DMODEL) + h * HDIM;
    const u16* Kbase = Qbase + DMODEL;
    const u16* Vtbase = vtb + (long)z * HDIM * SLEN;

#pragma unroll
    for (int i = 0; i < 2; i++) {
        int off = wave * 2048 + i * 1024 + lane * 16;
        int row = off >> 7, c = (off >> 4) & 7, g = c ^ (row & 7);
        gload_lds16(Qbase + (long)(m0 + row) * (3 * DMODEL) + g * 8,
                    (char*)&Qs[0][0] + wave * 2048 + i * 1024);
    }
#pragma unroll
    for (int i = 0; i < 16; i++) {
        int off = wave * 16384 + i * 1024 + lane * 16;
        int row = off >> 7, c = (off >> 4) & 7, g = c ^ (row & 7);
        gload_lds16(Kbase + (long)row * (3 * DMODEL) + g * 8,
                    (char*)&Ks[0][0] + wave * 16384 + i * 1024);
    }
    __syncthreads();

    f32x4 acc[4][8];
#pragma unroll
    for (int i = 0; i < 4; i++)
#pragma unroll
        for (int j = 0; j < 8; j++) acc[i][j] = (f32x4){0.f, 0.f, 0.f, 0.f};

#pragma unroll
    for (int ks = 0; ks < 2; ks++) {
        bf16x8 afr[4], bfr[8];
#pragma unroll
        for (int i = 0; i < 4; i++) {
            int row = i * 16 + l16;
            int slot = ((ks << 2) + quad) ^ (row & 7);
            afr[i] = *reinterpret_cast<const bf16x8*>((char*)&Qs[0][0] + row * 128 + slot * 16);
        }
#pragma unroll
        for (int j = 0; j < 8; j++) {
            int row = wave * 128 + j * 16 + l16;
            int slot = ((ks << 2) + quad) ^ (row & 7);
            bfr[j] = *reinterpret_cast<const bf16x8*>((char*)&Ks[0][0] + row * 128 + slot * 16);
        }
#pragma unroll
        for (int i = 0; i < 4; i++)
#pragma unroll
            for (int j = 0; j < 8; j++)
                acc[i][j] = __builtin_amdgcn_mfma_f32_16x16x32_bf16(afr[i], bfr[j], acc[i][j], 0, 0, 0);
    }

    float ma[8];
#pragma unroll
    for (int j = 0; j < 8; j++) ma[j] = maskadd[wave * 128 + j * 16 + l16];

    float rmax[4][4];
#pragma unroll
    for (int i = 0; i < 4; i++)
#pragma unroll
        for (int r = 0; r < 4; r++) {
            float m = -3e38f;
#pragma unroll
            for (int j = 0; j < 8; j++) m = fmaxf(m, acc[i][j][r] * scale + ma[j]);
            rmax[i][r] = m;
        }
#pragma unroll
    for (int off = 1; off < 16; off <<= 1)
#pragma unroll
        for (int i = 0; i < 4; i++)
#pragma unroll
            for (int r = 0; r < 4; r++)
                rmax[i][r] = fmaxf(rmax[i][r], __shfl_xor(rmax[i][r], off, 64));
    if (l16 == 0) {
#pragma unroll
        for (int i = 0; i < 4; i++)
#pragma unroll
            for (int r = 0; r < 4; r++) redA[i * 16 + quad * 4 + r][wave] = rmax[i][r];
    }
    __syncthreads();          // all waves done reading Ks; safe to restage V

    {
        const u16* Vb = Vtbase + 0;
#pragma unroll
        for (int i = 0; i < 8; i++) {
            int o = wave * 8192 + i * 1024 + lane * 16;
            int hd = o >> 9, c = (o >> 4) & 31, g = c ^ (hd & 7);
            gload_lds16(Vb + (long)hd * SLEN + g * 8, (char*)Vh + wave * 8192 + i * 1024);
        }
    }

#pragma unroll
    for (int i = 0; i < 4; i++)
#pragma unroll
        for (int r = 0; r < 4; r++) {
            f32x4 v = *reinterpret_cast<const f32x4*>(&redA[i * 16 + quad * 4 + r][0]);
            rmax[i][r] = fmaxf(fmaxf(v[0], v[1]), fmaxf(v[2], v[3]));
        }

    float rsum[4][4];
#pragma unroll
    for (int i = 0; i < 4; i++)
#pragma unroll
        for (int r = 0; r < 4; r++) {
            float s = 0.f;
#pragma unroll
            for (int j = 0; j < 8; j++) {
                float e = expf(acc[i][j][r] * scale + ma[j] - rmax[i][r]);
                acc[i][j][r] = e;
                s += e;
            }
            rsum[i][r] = s;
        }
#pragma unroll
    for (int off = 1; off < 16; off <<= 1)
#pragma unroll
        for (int i = 0; i < 4; i++)
#pragma unroll
            for (int r = 0; r < 4; r++)
                rsum[i][r] += __shfl_xor(rsum[i][r], off, 64);
    if (l16 == 0) {
#pragma unroll
        for (int i = 0; i < 4; i++)
#pragma unroll
            for (int r = 0; r < 4; r++) redB[i * 16 + quad * 4 + r][wave] = rsum[i][r];
    }
    __syncthreads();          // (also drains V half0 loads)

    float* ap = attn + (long)z * SLEN * SLEN;
#pragma unroll
    for (int i = 0; i < 4; i++)
#pragma unroll
        for (int r = 0; r < 4; r++) {
            f32x4 v = *reinterpret_cast<const f32x4*>(&redB[i * 16 + quad * 4 + r][0]);
            float inv = 1.0f / (v[0] + v[1] + v[2] + v[3]);
            long row = m0 + i * 16 + quad * 4 + r;
#pragma unroll
            for (int j = 0; j < 8; j++) {
                int col = (wave << 7) + j * 16 + l16;
                float p = acc[i][j][r] * inv;
                acc[i][j][r] = p;
                ap[row * SLEN + col] = p;
            }
        }

    if (wave < 2) {
#pragma unroll
        for (int i = 0; i < 4; i++)
#pragma unroll
            for (int j = 0; j < 8; j++) {
                int cl = (wave << 7) + j * 16 + l16;
#pragma unroll
                for (int r = 0; r < 4; r++) {
                    int row = i * 16 + quad * 4 + r;
                    int slot = (cl >> 3) ^ (row & 7);
                    *(u16*)((char*)Ph + row * 512 + slot * 16 + (cl & 7) * 2) = f2bs(acc[i][j][r]);
                }
            }
    }
    __syncthreads();          // Ph half0 + Vh half0 ready

    f32x4 acc2[4];
#pragma unroll
    for (int j = 0; j < 4; j++) acc2[j] = (f32x4){0.f, 0.f, 0.f, 0.f};

#pragma unroll
    for (int step = 0; step < 8; step++) {
        int Prow = (wave << 4) + l16;
        int aslot = (step * 4 + quad) ^ (Prow & 7);
        bf16x8 af = *reinterpret_cast<const bf16x8*>((char*)Ph + Prow * 512 + aslot * 16);
#pragma unroll
        for (int j = 0; j < 4; j++) {
            int hd = j * 16 + l16;
            int bslot = (step * 4 + quad) ^ (hd & 7);
            bf16x8 bf = *reinterpret_cast<const bf16x8*>((char*)Vh + hd * 512 + bslot * 16);
            acc2[j] = __builtin_amdgcn_mfma_f32_16x16x32_bf16(af, bf, acc2[j], 0, 0, 0);
        }
    }
    __syncthreads();          // all reads of half0 regions done

    {
        const u16* Vb = Vtbase + 256;
#pragma unroll
        for (int i = 0; i < 8; i++) {
            int o = wave * 8192 + i * 1024 + lane * 16;
            int hd = o >> 9, c = (o >> 4) & 31, g = c ^ (hd & 7);
            gload_lds16(Vb + (long)hd * SLEN + g * 8, (char*)Vh + wave * 8192 + i * 1024);
        }
    }
    if (wave >= 2) {
#pragma unroll
        for (int i = 0; i < 4; i++)
#pragma unroll
            for (int j = 0; j < 8; j++) {
                int cl = ((wave - 2) << 7) + j * 16 + l16;
#pragma unroll
                for (int r = 0; r < 4; r++) {
                    int row = i * 16 + quad * 4 + r;
                    int slot = (cl >> 3) ^ (row & 7);
                    *(u16*)((char*)Ph + row * 512 + slot * 16 + (cl & 7) * 2) = f2bs(acc[i][j][r]);
                }
            }
    }
    __syncthreads();          // Ph half1 + Vh half1 ready

#pragma unroll
    for (int step = 0; step < 8; step++) {
        int Prow = (wave << 4) + l16;
        int aslot = (step * 4 + quad) ^ (Prow & 7);
        bf16x8 af = *reinterpret_cast<const bf16x8*>((char*)Ph + Prow * 512 + aslot * 16);
#pragma unroll
        for (int j = 0; j < 4; j++) {
            int hd = j * 16 + l16;
            int bslot = (step * 4 + quad) ^ (hd & 7);
            bf16x8 bf = *reinterpret_cast<const bf16x8*>((char*)Vh + hd * 512 + bslot * 16);
            acc2[j] = __builtin_amdgcn_mfma_f32_16x16x32_bf16(af, bf, acc2[j], 0, 0, 0);
        }
    }

#pragma unroll
    for (int j = 0; j < 4; j++)
#pragma unroll
        for (int r = 0; r < 4; r++) {
            int q = m0 + (wave << 4) + quad * 4 + r;
            ob[((long)(b * SLEN + q)) * DMODEL + h * HDIM + j * 16 + l16] = f2bs(acc2[j][r]);
        }
}

// ------- bf16 MFMA GEMM, depth-3 counted-vmcnt pipeline + T2 swizzle + T5 --
// C[z] = epi( scale * A[z] @ B[z]^T + bias ),  A:[M][K] bf16, B:[N][K] bf16
// LDS layout: slot c of tile-row r holds k-chunk c ^ ((r>>1)&3)  (16B slots).
// Staged via pre-swizzled GLOBAL source (LDS dest linear, m173 pattern);
// fragment read XORs the same involution -> 2-way banks (free) vs 8-way.
// QKVF: also scatter V-part (col>=1536) into vt[b,h,hd,s] (packed ushort4)
template<int BM, int BN, int OUTBF, int GELU, int QKVF>
__global__ __launch_bounds__(256) void gemm_bf16(
    const u16* __restrict__ A, int lda, long sA1, long sA2,
    const u16* __restrict__ B, int ldb, long sB1, long sB2,
    void* __restrict__ Cv, int ldc, long sC1, long sC2,
    int zdiv, const float* __restrict__ bias,
    int N, int K, float scale, u16* __restrict__ vt)
{
    __shared__ u16 As[3][BM][32];
    __shared__ u16 Bs[3][BN][32];
    int z = blockIdx.z;
    int zq = z / zdiv, zr = z - zq * zdiv;
    A += zq * sA1 + zr * sA2;
    B += zq * sB1 + zr * sB2;

    int m0 = blockIdx.y * BM;
    int n0 = blockIdx.x * BN;
    int tid = threadIdx.x;
    int wave = tid >> 6, lane = tid & 63;
    int quad = lane >> 4, l16 = lane & 15;
    int wr = wave >> 1, wc = wave & 1;
    constexpr int MR = BM / 32, NR = BN / 32;
    constexpr int LPT = BM / 64 + BN / 64;     // gloads/wave/tile

    f32x4 acc[MR][NR];
#pragma unroll
    for (int i = 0; i < MR; i++)
#pragma unroll
        for (int j = 0; j < NR; j++) acc[i][j] = (f32x4){0.f, 0.f, 0.f, 0.f};

    int srow = lane >> 2;          // 0..15 (row within 16-row chunk)
    int sc   = lane & 3;           // 16B slot within row (linear LDS dest)

    auto stage = [&](int buf, int k0) {
#pragma unroll
        for (int i = 0; i < BM / 64; i++) {
            int chunk = wave * (BM / 64) + i;
            int lrow = chunk * 16 + srow;                      // tile row
            int gcol = (sc ^ ((lrow >> 1) & 3)) * 8;           // pre-swizzled src chunk
            gload_lds16(A + (long)(m0 + lrow) * lda + k0 + gcol, &As[buf][chunk * 16][0]);
        }
#pragma unroll
        for (int i = 0; i < BN / 64; i++) {
            int chunk = wave * (BN / 64) + i;
            int lrow = chunk * 16 + srow;
            int grow = n0 + lrow;
            if (grow > N - 1) grow = N - 1;   // tail: duplicate reads, masked in epilogue
            int gcol = (sc ^ ((lrow >> 1) & 3)) * 8;
            gload_lds16(B + (long)grow * ldb + k0 + gcol, &Bs[buf][chunk * 16][0]);
        }
    };

    int nt = K >> 5;
    stage(0, 0);
    if (nt > 1) stage(1, 32);
    if (nt > 2) stage(2, 64);

    int cur = 0;
    for (int t = 0; t < nt; ++t) {
        // wait for tile t (2 younger tiles may stay in flight), then align waves
        if (t + 2 < nt)      waitv<2 * LPT>();
        else if (t + 1 < nt) waitv<LPT>();
        else                 waitv<0>();
        __builtin_amdgcn_s_barrier();
        __builtin_amdgcn_sched_barrier(0);

        bf16x8 afr[MR], bfr[NR];
#pragma unroll
        for (int i = 0; i < MR; i++) {
            int row = wr * (BM / 2) + i * 16 + l16;
            int slot = quad ^ ((row >> 1) & 3);
            afr[i] = *reinterpret_cast<const bf16x8*>((char*)&As[cur][0][0] + row * 64 + slot * 16);
        }
#pragma unroll
        for (int j = 0; j < NR; j++) {
            int row = wc * (BN / 2) + j * 16 + l16;
            int slot = quad ^ ((row >> 1) & 3);
            bfr[j] = *reinterpret_cast<const bf16x8*>((char*)&Bs[cur][0][0] + row * 64 + slot * 16);
        }
        __builtin_amdgcn_s_setprio(1);
#pragma unroll
        for (int i = 0; i < MR; i++)
#pragma unroll
            for (int j = 0; j < NR; j++)
                acc[i][j] = __builtin_amdgcn_mfma_f32_16x16x32_bf16(afr[i], bfr[j], acc[i][j], 0, 0, 0);
        __builtin_amdgcn_s_setprio(0);

        // all waves finished reading buffer `cur` -> safe to overwrite
        asm volatile("" ::: "memory");
        __builtin_amdgcn_sched_barrier(0);
        __builtin_amdgcn_s_barrier();
        __builtin_amdgcn_sched_barrier(0);
        if (t + 3 < nt) stage(cur, (t + 3) * 32);
        cur = cur + 1; if (cur == 3) cur = 0;
    }

    float* Cf = (float*)Cv;
    u16*   Cb = (u16*)Cv;
    long coff = zq * sC1 + zr * sC2;
#pragma unroll
    for (int i = 0; i < MR; i++) {
        int rbase = m0 + wr * (BM / 2) + i * 16 + quad * 4;
#pragma unroll
        for (int j = 0; j < NR; j++) {
            int col = n0 + wc * (BN / 2) + j * 16 + l16;
            if (col < N) {
                float badd = bias ? bias[col] : 0.f;
                u16x4 v4;
#pragma unroll
                for (int r = 0; r < 4; r++) {
                    float vv = acc[i][j][r] * scale + badd;
                    if (GELU) vv = 0.5f * vv * (1.0f + erff(vv * 0.70710678118f));
                    long idx = coff + (long)(rbase + r) * ldc + col;
                    if (OUTBF) { u16 u = f2bs(vv); Cb[idx] = u; v4[r] = u; }
                    else       Cf[idx] = vv;
                }
                if (QKVF && col >= 2 * DMODEL) {
                    int hh = (col - 2 * DMODEL) >> 6, hd = col & 63;
                    int bb = rbase >> 9, s = rbase & (SLEN - 1);
                    *reinterpret_cast<u16x4*>(
                        vt + ((long)(bb * NHEAD + hh) * HDIM + hd) * SLEN + s) = v4;
                }
            }
        }
    }
}

template<int BM, int BN, int OUTBF, int GELU, int QKVF = 0>
static inline void launch_gemm(hipStream_t stream,
    const u16* A, int lda, long sA1, long sA2,
    const u16* B, int ldb, long sB1, long sB2,
    void* C, int ldc, long sC1, long sC2,
    int zdiv, const float* bias, int M, int N, int K, float scale, int Z,
    u16* vt = nullptr)
{
    dim3 grid((N + BN - 1) / BN, M / BM, Z);
    gemm_bf16<BM, BN, OUTBF, GELU, QKVF><<<grid, 256, 0, stream>>>(
        A, lda, sA1, sA2, B, ldb, sB1, sB2, C, ldc, sC1, sC2,
        zdiv, bias, N, K, scale, vt);
}

// ---------------- driver ----------------
extern "C" void kernel_launch(void* const* d_in, const int* in_sizes, int n_in,
                              void* d_out, int out_size, void* d_ws, size_t ws_size,
                              hipStream_t stream)
{
    const int*   ids   = (const int*)d_in[0];
    const int*   amask = (const int*)d_in[1];
    const float* word  = (const float*)d_in[2];
    const float* pos   = (const float*)d_in[3];
    const float* seg   = (const float*)d_in[4];
    const float* eg    = (const float*)d_in[5];
    const float* eb    = (const float*)d_in[6];
    const float* Wq    = (const float*)d_in[7];
    const float* Wk    = (const float*)d_in[8];
    const float* Wv    = (const float*)d_in[9];
    const float* Wo    = (const float*)d_in[10];
    const float* F1w   = (const float*)d_in[11];
    const float* F1b   = (const float*)d_in[12];
    const float* F2w   = (const float*)d_in[13];
    const float* F2b   = (const float*)d_in[14];
    const float* G1    = (const float*)d_in[15];
    const float* B1    = (const float*)d_in[16];
    const float* G2    = (const float*)d_in[17];
    const float* B2    = (const float*)d_in[18];
    const float* OutW  = (const float*)d_in[19];
    const float* OutB  = (const float*)d_in[20];

    float* logits = (float*)d_out;
    float* attn_base = logits + (long)NTOK * VOCAB;

    long nd = (long)NTOK * DMODEL;
    // f32 region
    float* x  = (float*)d_ws;          // NTOK x D
    float* x1 = x + nd;                // NTOK x D
    float* p0 = x1 + nd;               // NTOK x D partials
    float* p1 = p0 + nd;
    float* p2 = p1 + nd;
    float* p3 = p2 + nd;
    // bf16 region
    u16* xb   = (u16*)(p3 + nd);                       // NTOK x D
    u16* x1b  = xb + nd;                               // NTOK x D
    u16* qkvb = x1b + nd;                              // NTOK x 3D
    u16* vtb  = qkvb + (long)NTOK * 3 * DMODEL;        // B*H x HD x S == nd
    u16* ob   = vtb + nd;                              // NTOK x D
    u16* hb   = ob + nd;                               // NTOK x F
    u16* wT   = hb + (long)NTOK * FDIM;                // 12 x LAYER_W_ELEMS
    u16* owT  = wT + (long)NLAYER * LAYER_W_ELEMS;     // [VOCAB][D]

    conv_all_kernel<<<TILES_ALL + TILES_OW, 256, 0, stream>>>(
        Wq, Wk, Wv, Wo, F1w, F2w, OutW, wT, owT);

    embed_ln_kernel<<<NTOK, 256, 0, stream>>>(ids, word, pos, seg, eg, eb, x, xb);

    for (int l = 0; l < NLAYER; l++) {
        const u16* qkvT = wT + (long)l * LAYER_W_ELEMS;
        const u16* woT  = qkvT + 3 * DD;
        const u16* f1T  = qkvT + 4 * DD;
        const u16* f2T  = qkvT + 4 * DD + DF;
        const float* f1b = F1b + (long)l * FDIM;
        const float* f2b = F2b + (long)l * DMODEL;
        float* attn_l = attn_base + (long)l * NBATCH * NHEAD * SLEN * SLEN;

        // fused QKV: [NTOK,768] @ [768,2304] -> qkvb bf16 (+ V scattered into vtb)
        launch_gemm<128, 128, 1, 0, 1>(stream, xb, DMODEL, 0, 0,
                                       qkvT, DMODEL, 0, 0,
                                       qkvb, 3 * DMODEL, 0, 0,
                                       1, nullptr, NTOK, 3 * DMODEL, DMODEL, 1.f, 1, vtb);

        // fused QK^T + mask + softmax + PV -> attn_l (f32) + ob (bf16)
        attn_kernel<<<dim3(SLEN / 64, NBATCH * NHEAD), 256, 0, stream>>>(
            qkvb, vtb, amask, attn_l, ob);

        // o @ Wo, split-K=2 -> p0,p1  (k-chunk 384)
        launch_gemm<128, 64, 0, 0>(stream, ob, DMODEL, 384, 0,
                                   woT, DMODEL, 384, 0,
                                   p0, DMODEL, nd, 0,
                                   1, nullptr, NTOK, DMODEL, 384, 1.f, 2);

        ln_res2_kernel<<<NTOK, 256, 0, stream>>>(x, p0, p1, nullptr,
                                                 G1 + (long)l * DMODEL, B1 + (long)l * DMODEL, x1, x1b);

        // h = gelu(x1 @ f1w + f1b)  -> hb bf16
        launch_gemm<128, 128, 1, 1>(stream, x1b, DMODEL, 0, 0,
                                    f1T, DMODEL, 0, 0,
                                    hb, FDIM, 0, 0,
                                    1, f1b, NTOK, FDIM, DMODEL, 1.f, 1);

        // FF2 split-K=4: partial s covers k in [s*768, s*768+768)
        launch_gemm<128, 128, 0, 0>(stream, hb, FDIM, 768, 0,
                                    f2T, FDIM, 768, 0,
                                    p0, DMODEL, nd, 0,
                                    1, nullptr, NTOK, DMODEL, 768, 1.f, 4);

        ln_res4_kernel<<<NTOK, 256, 0, stream>>>(x1, p0, p1, p2, p3, f2b,
                                                 G2 + (long)l * DMODEL, B2 + (long)l * DMODEL, x, xb);
    }

    // logits = x @ out_w + out_b
    launch_gemm<128, 128, 0, 0>(stream, xb, DMODEL, 0, 0,
                                owT, DMODEL, 0, 0,
                                logits, VOCAB, 0, 0,
                                1, OutB, NTOK, VOCAB, DMODEL, 1.f, 1);
}

// Round 7
// 1758.326 us; speedup vs baseline: 5.9361x; 1.0846x over previous
//
#include <hip/hip_runtime.h>
#include <hip/hip_bf16.h>

#define NLAYER 12
#define DMODEL 768
#define NHEAD  12
#define HDIM   64
#define FDIM   3072
#define VOCAB  30522
#define SLEN   512
#define NBATCH 4
#define NTOK   (NBATCH*SLEN)
#define EPSLN  1e-5f

typedef unsigned short u16;
using bf16 = __hip_bfloat16;
typedef __bf16 bf16x8 __attribute__((ext_vector_type(8)));
typedef float  f32x4  __attribute__((ext_vector_type(4)));
typedef u16    u16x4  __attribute__((ext_vector_type(4)));

__device__ __forceinline__ u16 f2bs(float f) {
    bf16 h = __float2bfloat16(f);
    return *reinterpret_cast<u16*>(&h);
}

// async global->LDS, 16B per lane. LDS dest = wave-uniform base + lane*16.
__device__ __forceinline__ void gload_lds16(const void* g, void* l) {
    auto gp = (const __attribute__((address_space(1))) unsigned int*)g;
    auto lp = (__attribute__((address_space(3))) unsigned int*)(unsigned long long)l;
    __builtin_amdgcn_global_load_lds(gp, lp, 16, 0, 0);
}

template<int N> __device__ __forceinline__ void waitv() {
    if constexpr (N == 0)      asm volatile("s_waitcnt vmcnt(0)" ::: "memory");
    else if constexpr (N == 3) asm volatile("s_waitcnt vmcnt(3)" ::: "memory");
    else if constexpr (N == 4) asm volatile("s_waitcnt vmcnt(4)" ::: "memory");
    else if constexpr (N == 6) asm volatile("s_waitcnt vmcnt(6)" ::: "memory");
    else if constexpr (N == 8) asm volatile("s_waitcnt vmcnt(8)" ::: "memory");
}

// ---------------- reductions ----------------
__device__ __forceinline__ float wave_sum64(float v) {
#pragma unroll
    for (int off = 32; off > 0; off >>= 1) v += __shfl_down(v, off, 64);
    return v;
}
__device__ __forceinline__ float block_sum256(float v, float* red) {
    v = wave_sum64(v);
    __syncthreads();
    if ((threadIdx.x & 63) == 0) red[threadIdx.x >> 6] = v;
    __syncthreads();
    return red[0] + red[1] + red[2] + red[3];
}

// ---------------- embedding + LN (writes f32 + bf16) ----------------
__global__ __launch_bounds__(256) void embed_ln_kernel(
    const int* __restrict__ ids, const float* __restrict__ word,
    const float* __restrict__ pos, const float* __restrict__ seg,
    const float* __restrict__ g, const float* __restrict__ b,
    float* __restrict__ out, u16* __restrict__ outb)
{
    __shared__ float red[4];
    int t = blockIdx.x;
    int s = t & (SLEN - 1);
    long woff = (long)ids[t] * DMODEL;
    float vals[3];
#pragma unroll
    for (int i = 0; i < 3; i++) {
        int d = threadIdx.x + i * 256;
        vals[i] = word[woff + d] + pos[(long)s * DMODEL + d] + seg[d];
    }
    float mu = block_sum256(vals[0] + vals[1] + vals[2], red) * (1.0f / DMODEL);
    float vv = 0.f;
#pragma unroll
    for (int i = 0; i < 3; i++) { float d0 = vals[i] - mu; vv += d0 * d0; }
    float rstd = rsqrtf(block_sum256(vv, red) * (1.0f / DMODEL) + EPSLN);
#pragma unroll
    for (int i = 0; i < 3; i++) {
        int d = threadIdx.x + i * 256;
        float r = (vals[i] - mu) * rstd * g[d] + b[d];
        out[(long)t * DMODEL + d] = r;
        outb[(long)t * DMODEL + d] = f2bs(r);
    }
}

// ------------- residual + 2 partials (+opt bias) + LN ----------------------
__global__ __launch_bounds__(256) void ln_res2_kernel(
    const float* __restrict__ a, const float* __restrict__ p0,
    const float* __restrict__ p1, const float* __restrict__ cbias,
    const float* __restrict__ g, const float* __restrict__ beta,
    float* __restrict__ out, u16* __restrict__ outb)
{
    __shared__ float red[4];
    long t = blockIdx.x;
    float vals[3];
#pragma unroll
    for (int i = 0; i < 3; i++) {
        int d = threadIdx.x + i * 256;
        float bb = cbias ? cbias[d] : 0.f;
        vals[i] = a[t * DMODEL + d] + p0[t * DMODEL + d] + p1[t * DMODEL + d] + bb;
    }
    float mu = block_sum256(vals[0] + vals[1] + vals[2], red) * (1.0f / DMODEL);
    float vv = 0.f;
#pragma unroll
    for (int i = 0; i < 3; i++) { float d0 = vals[i] - mu; vv += d0 * d0; }
    float rstd = rsqrtf(block_sum256(vv, red) * (1.0f / DMODEL) + EPSLN);
#pragma unroll
    for (int i = 0; i < 3; i++) {
        int d = threadIdx.x + i * 256;
        float r = (vals[i] - mu) * rstd * g[d] + beta[d];
        out[t * DMODEL + d] = r;
        outb[t * DMODEL + d] = f2bs(r);
    }
}

// ------------- residual + 4 partials + bias + LN (split-K=4 FF2 reduce) ----
__global__ __launch_bounds__(256) void ln_res4_kernel(
    const float* __restrict__ a, const float* __restrict__ p0,
    const float* __restrict__ p1, const float* __restrict__ p2,
    const float* __restrict__ p3, const float* __restrict__ cbias,
    const float* __restrict__ g, const float* __restrict__ beta,
    float* __restrict__ out, u16* __restrict__ outb)
{
    __shared__ float red[4];
    long t = blockIdx.x;
    float vals[3];
#pragma unroll
    for (int i = 0; i < 3; i++) {
        int d = threadIdx.x + i * 256;
        vals[i] = a[t * DMODEL + d] + p0[t * DMODEL + d] + p1[t * DMODEL + d]
                + p2[t * DMODEL + d] + p3[t * DMODEL + d] + cbias[d];
    }
    float mu = block_sum256(vals[0] + vals[1] + vals[2], red) * (1.0f / DMODEL);
    float vv = 0.f;
#pragma unroll
    for (int i = 0; i < 3; i++) { float d0 = vals[i] - mu; vv += d0 * d0; }
    float rstd = rsqrtf(block_sum256(vv, red) * (1.0f / DMODEL) + EPSLN);
#pragma unroll
    for (int i = 0; i < 3; i++) {
        int d = threadIdx.x + i * 256;
        float r = (vals[i] - mu) * rstd * g[d] + beta[d];
        out[t * DMODEL + d] = r;
        outb[t * DMODEL + d] = f2bs(r);
    }
}

// ---------------- all-weights transpose-convert, ONE launch ----------------
#define DD (DMODEL*DMODEL)
#define DF (DMODEL*FDIM)
#define LAYER_W_ELEMS (4*DD + 2*DF)
#define TILES_DD 576
#define TILES_DF 2304
#define TILES_LAYER (4*TILES_DD + 2*TILES_DF)
#define TILES_ALL (NLAYER*TILES_LAYER)
#define NTX_OW ((VOCAB + 31) / 32)
#define TILES_OW (NTX_OW * (DMODEL/32))

__global__ __launch_bounds__(256) void conv_all_kernel(
    const float* __restrict__ Wq, const float* __restrict__ Wk,
    const float* __restrict__ Wv, const float* __restrict__ Wo,
    const float* __restrict__ F1w, const float* __restrict__ F2w,
    const float* __restrict__ OutW, u16* __restrict__ wT, u16* __restrict__ owT)
{
    __shared__ float t[32][33];
    int id = blockIdx.x;
    const float* src; u16* dst; int K, N, tt;
    if (id < TILES_ALL) {
        int l = id / TILES_LAYER, r = id - l * TILES_LAYER;
        u16* base = wT + (long)l * LAYER_W_ELEMS;
        if (r < TILES_DD)           { src = Wq  + (long)l * DD; dst = base;            K = DMODEL; N = DMODEL; tt = r; }
        else if (r < 2 * TILES_DD)  { src = Wk  + (long)l * DD; dst = base + DD;       K = DMODEL; N = DMODEL; tt = r - TILES_DD; }
        else if (r < 3 * TILES_DD)  { src = Wv  + (long)l * DD; dst = base + 2 * DD;   K = DMODEL; N = DMODEL; tt = r - 2 * TILES_DD; }
        else if (r < 4 * TILES_DD)  { src = Wo  + (long)l * DD; dst = base + 3 * DD;   K = DMODEL; N = DMODEL; tt = r - 3 * TILES_DD; }
        else if (r < 4 * TILES_DD + TILES_DF)
                                    { src = F1w + (long)l * DF; dst = base + 4 * DD;   K = DMODEL; N = FDIM;   tt = r - 4 * TILES_DD; }
        else                        { src = F2w + (long)l * DF; dst = base + 4 * DD + DF; K = FDIM; N = DMODEL; tt = r - 4 * TILES_DD - TILES_DF; }
    } else {
        src = OutW; dst = owT; K = DMODEL; N = VOCAB; tt = id - TILES_ALL;
    }
    int ntx = (N + 31) >> 5;
    int n0 = (tt % ntx) * 32, k0 = (tt / ntx) * 32;
    int tx = threadIdx.x & 31, ty = threadIdx.x >> 5;
#pragma unroll
    for (int i = 0; i < 32; i += 8) {
        int k = k0 + ty + i, n = n0 + tx;
        t[ty + i][tx] = (k < K && n < N) ? src[(long)k * N + n] : 0.f;
    }
    __syncthreads();
#pragma unroll
    for (int i = 0; i < 32; i += 8) {
        int n = n0 + ty + i, k = k0 + tx;
        if (n < N && k < K) dst[(long)n * K + k] = f2bs(t[tx][ty + i]);
    }
}

// -------- fused QK^T + mask + softmax + PV  (one kernel per 64 Q-rows) -----
__global__ __launch_bounds__(256, 2) void attn_kernel(
    const u16* __restrict__ qkvb, const u16* __restrict__ vtb,
    const int* __restrict__ amask,
    float* __restrict__ attn, u16* __restrict__ ob)
{
    __shared__ u16 Qs[64][64];
    __shared__ u16 Ks[SLEN][64];
    __shared__ float maskadd[SLEN];
    __shared__ __align__(16) float redA[64][4];
    __shared__ __align__(16) float redB[64][4];

    u16* Ph = &Ks[0][0];
    u16* Vh = &Ks[256][0];

    int z = blockIdx.y;
    int b = z / NHEAD, h = z - b * NHEAD;
    int m0 = blockIdx.x * 64;
    int tid = threadIdx.x;
    int wave = tid >> 6, lane = tid & 63;
    int quad = lane >> 4, l16 = lane & 15;
    const float scale = 0.036084391824351615f;   // 1/sqrt(768)

    for (int i = tid; i < SLEN; i += 256)
        maskadd[i] = amask[b * SLEN + i] ? 0.f : -1e30f;

    const u16* Qbase = qkvb + (long)(b * SLEN) * (3 * DMODEL) + h * HDIM;
    const u16* Kbase = Qbase + DMODEL;
    const u16* Vtbase = vtb + (long)z * HDIM * SLEN;

#pragma unroll
    for (int i = 0; i < 2; i++) {
        int off = wave * 2048 + i * 1024 + lane * 16;
        int row = off >> 7, c = (off >> 4) & 7, g = c ^ (row & 7);
        gload_lds16(Qbase + (long)(m0 + row) * (3 * DMODEL) + g * 8,
                    (char*)&Qs[0][0] + wave * 2048 + i * 1024);
    }
#pragma unroll
    for (int i = 0; i < 16; i++) {
        int off = wave * 16384 + i * 1024 + lane * 16;
        int row = off >> 7, c = (off >> 4) & 7, g = c ^ (row & 7);
        gload_lds16(Kbase + (long)row * (3 * DMODEL) + g * 8,
                    (char*)&Ks[0][0] + wave * 16384 + i * 1024);
    }
    __syncthreads();

    f32x4 acc[4][8];
#pragma unroll
    for (int i = 0; i < 4; i++)
#pragma unroll
        for (int j = 0; j < 8; j++) acc[i][j] = (f32x4){0.f, 0.f, 0.f, 0.f};

#pragma unroll
    for (int ks = 0; ks < 2; ks++) {
        bf16x8 afr[4], bfr[8];
#pragma unroll
        for (int i = 0; i < 4; i++) {
            int row = i * 16 + l16;
            int slot = ((ks << 2) + quad) ^ (row & 7);
            afr[i] = *reinterpret_cast<const bf16x8*>((char*)&Qs[0][0] + row * 128 + slot * 16);
        }
#pragma unroll
        for (int j = 0; j < 8; j++) {
            int row = wave * 128 + j * 16 + l16;
            int slot = ((ks << 2) + quad) ^ (row & 7);
            bfr[j] = *reinterpret_cast<const bf16x8*>((char*)&Ks[0][0] + row * 128 + slot * 16);
        }
#pragma unroll
        for (int i = 0; i < 4; i++)
#pragma unroll
            for (int j = 0; j < 8; j++)
                acc[i][j] = __builtin_amdgcn_mfma_f32_16x16x32_bf16(afr[i], bfr[j], acc[i][j], 0, 0, 0);
    }

    float ma[8];
#pragma unroll
    for (int j = 0; j < 8; j++) ma[j] = maskadd[wave * 128 + j * 16 + l16];

    float rmax[4][4];
#pragma unroll
    for (int i = 0; i < 4; i++)
#pragma unroll
        for (int r = 0; r < 4; r++) {
            float m = -3e38f;
#pragma unroll
            for (int j = 0; j < 8; j++) m = fmaxf(m, acc[i][j][r] * scale + ma[j]);
            rmax[i][r] = m;
        }
#pragma unroll
    for (int off = 1; off < 16; off <<= 1)
#pragma unroll
        for (int i = 0; i < 4; i++)
#pragma unroll
            for (int r = 0; r < 4; r++)
                rmax[i][r] = fmaxf(rmax[i][r], __shfl_xor(rmax[i][r], off, 64));
    if (l16 == 0) {
#pragma unroll
        for (int i = 0; i < 4; i++)
#pragma unroll
            for (int r = 0; r < 4; r++) redA[i * 16 + quad * 4 + r][wave] = rmax[i][r];
    }
    __syncthreads();          // all waves done reading Ks; safe to restage V

    {
        const u16* Vb = Vtbase + 0;
#pragma unroll
        for (int i = 0; i < 8; i++) {
            int o = wave * 8192 + i * 1024 + lane * 16;
            int hd = o >> 9, c = (o >> 4) & 31, g = c ^ (hd & 7);
            gload_lds16(Vb + (long)hd * SLEN + g * 8, (char*)Vh + wave * 8192 + i * 1024);
        }
    }

#pragma unroll
    for (int i = 0; i < 4; i++)
#pragma unroll
        for (int r = 0; r < 4; r++) {
            f32x4 v = *reinterpret_cast<const f32x4*>(&redA[i * 16 + quad * 4 + r][0]);
            rmax[i][r] = fmaxf(fmaxf(v[0], v[1]), fmaxf(v[2], v[3]));
        }

    float rsum[4][4];
#pragma unroll
    for (int i = 0; i < 4; i++)
#pragma unroll
        for (int r = 0; r < 4; r++) {
            float s = 0.f;
#pragma unroll
            for (int j = 0; j < 8; j++) {
                float e = expf(acc[i][j][r] * scale + ma[j] - rmax[i][r]);
                acc[i][j][r] = e;
                s += e;
            }
            rsum[i][r] = s;
        }
#pragma unroll
    for (int off = 1; off < 16; off <<= 1)
#pragma unroll
        for (int i = 0; i < 4; i++)
#pragma unroll
            for (int r = 0; r < 4; r++)
                rsum[i][r] += __shfl_xor(rsum[i][r], off, 64);
    if (l16 == 0) {
#pragma unroll
        for (int i = 0; i < 4; i++)
#pragma unroll
            for (int r = 0; r < 4; r++) redB[i * 16 + quad * 4 + r][wave] = rsum[i][r];
    }
    __syncthreads();          // (also drains V half0 loads)

    float* ap = attn + (long)z * SLEN * SLEN;
#pragma unroll
    for (int i = 0; i < 4; i++)
#pragma unroll
        for (int r = 0; r < 4; r++) {
            f32x4 v = *reinterpret_cast<const f32x4*>(&redB[i * 16 + quad * 4 + r][0]);
            float inv = 1.0f / (v[0] + v[1] + v[2] + v[3]);
            long row = m0 + i * 16 + quad * 4 + r;
#pragma unroll
            for (int j = 0; j < 8; j++) {
                int col = (wave << 7) + j * 16 + l16;
                float p = acc[i][j][r] * inv;
                acc[i][j][r] = p;
                ap[row * SLEN + col] = p;
            }
        }

    if (wave < 2) {
#pragma unroll
        for (int i = 0; i < 4; i++)
#pragma unroll
            for (int j = 0; j < 8; j++) {
                int cl = (wave << 7) + j * 16 + l16;
#pragma unroll
                for (int r = 0; r < 4; r++) {
                    int row = i * 16 + quad * 4 + r;
                    int slot = (cl >> 3) ^ (row & 7);
                    *(u16*)((char*)Ph + row * 512 + slot * 16 + (cl & 7) * 2) = f2bs(acc[i][j][r]);
                }
            }
    }
    __syncthreads();          // Ph half0 + Vh half0 ready

    f32x4 acc2[4];
#pragma unroll
    for (int j = 0; j < 4; j++) acc2[j] = (f32x4){0.f, 0.f, 0.f, 0.f};

#pragma unroll
    for (int step = 0; step < 8; step++) {
        int Prow = (wave << 4) + l16;
        int aslot = (step * 4 + quad) ^ (Prow & 7);
        bf16x8 af = *reinterpret_cast<const bf16x8*>((char*)Ph + Prow * 512 + aslot * 16);
#pragma unroll
        for (int j = 0; j < 4; j++) {
            int hd = j * 16 + l16;
            int bslot = (step * 4 + quad) ^ (hd & 7);
            bf16x8 bf = *reinterpret_cast<const bf16x8*>((char*)Vh + hd * 512 + bslot * 16);
            acc2[j] = __builtin_amdgcn_mfma_f32_16x16x32_bf16(af, bf, acc2[j], 0, 0, 0);
        }
    }
    __syncthreads();          // all reads of half0 regions done

    {
        const u16* Vb = Vtbase + 256;
#pragma unroll
        for (int i = 0; i < 8; i++) {
            int o = wave * 8192 + i * 1024 + lane * 16;
            int hd = o >> 9, c = (o >> 4) & 31, g = c ^ (hd & 7);
            gload_lds16(Vb + (long)hd * SLEN + g * 8, (char*)Vh + wave * 8192 + i * 1024);
        }
    }
    if (wave >= 2) {
#pragma unroll
        for (int i = 0; i < 4; i++)
#pragma unroll
            for (int j = 0; j < 8; j++) {
                int cl = ((wave - 2) << 7) + j * 16 + l16;
#pragma unroll
                for (int r = 0; r < 4; r++) {
                    int row = i * 16 + quad * 4 + r;
                    int slot = (cl >> 3) ^ (row & 7);
                    *(u16*)((char*)Ph + row * 512 + slot * 16 + (cl & 7) * 2) = f2bs(acc[i][j][r]);
                }
            }
    }
    __syncthreads();          // Ph half1 + Vh half1 ready

#pragma unroll
    for (int step = 0; step < 8; step++) {
        int Prow = (wave << 4) + l16;
        int aslot = (step * 4 + quad) ^ (Prow & 7);
        bf16x8 af = *reinterpret_cast<const bf16x8*>((char*)Ph + Prow * 512 + aslot * 16);
#pragma unroll
        for (int j = 0; j < 4; j++) {
            int hd = j * 16 + l16;
            int bslot = (step * 4 + quad) ^ (hd & 7);
            bf16x8 bf = *reinterpret_cast<const bf16x8*>((char*)Vh + hd * 512 + bslot * 16);
            acc2[j] = __builtin_amdgcn_mfma_f32_16x16x32_bf16(af, bf, acc2[j], 0, 0, 0);
        }
    }

#pragma unroll
    for (int j = 0; j < 4; j++)
#pragma unroll
        for (int r = 0; r < 4; r++) {
            int q = m0 + (wave << 4) + quad * 4 + r;
            ob[((long)(b * SLEN + q)) * DMODEL + h * HDIM + j * 16 + l16] = f2bs(acc2[j][r]);
        }
}

// --- bf16 MFMA GEMM: 8-wave blocks, BK=64, depth-2 counted-vmcnt, swizzled --
// C[z] = epi( scale * A[z] @ B[z]^T + bias ),  A:[M][K] bf16, B:[N][K] bf16
// Waves 2x4: wave tile (BM/2) x (BN/4).  LDS rows are 128B; slot s of row r
// holds k-chunk s ^ (r&7) (pre-swizzled global source, linear LDS dest;
// fragment read XORs the same involution -> 2-way banks).
// QKVF: also scatter V-part (col>=1536) into vt[b,h,hd,s] (packed ushort4)
template<int BM, int BN, int OUTBF, int GELU, int QKVF>
__global__ __launch_bounds__(512) void gemm_bf16(
    const u16* __restrict__ A, int lda, long sA1, long sA2,
    const u16* __restrict__ B, int ldb, long sB1, long sB2,
    void* __restrict__ Cv, int ldc, long sC1, long sC2,
    int zdiv, const float* __restrict__ bias,
    int N, int K, float scale, u16* __restrict__ vt)
{
    __shared__ u16 As[2][BM][64];
    __shared__ u16 Bs[2][BN][64];
    int z = blockIdx.z;
    int zq = z / zdiv, zr = z - zq * zdiv;
    A += zq * sA1 + zr * sA2;
    B += zq * sB1 + zr * sB2;

    int m0 = blockIdx.y * BM;
    int n0 = blockIdx.x * BN;
    int tid = threadIdx.x;
    int wave = tid >> 6, lane = tid & 63;
    int quad = lane >> 4, l16 = lane & 15;
    int wr = wave >> 2, wc = wave & 3;           // 2 x 4 wave grid
    constexpr int MR = BM / 32, NR = BN / 64;    // fragments per wave
    constexpr int PA = BM / 64, PB = BN / 64;    // staging passes
    constexpr int LPT = PA + PB;                 // gloads per WAVE per tile

    f32x4 acc[MR][NR];
#pragma unroll
    for (int i = 0; i < MR; i++)
#pragma unroll
        for (int j = 0; j < NR; j++) acc[i][j] = (f32x4){0.f, 0.f, 0.f, 0.f};

    auto stage = [&](int buf, int k0) {
#pragma unroll
        for (int p = 0; p < PA; p++) {
            int chunk = p * 512 + tid;               // 16B chunk id, 8 per row
            int row = chunk >> 3, sc = chunk & 7;
            int gcol = (sc ^ (row & 7)) * 8;         // pre-swizzled source chunk
            gload_lds16(A + (long)(m0 + row) * lda + k0 + gcol,
                        (char*)&As[buf][0][0] + p * 8192 + wave * 1024);
        }
#pragma unroll
        for (int p = 0; p < PB; p++) {
            int chunk = p * 512 + tid;
            int row = chunk >> 3, sc = chunk & 7;
            int grow = n0 + row;
            if (grow > N - 1) grow = N - 1;          // tail: dup reads, masked later
            int gcol = (sc ^ (row & 7)) * 8;
            gload_lds16(B + (long)grow * ldb + k0 + gcol,
                        (char*)&Bs[buf][0][0] + p * 8192 + wave * 1024);
        }
    };

    int nt = K >> 6;                                 // BK = 64
    stage(0, 0);
    if (nt > 1) stage(1, 64);

    for (int t = 0; t < nt; ++t) {
        if (t + 1 < nt) waitv<LPT>();                // next tile may stay in flight
        else            waitv<0>();
        __builtin_amdgcn_s_barrier();
        __builtin_amdgcn_sched_barrier(0);

        int cur = t & 1;
#pragma unroll
        for (int kh = 0; kh < 2; kh++) {             // two 32-K halves
            bf16x8 afr[MR], bfr[NR];
#pragma unroll
            for (int i = 0; i < MR; i++) {
                int row = wr * (BM / 2) + i * 16 + l16;
                int slot = ((kh << 2) + quad) ^ (row & 7);
                afr[i] = *reinterpret_cast<const bf16x8*>(
                    (char*)&As[cur][0][0] + row * 128 + slot * 16);
            }
#pragma unroll
            for (int j = 0; j < NR; j++) {
                int row = wc * (BN / 4) + j * 16 + l16;
                int slot = ((kh << 2) + quad) ^ (row & 7);
                bfr[j] = *reinterpret_cast<const bf16x8*>(
                    (char*)&Bs[cur][0][0] + row * 128 + slot * 16);
            }
            __builtin_amdgcn_s_setprio(1);
#pragma unroll
            for (int i = 0; i < MR; i++)
#pragma unroll
                for (int j = 0; j < NR; j++)
                    acc[i][j] = __builtin_amdgcn_mfma_f32_16x16x32_bf16(afr[i], bfr[j], acc[i][j], 0, 0, 0);
            __builtin_amdgcn_s_setprio(0);
        }

        asm volatile("" ::: "memory");
        __builtin_amdgcn_sched_barrier(0);
        __builtin_amdgcn_s_barrier();                // all reads of buf done
        __builtin_amdgcn_sched_barrier(0);
        if (t + 2 < nt) stage(cur, (t + 2) << 6);
    }

    float* Cf = (float*)Cv;
    u16*   Cb = (u16*)Cv;
    long coff = zq * sC1 + zr * sC2;
#pragma unroll
    for (int i = 0; i < MR; i++) {
        int rbase = m0 + wr * (BM / 2) + i * 16 + quad * 4;
#pragma unroll
        for (int j = 0; j < NR; j++) {
            int col = n0 + wc * (BN / 4) + j * 16 + l16;
            if (col < N) {
                float badd = bias ? bias[col] : 0.f;
                u16x4 v4;
#pragma unroll
                for (int r = 0; r < 4; r++) {
                    float vv = acc[i][j][r] * scale + badd;
                    if (GELU) vv = 0.5f * vv * (1.0f + erff(vv * 0.70710678118f));
                    long idx = coff + (long)(rbase + r) * ldc + col;
                    if (OUTBF) { u16 u = f2bs(vv); Cb[idx] = u; v4[r] = u; }
                    else       Cf[idx] = vv;
                }
                if (QKVF && col >= 2 * DMODEL) {
                    int hh = (col - 2 * DMODEL) >> 6, hd = col & 63;
                    int bb = rbase >> 9, s = rbase & (SLEN - 1);
                    *reinterpret_cast<u16x4*>(
                        vt + ((long)(bb * NHEAD + hh) * HDIM + hd) * SLEN + s) = v4;
                }
            }
        }
    }
}

template<int BM, int BN, int OUTBF, int GELU, int QKVF = 0>
static inline void launch_gemm(hipStream_t stream,
    const u16* A, int lda, long sA1, long sA2,
    const u16* B, int ldb, long sB1, long sB2,
    void* C, int ldc, long sC1, long sC2,
    int zdiv, const float* bias, int M, int N, int K, float scale, int Z,
    u16* vt = nullptr)
{
    dim3 grid((N + BN - 1) / BN, M / BM, Z);
    gemm_bf16<BM, BN, OUTBF, GELU, QKVF><<<grid, 512, 0, stream>>>(
        A, lda, sA1, sA2, B, ldb, sB1, sB2, C, ldc, sC1, sC2,
        zdiv, bias, N, K, scale, vt);
}

// ---------------- driver ----------------
extern "C" void kernel_launch(void* const* d_in, const int* in_sizes, int n_in,
                              void* d_out, int out_size, void* d_ws, size_t ws_size,
                              hipStream_t stream)
{
    const int*   ids   = (const int*)d_in[0];
    const int*   amask = (const int*)d_in[1];
    const float* word  = (const float*)d_in[2];
    const float* pos   = (const float*)d_in[3];
    const float* seg   = (const float*)d_in[4];
    const float* eg    = (const float*)d_in[5];
    const float* eb    = (const float*)d_in[6];
    const float* Wq    = (const float*)d_in[7];
    const float* Wk    = (const float*)d_in[8];
    const float* Wv    = (const float*)d_in[9];
    const float* Wo    = (const float*)d_in[10];
    const float* F1w   = (const float*)d_in[11];
    const float* F1b   = (const float*)d_in[12];
    const float* F2w   = (const float*)d_in[13];
    const float* F2b   = (const float*)d_in[14];
    const float* G1    = (const float*)d_in[15];
    const float* B1    = (const float*)d_in[16];
    const float* G2    = (const float*)d_in[17];
    const float* B2    = (const float*)d_in[18];
    const float* OutW  = (const float*)d_in[19];
    const float* OutB  = (const float*)d_in[20];

    float* logits = (float*)d_out;
    float* attn_base = logits + (long)NTOK * VOCAB;

    long nd = (long)NTOK * DMODEL;
    // f32 region
    float* x  = (float*)d_ws;          // NTOK x D
    float* x1 = x + nd;                // NTOK x D
    float* p0 = x1 + nd;               // NTOK x D partials
    float* p1 = p0 + nd;
    float* p2 = p1 + nd;
    float* p3 = p2 + nd;
    // bf16 region
    u16* xb   = (u16*)(p3 + nd);                       // NTOK x D
    u16* x1b  = xb + nd;                               // NTOK x D
    u16* qkvb = x1b + nd;                              // NTOK x 3D
    u16* vtb  = qkvb + (long)NTOK * 3 * DMODEL;        // B*H x HD x S == nd
    u16* ob   = vtb + nd;                              // NTOK x D
    u16* hb   = ob + nd;                               // NTOK x F
    u16* wT   = hb + (long)NTOK * FDIM;                // 12 x LAYER_W_ELEMS
    u16* owT  = wT + (long)NLAYER * LAYER_W_ELEMS;     // [VOCAB][D]

    conv_all_kernel<<<TILES_ALL + TILES_OW, 256, 0, stream>>>(
        Wq, Wk, Wv, Wo, F1w, F2w, OutW, wT, owT);

    embed_ln_kernel<<<NTOK, 256, 0, stream>>>(ids, word, pos, seg, eg, eb, x, xb);

    for (int l = 0; l < NLAYER; l++) {
        const u16* qkvT = wT + (long)l * LAYER_W_ELEMS;
        const u16* woT  = qkvT + 3 * DD;
        const u16* f1T  = qkvT + 4 * DD;
        const u16* f2T  = qkvT + 4 * DD + DF;
        const float* f1b = F1b + (long)l * FDIM;
        const float* f2b = F2b + (long)l * DMODEL;
        float* attn_l = attn_base + (long)l * NBATCH * NHEAD * SLEN * SLEN;

        // fused QKV: [NTOK,768] @ [768,2304] -> qkvb bf16 (+ V scattered into vtb)
        launch_gemm<128, 128, 1, 0, 1>(stream, xb, DMODEL, 0, 0,
                                       qkvT, DMODEL, 0, 0,
                                       qkvb, 3 * DMODEL, 0, 0,
                                       1, nullptr, NTOK, 3 * DMODEL, DMODEL, 1.f, 1, vtb);

        // fused QK^T + mask + softmax + PV -> attn_l (f32) + ob (bf16)
        attn_kernel<<<dim3(SLEN / 64, NBATCH * NHEAD), 256, 0, stream>>>(
            qkvb, vtb, amask, attn_l, ob);

        // o @ Wo, split-K=2 -> p0,p1  (k-chunk 384)
        launch_gemm<128, 64, 0, 0>(stream, ob, DMODEL, 384, 0,
                                   woT, DMODEL, 384, 0,
                                   p0, DMODEL, nd, 0,
                                   1, nullptr, NTOK, DMODEL, 384, 1.f, 2);

        ln_res2_kernel<<<NTOK, 256, 0, stream>>>(x, p0, p1, nullptr,
                                                 G1 + (long)l * DMODEL, B1 + (long)l * DMODEL, x1, x1b);

        // h = gelu(x1 @ f1w + f1b)  -> hb bf16
        launch_gemm<128, 128, 1, 1>(stream, x1b, DMODEL, 0, 0,
                                    f1T, DMODEL, 0, 0,
                                    hb, FDIM, 0, 0,
                                    1, f1b, NTOK, FDIM, DMODEL, 1.f, 1);

        // FF2 split-K=4: partial s covers k in [s*768, s*768+768)
        launch_gemm<128, 128, 0, 0>(stream, hb, FDIM, 768, 0,
                                    f2T, FDIM, 768, 0,
                                    p0, DMODEL, nd, 0,
                                    1, nullptr, NTOK, DMODEL, 768, 1.f, 4);

        ln_res4_kernel<<<NTOK, 256, 0, stream>>>(x1, p0, p1, p2, p3, f2b,
                                                 G2 + (long)l * DMODEL, B2 + (long)l * DMODEL, x, xb);
    }

    // logits = x @ out_w + out_b
    launch_gemm<128, 128, 0, 0>(stream, xb, DMODEL, 0, 0,
                                owT, DMODEL, 0, 0,
                                logits, VOCAB, 0, 0,
                                1, OutB, NTOK, VOCAB, DMODEL, 1.f, 1);
}

// Round 8
// 1725.987 us; speedup vs baseline: 6.0474x; 1.0187x over previous
//
#include <hip/hip_runtime.h>
#include <hip/hip_bf16.h>

#define NLAYER 12
#define DMODEL 768
#define NHEAD  12
#define HDIM   64
#define FDIM   3072
#define VOCAB  30522
#define SLEN   512
#define NBATCH 4
#define NTOK   (NBATCH*SLEN)
#define EPSLN  1e-5f

typedef unsigned short u16;
using bf16 = __hip_bfloat16;
typedef __bf16 bf16x8 __attribute__((ext_vector_type(8)));
typedef float  f32x4  __attribute__((ext_vector_type(4)));
typedef u16    u16x4  __attribute__((ext_vector_type(4)));

__device__ __forceinline__ u16 f2bs(float f) {
    bf16 h = __float2bfloat16(f);
    return *reinterpret_cast<u16*>(&h);
}

// async global->LDS, 16B per lane. LDS dest = wave-uniform base + lane*16.
__device__ __forceinline__ void gload_lds16(const void* g, void* l) {
    auto gp = (const __attribute__((address_space(1))) unsigned int*)g;
    auto lp = (__attribute__((address_space(3))) unsigned int*)(unsigned long long)l;
    __builtin_amdgcn_global_load_lds(gp, lp, 16, 0, 0);
}

template<int N> __device__ __forceinline__ void waitv() {
    if constexpr (N == 0)      asm volatile("s_waitcnt vmcnt(0)" ::: "memory");
    else if constexpr (N == 3) asm volatile("s_waitcnt vmcnt(3)" ::: "memory");
    else if constexpr (N == 4) asm volatile("s_waitcnt vmcnt(4)" ::: "memory");
    else if constexpr (N == 6) asm volatile("s_waitcnt vmcnt(6)" ::: "memory");
    else if constexpr (N == 8) asm volatile("s_waitcnt vmcnt(8)" ::: "memory");
}

// ---------------- reductions ----------------
__device__ __forceinline__ float wave_sum64(float v) {
#pragma unroll
    for (int off = 32; off > 0; off >>= 1) v += __shfl_down(v, off, 64);
    return v;
}
__device__ __forceinline__ float block_sum256(float v, float* red) {
    v = wave_sum64(v);
    __syncthreads();
    if ((threadIdx.x & 63) == 0) red[threadIdx.x >> 6] = v;
    __syncthreads();
    return red[0] + red[1] + red[2] + red[3];
}

// ---------------- embedding + LN (writes f32 + bf16) ----------------
__global__ __launch_bounds__(256) void embed_ln_kernel(
    const int* __restrict__ ids, const float* __restrict__ word,
    const float* __restrict__ pos, const float* __restrict__ seg,
    const float* __restrict__ g, const float* __restrict__ b,
    float* __restrict__ out, u16* __restrict__ outb)
{
    __shared__ float red[4];
    int t = blockIdx.x;
    int s = t & (SLEN - 1);
    long woff = (long)ids[t] * DMODEL;
    float vals[3];
#pragma unroll
    for (int i = 0; i < 3; i++) {
        int d = threadIdx.x + i * 256;
        vals[i] = word[woff + d] + pos[(long)s * DMODEL + d] + seg[d];
    }
    float mu = block_sum256(vals[0] + vals[1] + vals[2], red) * (1.0f / DMODEL);
    float vv = 0.f;
#pragma unroll
    for (int i = 0; i < 3; i++) { float d0 = vals[i] - mu; vv += d0 * d0; }
    float rstd = rsqrtf(block_sum256(vv, red) * (1.0f / DMODEL) + EPSLN);
#pragma unroll
    for (int i = 0; i < 3; i++) {
        int d = threadIdx.x + i * 256;
        float r = (vals[i] - mu) * rstd * g[d] + b[d];
        out[(long)t * DMODEL + d] = r;
        outb[(long)t * DMODEL + d] = f2bs(r);
    }
}

// ------------- residual + 2 partials (+opt bias) + LN ----------------------
__global__ __launch_bounds__(256) void ln_res2_kernel(
    const float* __restrict__ a, const float* __restrict__ p0,
    const float* __restrict__ p1, const float* __restrict__ cbias,
    const float* __restrict__ g, const float* __restrict__ beta,
    float* __restrict__ out, u16* __restrict__ outb)
{
    __shared__ float red[4];
    long t = blockIdx.x;
    float vals[3];
#pragma unroll
    for (int i = 0; i < 3; i++) {
        int d = threadIdx.x + i * 256;
        float bb = cbias ? cbias[d] : 0.f;
        vals[i] = a[t * DMODEL + d] + p0[t * DMODEL + d] + p1[t * DMODEL + d] + bb;
    }
    float mu = block_sum256(vals[0] + vals[1] + vals[2], red) * (1.0f / DMODEL);
    float vv = 0.f;
#pragma unroll
    for (int i = 0; i < 3; i++) { float d0 = vals[i] - mu; vv += d0 * d0; }
    float rstd = rsqrtf(block_sum256(vv, red) * (1.0f / DMODEL) + EPSLN);
#pragma unroll
    for (int i = 0; i < 3; i++) {
        int d = threadIdx.x + i * 256;
        float r = (vals[i] - mu) * rstd * g[d] + beta[d];
        out[t * DMODEL + d] = r;
        outb[t * DMODEL + d] = f2bs(r);
    }
}

// ---------------- all-weights transpose-convert, ONE launch ----------------
#define DD (DMODEL*DMODEL)
#define DF (DMODEL*FDIM)
#define LAYER_W_ELEMS (4*DD + 2*DF)
#define TILES_DD 576
#define TILES_DF 2304
#define TILES_LAYER (4*TILES_DD + 2*TILES_DF)
#define TILES_ALL (NLAYER*TILES_LAYER)
#define NTX_OW ((VOCAB + 31) / 32)
#define TILES_OW (NTX_OW * (DMODEL/32))

__global__ __launch_bounds__(256) void conv_all_kernel(
    const float* __restrict__ Wq, const float* __restrict__ Wk,
    const float* __restrict__ Wv, const float* __restrict__ Wo,
    const float* __restrict__ F1w, const float* __restrict__ F2w,
    const float* __restrict__ OutW, u16* __restrict__ wT, u16* __restrict__ owT)
{
    __shared__ float t[32][33];
    int id = blockIdx.x;
    const float* src; u16* dst; int K, N, tt;
    if (id < TILES_ALL) {
        int l = id / TILES_LAYER, r = id - l * TILES_LAYER;
        u16* base = wT + (long)l * LAYER_W_ELEMS;
        if (r < TILES_DD)           { src = Wq  + (long)l * DD; dst = base;            K = DMODEL; N = DMODEL; tt = r; }
        else if (r < 2 * TILES_DD)  { src = Wk  + (long)l * DD; dst = base + DD;       K = DMODEL; N = DMODEL; tt = r - TILES_DD; }
        else if (r < 3 * TILES_DD)  { src = Wv  + (long)l * DD; dst = base + 2 * DD;   K = DMODEL; N = DMODEL; tt = r - 2 * TILES_DD; }
        else if (r < 4 * TILES_DD)  { src = Wo  + (long)l * DD; dst = base + 3 * DD;   K = DMODEL; N = DMODEL; tt = r - 3 * TILES_DD; }
        else if (r < 4 * TILES_DD + TILES_DF)
                                    { src = F1w + (long)l * DF; dst = base + 4 * DD;   K = DMODEL; N = FDIM;   tt = r - 4 * TILES_DD; }
        else                        { src = F2w + (long)l * DF; dst = base + 4 * DD + DF; K = FDIM; N = DMODEL; tt = r - 4 * TILES_DD - TILES_DF; }
    } else {
        src = OutW; dst = owT; K = DMODEL; N = VOCAB; tt = id - TILES_ALL;
    }
    int ntx = (N + 31) >> 5;
    int n0 = (tt % ntx) * 32, k0 = (tt / ntx) * 32;
    int tx = threadIdx.x & 31, ty = threadIdx.x >> 5;
#pragma unroll
    for (int i = 0; i < 32; i += 8) {
        int k = k0 + ty + i, n = n0 + tx;
        t[ty + i][tx] = (k < K && n < N) ? src[(long)k * N + n] : 0.f;
    }
    __syncthreads();
#pragma unroll
    for (int i = 0; i < 32; i += 8) {
        int n = n0 + ty + i, k = k0 + tx;
        if (n < N && k < K) dst[(long)n * K + k] = f2bs(t[tx][ty + i]);
    }
}

// -------- fused QK^T + mask + softmax + PV  (one kernel per 64 Q-rows) -----
__global__ __launch_bounds__(256, 2) void attn_kernel(
    const u16* __restrict__ qkvb, const u16* __restrict__ vtb,
    const int* __restrict__ amask,
    float* __restrict__ attn, u16* __restrict__ ob)
{
    __shared__ u16 Qs[64][64];
    __shared__ u16 Ks[SLEN][64];
    __shared__ float maskadd[SLEN];
    __shared__ __align__(16) float redA[64][4];
    __shared__ __align__(16) float redB[64][4];

    u16* Ph = &Ks[0][0];
    u16* Vh = &Ks[256][0];

    int z = blockIdx.y;
    int b = z / NHEAD, h = z - b * NHEAD;
    int m0 = blockIdx.x * 64;
    int tid = threadIdx.x;
    int wave = tid >> 6, lane = tid & 63;
    int quad = lane >> 4, l16 = lane & 15;
    const float scale = 0.036084391824351615f;   // 1/sqrt(768)

    for (int i = tid; i < SLEN; i += 256)
        maskadd[i] = amask[b * SLEN + i] ? 0.f : -1e30f;

    const u16* Qbase = qkvb + (long)(b * SLEN) * (3 * DMODEL) + h * HDIM;
    const u16* Kbase = Qbase + DMODEL;
    const u16* Vtbase = vtb + (long)z * HDIM * SLEN;

#pragma unroll
    for (int i = 0; i < 2; i++) {
        int off = wave * 2048 + i * 1024 + lane * 16;
        int row = off >> 7, c = (off >> 4) & 7, g = c ^ (row & 7);
        gload_lds16(Qbase + (long)(m0 + row) * (3 * DMODEL) + g * 8,
                    (char*)&Qs[0][0] + wave * 2048 + i * 1024);
    }
#pragma unroll
    for (int i = 0; i < 16; i++) {
        int off = wave * 16384 + i * 1024 + lane * 16;
        int row = off >> 7, c = (off >> 4) & 7, g = c ^ (row & 7);
        gload_lds16(Kbase + (long)row * (3 * DMODEL) + g * 8,
                    (char*)&Ks[0][0] + wave * 16384 + i * 1024);
    }
    __syncthreads();

    f32x4 acc[4][8];
#pragma unroll
    for (int i = 0; i < 4; i++)
#pragma unroll
        for (int j = 0; j < 8; j++) acc[i][j] = (f32x4){0.f, 0.f, 0.f, 0.f};

#pragma unroll
    for (int ks = 0; ks < 2; ks++) {
        bf16x8 afr[4], bfr[8];
#pragma unroll
        for (int i = 0; i < 4; i++) {
            int row = i * 16 + l16;
            int slot = ((ks << 2) + quad) ^ (row & 7);
            afr[i] = *reinterpret_cast<const bf16x8*>((char*)&Qs[0][0] + row * 128 + slot * 16);
        }
#pragma unroll
        for (int j = 0; j < 8; j++) {
            int row = wave * 128 + j * 16 + l16;
            int slot = ((ks << 2) + quad) ^ (row & 7);
            bfr[j] = *reinterpret_cast<const bf16x8*>((char*)&Ks[0][0] + row * 128 + slot * 16);
        }
#pragma unroll
        for (int i = 0; i < 4; i++)
#pragma unroll
            for (int j = 0; j < 8; j++)
                acc[i][j] = __builtin_amdgcn_mfma_f32_16x16x32_bf16(afr[i], bfr[j], acc[i][j], 0, 0, 0);
    }

    float ma[8];
#pragma unroll
    for (int j = 0; j < 8; j++) ma[j] = maskadd[wave * 128 + j * 16 + l16];

    float rmax[4][4];
#pragma unroll
    for (int i = 0; i < 4; i++)
#pragma unroll
        for (int r = 0; r < 4; r++) {
            float m = -3e38f;
#pragma unroll
            for (int j = 0; j < 8; j++) m = fmaxf(m, acc[i][j][r] * scale + ma[j]);
            rmax[i][r] = m;
        }
#pragma unroll
    for (int off = 1; off < 16; off <<= 1)
#pragma unroll
        for (int i = 0; i < 4; i++)
#pragma unroll
            for (int r = 0; r < 4; r++)
                rmax[i][r] = fmaxf(rmax[i][r], __shfl_xor(rmax[i][r], off, 64));
    if (l16 == 0) {
#pragma unroll
        for (int i = 0; i < 4; i++)
#pragma unroll
            for (int r = 0; r < 4; r++) redA[i * 16 + quad * 4 + r][wave] = rmax[i][r];
    }
    __syncthreads();          // all waves done reading Ks; safe to restage V

    {
        const u16* Vb = Vtbase + 0;
#pragma unroll
        for (int i = 0; i < 8; i++) {
            int o = wave * 8192 + i * 1024 + lane * 16;
            int hd = o >> 9, c = (o >> 4) & 31, g = c ^ (hd & 7);
            gload_lds16(Vb + (long)hd * SLEN + g * 8, (char*)Vh + wave * 8192 + i * 1024);
        }
    }

#pragma unroll
    for (int i = 0; i < 4; i++)
#pragma unroll
        for (int r = 0; r < 4; r++) {
            f32x4 v = *reinterpret_cast<const f32x4*>(&redA[i * 16 + quad * 4 + r][0]);
            rmax[i][r] = fmaxf(fmaxf(v[0], v[1]), fmaxf(v[2], v[3]));
        }

    float rsum[4][4];
#pragma unroll
    for (int i = 0; i < 4; i++)
#pragma unroll
        for (int r = 0; r < 4; r++) {
            float s = 0.f;
#pragma unroll
            for (int j = 0; j < 8; j++) {
                float e = expf(acc[i][j][r] * scale + ma[j] - rmax[i][r]);
                acc[i][j][r] = e;
                s += e;
            }
            rsum[i][r] = s;
        }
#pragma unroll
    for (int off = 1; off < 16; off <<= 1)
#pragma unroll
        for (int i = 0; i < 4; i++)
#pragma unroll
            for (int r = 0; r < 4; r++)
                rsum[i][r] += __shfl_xor(rsum[i][r], off, 64);
    if (l16 == 0) {
#pragma unroll
        for (int i = 0; i < 4; i++)
#pragma unroll
            for (int r = 0; r < 4; r++) redB[i * 16 + quad * 4 + r][wave] = rsum[i][r];
    }
    __syncthreads();          // (also drains V half0 loads)

    float* ap = attn + (long)z * SLEN * SLEN;
#pragma unroll
    for (int i = 0; i < 4; i++)
#pragma unroll
        for (int r = 0; r < 4; r++) {
            f32x4 v = *reinterpret_cast<const f32x4*>(&redB[i * 16 + quad * 4 + r][0]);
            float inv = 1.0f / (v[0] + v[1] + v[2] + v[3]);
            long row = m0 + i * 16 + quad * 4 + r;
#pragma unroll
            for (int j = 0; j < 8; j++) {
                int col = (wave << 7) + j * 16 + l16;
                float p = acc[i][j][r] * inv;
                acc[i][j][r] = p;
                ap[row * SLEN + col] = p;
            }
        }

    if (wave < 2) {
#pragma unroll
        for (int i = 0; i < 4; i++)
#pragma unroll
            for (int j = 0; j < 8; j++) {
                int cl = (wave << 7) + j * 16 + l16;
#pragma unroll
                for (int r = 0; r < 4; r++) {
                    int row = i * 16 + quad * 4 + r;
                    int slot = (cl >> 3) ^ (row & 7);
                    *(u16*)((char*)Ph + row * 512 + slot * 16 + (cl & 7) * 2) = f2bs(acc[i][j][r]);
                }
            }
    }
    __syncthreads();          // Ph half0 + Vh half0 ready

    f32x4 acc2[4];
#pragma unroll
    for (int j = 0; j < 4; j++) acc2[j] = (f32x4){0.f, 0.f, 0.f, 0.f};

#pragma unroll
    for (int step = 0; step < 8; step++) {
        int Prow = (wave << 4) + l16;
        int aslot = (step * 4 + quad) ^ (Prow & 7);
        bf16x8 af = *reinterpret_cast<const bf16x8*>((char*)Ph + Prow * 512 + aslot * 16);
#pragma unroll
        for (int j = 0; j < 4; j++) {
            int hd = j * 16 + l16;
            int bslot = (step * 4 + quad) ^ (hd & 7);
            bf16x8 bf = *reinterpret_cast<const bf16x8*>((char*)Vh + hd * 512 + bslot * 16);
            acc2[j] = __builtin_amdgcn_mfma_f32_16x16x32_bf16(af, bf, acc2[j], 0, 0, 0);
        }
    }
    __syncthreads();          // all reads of half0 regions done

    {
        const u16* Vb = Vtbase + 256;
#pragma unroll
        for (int i = 0; i < 8; i++) {
            int o = wave * 8192 + i * 1024 + lane * 16;
            int hd = o >> 9, c = (o >> 4) & 31, g = c ^ (hd & 7);
            gload_lds16(Vb + (long)hd * SLEN + g * 8, (char*)Vh + wave * 8192 + i * 1024);
        }
    }
    if (wave >= 2) {
#pragma unroll
        for (int i = 0; i < 4; i++)
#pragma unroll
            for (int j = 0; j < 8; j++) {
                int cl = ((wave - 2) << 7) + j * 16 + l16;
#pragma unroll
                for (int r = 0; r < 4; r++) {
                    int row = i * 16 + quad * 4 + r;
                    int slot = (cl >> 3) ^ (row & 7);
                    *(u16*)((char*)Ph + row * 512 + slot * 16 + (cl & 7) * 2) = f2bs(acc[i][j][r]);
                }
            }
    }
    __syncthreads();          // Ph half1 + Vh half1 ready

#pragma unroll
    for (int step = 0; step < 8; step++) {
        int Prow = (wave << 4) + l16;
        int aslot = (step * 4 + quad) ^ (Prow & 7);
        bf16x8 af = *reinterpret_cast<const bf16x8*>((char*)Ph + Prow * 512 + aslot * 16);
#pragma unroll
        for (int j = 0; j < 4; j++) {
            int hd = j * 16 + l16;
            int bslot = (step * 4 + quad) ^ (hd & 7);
            bf16x8 bf = *reinterpret_cast<const bf16x8*>((char*)Vh + hd * 512 + bslot * 16);
            acc2[j] = __builtin_amdgcn_mfma_f32_16x16x32_bf16(af, bf, acc2[j], 0, 0, 0);
        }
    }

#pragma unroll
    for (int j = 0; j < 4; j++)
#pragma unroll
        for (int r = 0; r < 4; r++) {
            int q = m0 + (wave << 4) + quad * 4 + r;
            ob[((long)(b * SLEN + q)) * DMODEL + h * HDIM + j * 16 + l16] = f2bs(acc2[j][r]);
        }
}

// --- bf16 MFMA GEMM: 8-wave blocks, BK=64, depth-2 counted-vmcnt, swizzled --
// C[z] = epi( scale * A[z] @ B[z]^T + bias ),  A:[M][K] bf16, B:[N][K] bf16
// Waves 2x4: wave tile (BM/2) x (BN/4).  LDS rows are 128B; slot s of row r
// holds k-chunk s ^ (r&7) (pre-swizzled global source, linear LDS dest;
// fragment read XORs the same involution -> 2-way banks).
// QKVF: also scatter V-part (col>=1536) into vt[b,h,hd,s] (packed ushort4)
template<int BM, int BN, int OUTBF, int GELU, int QKVF>
__global__ __launch_bounds__(512) void gemm_bf16(
    const u16* __restrict__ A, int lda, long sA1, long sA2,
    const u16* __restrict__ B, int ldb, long sB1, long sB2,
    void* __restrict__ Cv, int ldc, long sC1, long sC2,
    int zdiv, const float* __restrict__ bias,
    int N, int K, float scale, u16* __restrict__ vt)
{
    __shared__ u16 As[2][BM][64];
    __shared__ u16 Bs[2][BN][64];
    int z = blockIdx.z;
    int zq = z / zdiv, zr = z - zq * zdiv;
    A += zq * sA1 + zr * sA2;
    B += zq * sB1 + zr * sB2;

    int m0 = blockIdx.y * BM;
    int n0 = blockIdx.x * BN;
    int tid = threadIdx.x;
    int wave = tid >> 6, lane = tid & 63;
    int quad = lane >> 4, l16 = lane & 15;
    int wr = wave >> 2, wc = wave & 3;           // 2 x 4 wave grid
    constexpr int MR = BM / 32, NR = BN / 64;    // fragments per wave
    constexpr int PA = BM / 64, PB = BN / 64;    // staging passes
    constexpr int LPT = PA + PB;                 // gloads per WAVE per tile

    f32x4 acc[MR][NR];
#pragma unroll
    for (int i = 0; i < MR; i++)
#pragma unroll
        for (int j = 0; j < NR; j++) acc[i][j] = (f32x4){0.f, 0.f, 0.f, 0.f};

    auto stage = [&](int buf, int k0) {
#pragma unroll
        for (int p = 0; p < PA; p++) {
            int chunk = p * 512 + tid;               // 16B chunk id, 8 per row
            int row = chunk >> 3, sc = chunk & 7;
            int gcol = (sc ^ (row & 7)) * 8;         // pre-swizzled source chunk
            gload_lds16(A + (long)(m0 + row) * lda + k0 + gcol,
                        (char*)&As[buf][0][0] + p * 8192 + wave * 1024);
        }
#pragma unroll
        for (int p = 0; p < PB; p++) {
            int chunk = p * 512 + tid;
            int row = chunk >> 3, sc = chunk & 7;
            int grow = n0 + row;
            if (grow > N - 1) grow = N - 1;          // tail: dup reads, masked later
            int gcol = (sc ^ (row & 7)) * 8;
            gload_lds16(B + (long)grow * ldb + k0 + gcol,
                        (char*)&Bs[buf][0][0] + p * 8192 + wave * 1024);
        }
    };

    int nt = K >> 6;                                 // BK = 64
    stage(0, 0);
    if (nt > 1) stage(1, 64);

    for (int t = 0; t < nt; ++t) {
        if (t + 1 < nt) waitv<LPT>();                // next tile may stay in flight
        else            waitv<0>();
        __builtin_amdgcn_s_barrier();
        __builtin_amdgcn_sched_barrier(0);

        int cur = t & 1;
#pragma unroll
        for (int kh = 0; kh < 2; kh++) {             // two 32-K halves
            bf16x8 afr[MR], bfr[NR];
#pragma unroll
            for (int i = 0; i < MR; i++) {
                int row = wr * (BM / 2) + i * 16 + l16;
                int slot = ((kh << 2) + quad) ^ (row & 7);
                afr[i] = *reinterpret_cast<const bf16x8*>(
                    (char*)&As[cur][0][0] + row * 128 + slot * 16);
            }
#pragma unroll
            for (int j = 0; j < NR; j++) {
                int row = wc * (BN / 4) + j * 16 + l16;
                int slot = ((kh << 2) + quad) ^ (row & 7);
                bfr[j] = *reinterpret_cast<const bf16x8*>(
                    (char*)&Bs[cur][0][0] + row * 128 + slot * 16);
            }
            __builtin_amdgcn_s_setprio(1);
#pragma unroll
            for (int i = 0; i < MR; i++)
#pragma unroll
                for (int j = 0; j < NR; j++)
                    acc[i][j] = __builtin_amdgcn_mfma_f32_16x16x32_bf16(afr[i], bfr[j], acc[i][j], 0, 0, 0);
            __builtin_amdgcn_s_setprio(0);
        }

        asm volatile("" ::: "memory");
        __builtin_amdgcn_sched_barrier(0);
        __builtin_amdgcn_s_barrier();                // all reads of buf done
        __builtin_amdgcn_sched_barrier(0);
        if (t + 2 < nt) stage(cur, (t + 2) << 6);
    }

    float* Cf = (float*)Cv;
    u16*   Cb = (u16*)Cv;
    long coff = zq * sC1 + zr * sC2;
#pragma unroll
    for (int i = 0; i < MR; i++) {
        int rbase = m0 + wr * (BM / 2) + i * 16 + quad * 4;
#pragma unroll
        for (int j = 0; j < NR; j++) {
            int col = n0 + wc * (BN / 4) + j * 16 + l16;
            if (col < N) {
                float badd = bias ? bias[col] : 0.f;
                u16x4 v4;
#pragma unroll
                for (int r = 0; r < 4; r++) {
                    float vv = acc[i][j][r] * scale + badd;
                    if (GELU) vv = 0.5f * vv * (1.0f + erff(vv * 0.70710678118f));
                    long idx = coff + (long)(rbase + r) * ldc + col;
                    if (OUTBF) { u16 u = f2bs(vv); Cb[idx] = u; v4[r] = u; }
                    else       Cf[idx] = vv;
                }
                if (QKVF && col >= 2 * DMODEL) {
                    int hh = (col - 2 * DMODEL) >> 6, hd = col & 63;
                    int bb = rbase >> 9, s = rbase & (SLEN - 1);
                    *reinterpret_cast<u16x4*>(
                        vt + ((long)(bb * NHEAD + hh) * HDIM + hd) * SLEN + s) = v4;
                }
            }
        }
    }
}

template<int BM, int BN, int OUTBF, int GELU, int QKVF = 0>
static inline void launch_gemm(hipStream_t stream,
    const u16* A, int lda, long sA1, long sA2,
    const u16* B, int ldb, long sB1, long sB2,
    void* C, int ldc, long sC1, long sC2,
    int zdiv, const float* bias, int M, int N, int K, float scale, int Z,
    u16* vt = nullptr)
{
    dim3 grid((N + BN - 1) / BN, M / BM, Z);
    gemm_bf16<BM, BN, OUTBF, GELU, QKVF><<<grid, 512, 0, stream>>>(
        A, lda, sA1, sA2, B, ldb, sB1, sB2, C, ldc, sC1, sC2,
        zdiv, bias, N, K, scale, vt);
}

// ---------------- driver ----------------
extern "C" void kernel_launch(void* const* d_in, const int* in_sizes, int n_in,
                              void* d_out, int out_size, void* d_ws, size_t ws_size,
                              hipStream_t stream)
{
    const int*   ids   = (const int*)d_in[0];
    const int*   amask = (const int*)d_in[1];
    const float* word  = (const float*)d_in[2];
    const float* pos   = (const float*)d_in[3];
    const float* seg   = (const float*)d_in[4];
    const float* eg    = (const float*)d_in[5];
    const float* eb    = (const float*)d_in[6];
    const float* Wq    = (const float*)d_in[7];
    const float* Wk    = (const float*)d_in[8];
    const float* Wv    = (const float*)d_in[9];
    const float* Wo    = (const float*)d_in[10];
    const float* F1w   = (const float*)d_in[11];
    const float* F1b   = (const float*)d_in[12];
    const float* F2w   = (const float*)d_in[13];
    const float* F2b   = (const float*)d_in[14];
    const float* G1    = (const float*)d_in[15];
    const float* B1    = (const float*)d_in[16];
    const float* G2    = (const float*)d_in[17];
    const float* B2    = (const float*)d_in[18];
    const float* OutW  = (const float*)d_in[19];
    const float* OutB  = (const float*)d_in[20];

    float* logits = (float*)d_out;
    float* attn_base = logits + (long)NTOK * VOCAB;

    long nd = (long)NTOK * DMODEL;
    // f32 region
    float* x  = (float*)d_ws;          // NTOK x D
    float* x1 = x + nd;                // NTOK x D
    float* p0 = x1 + nd;               // NTOK x D partials
    float* p1 = p0 + nd;
    // bf16 region
    u16* xb   = (u16*)(p1 + nd);                       // NTOK x D
    u16* x1b  = xb + nd;                               // NTOK x D
    u16* qkvb = x1b + nd;                              // NTOK x 3D
    u16* vtb  = qkvb + (long)NTOK * 3 * DMODEL;        // B*H x HD x S == nd
    u16* ob   = vtb + nd;                              // NTOK x D
    u16* hb   = ob + nd;                               // NTOK x F
    u16* wT   = hb + (long)NTOK * FDIM;                // 12 x LAYER_W_ELEMS
    u16* owT  = wT + (long)NLAYER * LAYER_W_ELEMS;     // [VOCAB][D]

    conv_all_kernel<<<TILES_ALL + TILES_OW, 256, 0, stream>>>(
        Wq, Wk, Wv, Wo, F1w, F2w, OutW, wT, owT);

    embed_ln_kernel<<<NTOK, 256, 0, stream>>>(ids, word, pos, seg, eg, eb, x, xb);

    for (int l = 0; l < NLAYER; l++) {
        const u16* qkvT = wT + (long)l * LAYER_W_ELEMS;
        const u16* woT  = qkvT + 3 * DD;
        const u16* f1T  = qkvT + 4 * DD;
        const u16* f2T  = qkvT + 4 * DD + DF;
        const float* f1b = F1b + (long)l * FDIM;
        const float* f2b = F2b + (long)l * DMODEL;
        float* attn_l = attn_base + (long)l * NBATCH * NHEAD * SLEN * SLEN;

        // fused QKV: [NTOK,768] @ [768,2304] -> qkvb bf16 (+ V scattered into vtb)
        launch_gemm<128, 64, 1, 0, 1>(stream, xb, DMODEL, 0, 0,
                                      qkvT, DMODEL, 0, 0,
                                      qkvb, 3 * DMODEL, 0, 0,
                                      1, nullptr, NTOK, 3 * DMODEL, DMODEL, 1.f, 1, vtb);

        // fused QK^T + mask + softmax + PV -> attn_l (f32) + ob (bf16)
        attn_kernel<<<dim3(SLEN / 64, NBATCH * NHEAD), 256, 0, stream>>>(
            qkvb, vtb, amask, attn_l, ob);

        // o @ Wo, split-K=2 -> p0,p1  (k-chunk 384)
        launch_gemm<128, 64, 0, 0>(stream, ob, DMODEL, 384, 0,
                                   woT, DMODEL, 384, 0,
                                   p0, DMODEL, nd, 0,
                                   1, nullptr, NTOK, DMODEL, 384, 1.f, 2);

        ln_res2_kernel<<<NTOK, 256, 0, stream>>>(x, p0, p1, nullptr,
                                                 G1 + (long)l * DMODEL, B1 + (long)l * DMODEL, x1, x1b);

        // h = gelu(x1 @ f1w + f1b)  -> hb bf16
        launch_gemm<128, 64, 1, 1>(stream, x1b, DMODEL, 0, 0,
                                   f1T, DMODEL, 0, 0,
                                   hb, FDIM, 0, 0,
                                   1, f1b, NTOK, FDIM, DMODEL, 1.f, 1);

        // FF2 split-K=2: partial s covers k in [s*1536, s*1536+1536)
        launch_gemm<128, 64, 0, 0>(stream, hb, FDIM, 1536, 0,
                                   f2T, FDIM, 1536, 0,
                                   p0, DMODEL, nd, 0,
                                   1, nullptr, NTOK, DMODEL, 1536, 1.f, 2);

        ln_res2_kernel<<<NTOK, 256, 0, stream>>>(x1, p0, p1, f2b,
                                                 G2 + (long)l * DMODEL, B2 + (long)l * DMODEL, x, xb);
    }

    // logits = x @ out_w + out_b
    launch_gemm<128, 128, 0, 0>(stream, xb, DMODEL, 0, 0,
                                owT, DMODEL, 0, 0,
                                logits, VOCAB, 0, 0,
                                1, OutB, NTOK, VOCAB, DMODEL, 1.f, 1);
}